// Round 1
// baseline (1055.746 us; speedup 1.0000x reference)
//
#include <hip/hip_runtime.h>

#define DEV __device__ __forceinline__

DEV float sigmoidf_(float x){ return 1.0f/(1.0f + __expf(-x)); }
DEV float tanhf_(float x){
    x = fminf(15.0f, fmaxf(-15.0f, x));
    float e = __expf(2.0f*x);
    return (e - 1.0f)/(e + 1.0f);
}

// ---------- weight transpose: [256][128][9] -> [128*9][256] ----------
__global__ __launch_bounds__(256)
void wtrans_kernel(const float* __restrict__ w, float* __restrict__ wT)
{
    int idx = blockIdx.x*256 + threadIdx.x;
    if (idx >= 256*128*9) return;
    int co  = idx / 1152;
    int rem = idx - co*1152;      // ci*9 + tap
    wT[rem*256 + co] = w[idx];
}

// ---------- 3x3 conv, input = concat(in0,in1), each [16][64][32][32] ----------
// wT: [[ci*9+tap]][256], out: [16][256][1024]
__global__ __launch_bounds__(256)
void conv3x3_kernel(const float* __restrict__ in0, const float* __restrict__ in1,
                    const float* __restrict__ wT, const float* __restrict__ bias,
                    float* __restrict__ out)
{
    const int b   = blockIdx.z;
    const int co0 = blockIdx.y * 32;
    const int r0  = blockIdx.x * 8;
    const int t = threadIdx.x;
    const int c = t & 31;    // output col
    const int r = t >> 5;    // output row within tile (0..7)

    __shared__ float lin[4][10][34];   // [ci][row -1..+8][col -1..+32]

    float acc[32];
#pragma unroll
    for (int j=0;j<32;j++) acc[j] = 0.0f;

    for (int ci0 = 0; ci0 < 128; ci0 += 4) {
        __syncthreads();
        for (int k = t; k < 4*10*34; k += 256) {
            int ci  = k / 340;
            int rem = k - ci*340;
            int rr  = rem / 34;
            int cc  = rem - rr*34;
            int gr  = r0 + rr - 1;
            int gc  = cc - 1;
            float v = 0.0f;
            if ((unsigned)gr < 32u && (unsigned)gc < 32u) {
                int cig = ci0 + ci;
                const float* src = (cig < 64) ? (in0 + (b*64 + cig)*1024)
                                              : (in1 + (b*64 + (cig-64))*1024);
                v = src[gr*32 + gc];
            }
            lin[ci][rr][cc] = v;
        }
        __syncthreads();
#pragma unroll
        for (int i=0;i<4;i++) {
#pragma unroll
            for (int ky=0;ky<3;ky++) {
#pragma unroll
                for (int kx=0;kx<3;kx++) {
                    float iv = lin[i][r+ky][c+kx];
                    const float* wrow = wT + ((ci0+i)*9 + ky*3 + kx)*256 + co0;
#pragma unroll
                    for (int j=0;j<32;j++) acc[j] = fmaf(iv, wrow[j], acc[j]);
                }
            }
        }
    }
    const int pix = (r0 + r)*32 + c;
#pragma unroll
    for (int j=0;j<32;j++)
        out[(b*256 + co0 + j)*1024 + pix] = acc[j] + bias[co0+j];
}

// ---------- GN (per-channel over 1024 pixels) + first gate block ----------
__global__ __launch_bounds__(256)
void gn_gate1_kernel(const float* __restrict__ cc, const float* __restrict__ gnw,
                     const float* __restrict__ gnb, const float* __restrict__ c_in,
                     float* __restrict__ c_tmp, float* __restrict__ sig_co)
{
    const int ch = blockIdx.x;   // 0..63
    const int b  = blockIdx.y;   // 0..15
    const int t  = threadIdx.x;
    __shared__ float red[4][8];

    float v[4][4];
    float scale[4], shift[4];
#pragma unroll
    for (int g=0; g<4; g++) {
        const float* src = cc + (b*256 + g*64 + ch)*1024;
        float ls = 0.f, lq = 0.f;
#pragma unroll
        for (int k=0;k<4;k++){
            float x = src[t + 256*k];
            v[g][k] = x; ls += x; lq += x*x;
        }
#pragma unroll
        for (int off=32; off>0; off>>=1){ ls += __shfl_xor(ls, off); lq += __shfl_xor(lq, off); }
        if ((t & 63) == 0){ red[t>>6][g] = ls; red[t>>6][4+g] = lq; }
    }
    __syncthreads();
#pragma unroll
    for (int g=0; g<4; g++) {
        float s = red[0][g]+red[1][g]+red[2][g]+red[3][g];
        float q = red[0][4+g]+red[1][4+g]+red[2][4+g]+red[3][4+g];
        float mu  = s * (1.0f/1024.0f);
        float var = q * (1.0f/1024.0f) - mu*mu;
        float rs  = rsqrtf(var + 1e-5f);
        float gw  = gnw[g*64+ch];
        scale[g] = rs*gw;
        shift[g] = gnb[g*64+ch] - mu*rs*gw;
    }
    const float* cp = c_in   + (b*64+ch)*1024;
    float* ct = c_tmp  + (b*64+ch)*1024;
    float* so = sig_co + (b*64+ch)*1024;
#pragma unroll
    for (int k=0;k<4;k++){
        int p = t + 256*k;
        float ni = v[0][k]*scale[0] + shift[0];
        float nf = v[1][k]*scale[1] + shift[1];
        float no = v[2][k]*scale[2] + shift[2];
        float ng = v[3][k]*scale[3] + shift[3];
        ct[p] = sigmoidf_(nf)*cp[p] + sigmoidf_(ni)*tanhf_(ng);
        so[p] = sigmoidf_(no);
    }
}

// ---------- GN + second (long) gate block ----------
__global__ __launch_bounds__(256)
void gn_gate2_kernel(const float* __restrict__ cc, const float* __restrict__ gnw,
                     const float* __restrict__ gnb, const float* __restrict__ lc_in,
                     const float* __restrict__ sig_co,
                     float* __restrict__ out_lc, float* __restrict__ out_c,
                     float* __restrict__ h_mid)
{
    const int ch = blockIdx.x;
    const int b  = blockIdx.y;
    const int t  = threadIdx.x;
    __shared__ float red[4][8];

    float v[4][4];
    float scale[4], shift[4];
#pragma unroll
    for (int g=0; g<4; g++) {
        const float* src = cc + (b*256 + g*64 + ch)*1024;
        float ls = 0.f, lq = 0.f;
#pragma unroll
        for (int k=0;k<4;k++){
            float x = src[t + 256*k];
            v[g][k] = x; ls += x; lq += x*x;
        }
#pragma unroll
        for (int off=32; off>0; off>>=1){ ls += __shfl_xor(ls, off); lq += __shfl_xor(lq, off); }
        if ((t & 63) == 0){ red[t>>6][g] = ls; red[t>>6][4+g] = lq; }
    }
    __syncthreads();
#pragma unroll
    for (int g=0; g<4; g++) {
        float s = red[0][g]+red[1][g]+red[2][g]+red[3][g];
        float q = red[0][4+g]+red[1][4+g]+red[2][4+g]+red[3][4+g];
        float mu  = s * (1.0f/1024.0f);
        float var = q * (1.0f/1024.0f) - mu*mu;
        float rs  = rsqrtf(var + 1e-5f);
        float gw  = gnw[g*64+ch];
        scale[g] = rs*gw;
        shift[g] = gnb[g*64+ch] - mu*rs*gw;
    }
    const float* lp = lc_in  + (b*64+ch)*1024;
    const float* so = sig_co + (b*64+ch)*1024;
    float* olc = out_lc + (b*64+ch)*1024;
    float* oc  = out_c  + (b*64+ch)*1024;
    float* ohm = h_mid  + (b*64+ch)*1024;
#pragma unroll
    for (int k=0;k<4;k++){
        int p = t + 256*k;
        float ni = v[0][k]*scale[0] + shift[0];
        float nf = v[1][k]*scale[1] + shift[1];
        float no = v[2][k]*scale[2] + shift[2];
        float ng = v[3][k]*scale[3] + shift[3];
        float lcn = sigmoidf_(nf)*lp[p] + sigmoidf_(ni)*tanhf_(ng);
        float cf  = sigmoidf_(no)*tanhf_(lcn);
        olc[p] = lcn;
        oc[p]  = cf;
        ohm[p] = so[p]*tanhf_(cf);
    }
}

// ---------- fused 1x1 projections: Q,Kh,Vh from h_mid; Km,Vm from m ----------
__global__ __launch_bounds__(256)
void proj_kernel(const float* __restrict__ h_mid, const float* __restrict__ m_in,
                 const float* __restrict__ wq, const float* __restrict__ bq,
                 const float* __restrict__ wk, const float* __restrict__ bk,
                 const float* __restrict__ wk2, const float* __restrict__ bk2,
                 const float* __restrict__ wv, const float* __restrict__ bv,
                 const float* __restrict__ wv2, const float* __restrict__ bv2,
                 float* __restrict__ Qo, float* __restrict__ Kho, float* __restrict__ Kmo,
                 float* __restrict__ Vho, float* __restrict__ Vmo)
{
    const int b  = blockIdx.y;
    const int p0 = blockIdx.x * 64;
    const int t  = threadIdx.x;
    __shared__ float hs[64*64];
    __shared__ float ms[64*64];
    for (int k=t;k<4096;k+=256){
        int cch = k>>6, pp = k&63;
        hs[k] = h_mid[(b*64+cch)*1024 + p0+pp];
        ms[k] = m_in [(b*64+cch)*1024 + p0+pp];
    }
    __syncthreads();
    const int p = t & 63;
    const int g = __builtin_amdgcn_readfirstlane(t >> 6);   // wave-uniform 0..3

    {
        float aq[8], ak[8], av[16];
#pragma unroll
        for (int j=0;j<8;j++){ aq[j]=bq[g*8+j]; ak[j]=bk[g*8+j]; }
#pragma unroll
        for (int j=0;j<16;j++) av[j]=bv[g*16+j];
        for (int cc=0;cc<64;cc++){
            float x = hs[cc*64+p];
#pragma unroll
            for (int j=0;j<8;j++)  aq[j] = fmaf(wq[(g*8+j)*64+cc],  x, aq[j]);
#pragma unroll
            for (int j=0;j<8;j++)  ak[j] = fmaf(wk[(g*8+j)*64+cc],  x, ak[j]);
#pragma unroll
            for (int j=0;j<16;j++) av[j] = fmaf(wv[(g*16+j)*64+cc], x, av[j]);
        }
#pragma unroll
        for (int j=0;j<8;j++){
            Qo [(b*32 + g*8+j)*1024 + p0+p] = aq[j];
            Kho[(b*32 + g*8+j)*1024 + p0+p] = ak[j];
        }
#pragma unroll
        for (int j=0;j<16;j++)
            Vho[(b*64 + g*16+j)*1024 + p0+p] = av[j];
    }
    {
        float ak[8], av[16];
#pragma unroll
        for (int j=0;j<8;j++)  ak[j]=bk2[g*8+j];
#pragma unroll
        for (int j=0;j<16;j++) av[j]=bv2[g*16+j];
        for (int cc=0;cc<64;cc++){
            float x = ms[cc*64+p];
#pragma unroll
            for (int j=0;j<8;j++)  ak[j] = fmaf(wk2[(g*8+j)*64+cc],  x, ak[j]);
#pragma unroll
            for (int j=0;j<16;j++) av[j] = fmaf(wv2[(g*16+j)*64+cc], x, av[j]);
        }
#pragma unroll
        for (int j=0;j<8;j++)
            Kmo[(b*32 + g*8+j)*1024 + p0+p] = ak[j];
#pragma unroll
        for (int j=0;j<16;j++)
            Vmo[(b*64 + g*16+j)*1024 + p0+p] = av[j];
    }
}

// ---------- dual flash attention: softmax(Q^T K) V for (Kh,Vh) and (Km,Vm) ----------
__global__ __launch_bounds__(512)
void attn_kernel(const float* __restrict__ Qg,
                 const float* __restrict__ K1, const float* __restrict__ V1,
                 const float* __restrict__ K2, const float* __restrict__ V2,
                 float* __restrict__ Z1, float* __restrict__ Z2)
{
    const int b   = blockIdx.y;
    const int p0  = blockIdx.x * 64;
    const int t   = threadIdx.x;
    const int p   = t & 63;
    const int sub = __builtin_amdgcn_readfirstlane(t >> 6);  // 0..7

    __shared__ __align__(16) float Kt[32*128];
    __shared__ __align__(16) float Vt[64*128];
    __shared__ __align__(16) float Pt[128*64];
    __shared__ float redm[8][64];
    __shared__ float reds[8][64];

    float qreg[32];
#pragma unroll
    for (int a=0;a<32;a++) qreg[a] = Qg[(b*32+a)*1024 + p0 + p];

    for (int pass=0; pass<2; pass++){
        const float* Kg = pass ? K2 : K1;
        const float* Vg = pass ? V2 : V1;
        float*       Zg = pass ? Z2 : Z1;
        float m_run = -1e30f, l_run = 0.0f;
        float acc[8];
#pragma unroll
        for (int j=0;j<8;j++) acc[j]=0.f;

        for (int q0=0;q0<1024;q0+=128){
            __syncthreads();   // protect Kt/Vt/Pt from previous chunk readers
            for (int k=t;k<32*128;k+=512) Kt[k] = Kg[(b*32 + (k>>7))*1024 + q0 + (k&127)];
            for (int k=t;k<64*128;k+=512) Vt[k] = Vg[(b*64 + (k>>7))*1024 + q0 + (k&127)];
            __syncthreads();

            // scores for q = sub*16 .. sub*16+15
            float s[16];
#pragma unroll
            for (int j=0;j<16;j++) s[j]=0.f;
            for (int a=0;a<32;a++){
                float qa = qreg[a];
                const float4* krow = reinterpret_cast<const float4*>(Kt + a*128 + sub*16);
#pragma unroll
                for (int j4=0;j4<4;j4++){
                    float4 kv = krow[j4];
                    s[j4*4+0] = fmaf(qa, kv.x, s[j4*4+0]);
                    s[j4*4+1] = fmaf(qa, kv.y, s[j4*4+1]);
                    s[j4*4+2] = fmaf(qa, kv.z, s[j4*4+2]);
                    s[j4*4+3] = fmaf(qa, kv.w, s[j4*4+3]);
                }
            }
            float lm = s[0];
#pragma unroll
            for (int j=1;j<16;j++) lm = fmaxf(lm, s[j]);
            redm[sub][p] = lm;
            __syncthreads();
            float chm = redm[0][p];
#pragma unroll
            for (int ss=1;ss<8;ss++) chm = fmaxf(chm, redm[ss][p]);
            float m_new = fmaxf(m_run, chm);
            float f = __expf(m_run - m_new);
            __syncthreads();   // done reading redm before reusing reds/Pt region
            float lsum = 0.f;
#pragma unroll
            for (int j=0;j<16;j++){
                float pv = __expf(s[j] - m_new);
                lsum += pv;
                Pt[(sub*16+j)*64 + p] = pv;
            }
            reds[sub][p] = lsum;
            __syncthreads();   // Pt + reds visible
            float chs = 0.f;
#pragma unroll
            for (int ss=0;ss<8;ss++) chs += reds[ss][p];
            l_run = l_run*f + chs;
            m_run = m_new;
#pragma unroll
            for (int j=0;j<8;j++) acc[j] *= f;
            // O[c][p] += P[q][p] * V[c][q], c = sub*8+j
#pragma unroll 4
            for (int qq=0;qq<128;qq++){
                float pv = Pt[qq*64 + p];
#pragma unroll
                for (int j=0;j<8;j++)
                    acc[j] = fmaf(pv, Vt[(sub*8+j)*128 + qq], acc[j]);
            }
        }
        float rl = 1.0f / l_run;
#pragma unroll
        for (int j=0;j<8;j++)
            Zg[(b*64 + sub*8+j)*1024 + p0 + p] = acc[j]*rl;
    }
}

// ---------- final: Z = wz*[Zh;Zm]+bz, comb = wm*[Z;h_mid]+bm, memory gates ----------
__global__ __launch_bounds__(256)
void final_kernel(const float* __restrict__ Zh, const float* __restrict__ Zm,
                  const float* __restrict__ h_mid, const float* __restrict__ m_in,
                  const float* __restrict__ wz, const float* __restrict__ bz,
                  const float* __restrict__ wm, const float* __restrict__ bm,
                  float* __restrict__ out_h, float* __restrict__ out_m)
{
    const int b  = blockIdx.y;
    const int p0 = blockIdx.x * 64;
    const int t  = threadIdx.x;
    const int p  = t & 63;
    const int g  = __builtin_amdgcn_readfirstlane(t >> 6);

    __shared__ float Zin[128*64];
    __shared__ float hs[64*64];
    __shared__ float Zmid[128*64];

    for (int k=t;k<8192;k+=256){
        int cch = k>>6, pp = k&63;
        Zin[k] = (cch<64) ? Zh[(b*64+cch)*1024 + p0+pp]
                          : Zm[(b*64+cch-64)*1024 + p0+pp];
    }
    for (int k=t;k<4096;k+=256){
        int cch = k>>6, pp = k&63;
        hs[k] = h_mid[(b*64+cch)*1024 + p0+pp];
    }
    __syncthreads();

    {   // phase 1: Z rows g*32..g*32+31
        float za[32];
#pragma unroll
        for (int j=0;j<32;j++) za[j] = bz[g*32+j];
        for (int k=0;k<128;k++){
            float x = Zin[k*64+p];
#pragma unroll
            for (int j=0;j<32;j++) za[j] = fmaf(wz[(g*32+j)*128 + k], x, za[j]);
        }
#pragma unroll
        for (int j=0;j<32;j++) Zmid[(g*32+j)*64 + p] = za[j];
    }
    __syncthreads();
    {   // phase 2: comb rows {g*16+j, 64+g*16+j, 128+g*16+j}
        float ao[16], ag[16], ai[16];
#pragma unroll
        for (int j=0;j<16;j++){
            ao[j]=bm[g*16+j]; ag[j]=bm[64+g*16+j]; ai[j]=bm[128+g*16+j];
        }
        for (int k=0;k<128;k++){
            float x = Zmid[k*64+p];
#pragma unroll
            for (int j=0;j<16;j++){
                ao[j] = fmaf(wm[(g*16+j)*192 + k],      x, ao[j]);
                ag[j] = fmaf(wm[(64+g*16+j)*192 + k],   x, ag[j]);
                ai[j] = fmaf(wm[(128+g*16+j)*192 + k],  x, ai[j]);
            }
        }
        for (int k=0;k<64;k++){
            float x = hs[k*64+p];
#pragma unroll
            for (int j=0;j<16;j++){
                ao[j] = fmaf(wm[(g*16+j)*192 + 128 + k],     x, ao[j]);
                ag[j] = fmaf(wm[(64+g*16+j)*192 + 128 + k],  x, ag[j]);
                ai[j] = fmaf(wm[(128+g*16+j)*192 + 128 + k], x, ai[j]);
            }
        }
#pragma unroll
        for (int j=0;j<16;j++){
            int ch = g*16+j;
            float mi = sigmoidf_(ai[j]);
            float mg = tanhf_(ag[j]);
            float mv = m_in[(b*64+ch)*1024 + p0+p];
            float mn = (1.0f - mi)*mv + mi*mg;
            out_m[(b*64+ch)*1024 + p0+p] = mn;
            out_h[(b*64+ch)*1024 + p0+p] = sigmoidf_(ao[j])*mn;
        }
    }
}

extern "C" void kernel_launch(void* const* d_in, const int* in_sizes, int n_in,
                              void* d_out, int out_size, void* d_ws, size_t ws_size,
                              hipStream_t stream)
{
    const float* x      = (const float*)d_in[0];
    const float* h      = (const float*)d_in[1];
    const float* c      = (const float*)d_in[2];
    const float* m      = (const float*)d_in[3];
    const float* lc     = (const float*)d_in[4];
    const float* conv_w = (const float*)d_in[5];
    const float* conv_b = (const float*)d_in[6];
    const float* gn1_w  = (const float*)d_in[7];
    const float* gn1_b  = (const float*)d_in[8];
    const float* convL_w= (const float*)d_in[9];
    const float* convL_b= (const float*)d_in[10];
    const float* gn2_w  = (const float*)d_in[11];
    const float* gn2_b  = (const float*)d_in[12];
    const float* wq  = (const float*)d_in[13];
    const float* bq  = (const float*)d_in[14];
    const float* wk  = (const float*)d_in[15];
    const float* bk  = (const float*)d_in[16];
    const float* wk2 = (const float*)d_in[17];
    const float* bk2 = (const float*)d_in[18];
    const float* wv  = (const float*)d_in[19];
    const float* bv  = (const float*)d_in[20];
    const float* wv2 = (const float*)d_in[21];
    const float* bv2 = (const float*)d_in[22];
    const float* wz  = (const float*)d_in[23];
    const float* bz  = (const float*)d_in[24];
    const float* wmw = (const float*)d_in[25];
    const float* bm  = (const float*)d_in[26];

    float* out = (float*)d_out;
    float* F = (float*)d_ws;
    // workspace layout (floats); total 13,697,024 f32 = 54.8 MB
    float* cc_raw = F;                    // [16][256][1024]
    float* c_tmp  = cc_raw + 4194304;     // [16][64][1024]
    float* sig_co = c_tmp  + 1048576;
    float* h_mid  = sig_co + 1048576;
    float* Qw  = h_mid + 1048576;         // [16][32][1024]
    float* Khw = Qw  + 524288;
    float* Kmw = Khw + 524288;
    float* Vhw = Kmw + 524288;            // [16][64][1024]
    float* Vmw = Vhw + 1048576;
    float* Zh  = Vmw + 1048576;
    float* Zm  = Zh  + 1048576;
    float* wT1 = Zm  + 1048576;           // [128*9][256]
    float* wT2 = wT1 + 294912;

    dim3 blk256(256);
    wtrans_kernel<<<dim3(1152), blk256, 0, stream>>>(conv_w,  wT1);
    wtrans_kernel<<<dim3(1152), blk256, 0, stream>>>(convL_w, wT2);

    dim3 cgrid(4, 8, 16);
    conv3x3_kernel<<<cgrid, blk256, 0, stream>>>(x, h, wT1, conv_b, cc_raw);
    gn_gate1_kernel<<<dim3(64,16), blk256, 0, stream>>>(cc_raw, gn1_w, gn1_b, c, c_tmp, sig_co);
    conv3x3_kernel<<<cgrid, blk256, 0, stream>>>(h, c_tmp, wT2, convL_b, cc_raw);
    gn_gate2_kernel<<<dim3(64,16), blk256, 0, stream>>>(cc_raw, gn2_w, gn2_b, lc, sig_co,
                                                        out + 3*1048576 /*lc_next*/,
                                                        out + 1*1048576 /*c_next*/,
                                                        h_mid);
    proj_kernel<<<dim3(16,16), blk256, 0, stream>>>(h_mid, m, wq,bq, wk,bk, wk2,bk2,
                                                    wv,bv, wv2,bv2, Qw, Khw, Kmw, Vhw, Vmw);
    attn_kernel<<<dim3(16,16), dim3(512), 0, stream>>>(Qw, Khw, Vhw, Kmw, Vmw, Zh, Zm);
    final_kernel<<<dim3(16,16), blk256, 0, stream>>>(Zh, Zm, h_mid, m, wz, bz, wmw, bm,
                                                     out /*h_next*/, out + 2*1048576 /*m_next*/);
    (void)in_sizes; (void)n_in; (void)out_size; (void)ws_size;
}

// Round 2
// 541.586 us; speedup vs baseline: 1.9494x; 1.9494x over previous
//
#include <hip/hip_runtime.h>

#define DEV __device__ __forceinline__

typedef __attribute__((ext_vector_type(8))) __bf16 bf16x8;
typedef __attribute__((ext_vector_type(4))) float f32x4;
typedef __attribute__((ext_vector_type(8))) unsigned short ushort8;
typedef __attribute__((ext_vector_type(2))) unsigned short ushort2v;

DEV float sigmoidf_(float x){ return 1.0f/(1.0f + __expf(-x)); }
DEV float tanhf_(float x){
    x = fminf(15.0f, fmaxf(-15.0f, x));
    float e = __expf(2.0f*x);
    return (e - 1.0f)/(e + 1.0f);
}
DEV unsigned short f2bf(float f){
    unsigned u = __builtin_bit_cast(unsigned, f);
    unsigned r = (u + 0x7FFFu + ((u>>16)&1u)) >> 16;
    return (unsigned short)r;
}
DEV unsigned swz(unsigned byte){ return byte ^ (((byte>>9)&1u)<<5); }

// ---------- weight pack: [256co][128ci][9tap] f32 -> [(ci/32)*9+tap][256co][32ci] bf16 ----------
__global__ __launch_bounds__(256)
void wprep_kernel(const float* __restrict__ w, unsigned short* __restrict__ wpk)
{
    int idx = blockIdx.x*256 + threadIdx.x;
    if (idx >= 256*128*9) return;
    int co  = idx / (128*9);
    int rem = idx - co*(128*9);
    int ci  = rem / 9;
    int tap = rem - ci*9;
    int kchunk = (ci>>5)*9 + tap;
    wpk[(kchunk*256 + co)*32 + (ci&31)] = f2bf(w[idx]);
}

// ---------- input pack: concat(in0,in1) [b][128ci][1024pix] f32 -> [b][1024pix][128ci] bf16 ----------
__global__ __launch_bounds__(256)
void packin_kernel(const float* __restrict__ in0, const float* __restrict__ in1,
                   unsigned short* __restrict__ outp)
{
    const int b  = blockIdx.y;
    const int p0 = blockIdx.x * 64;
    const int t  = threadIdx.x;
    __shared__ float tile[128][65];
    for (int k=t;k<8192;k+=256){
        int ci = k>>6, pp = k&63;
        const float* s = (ci<64) ? in0 + (b*64+ci)*1024 : in1 + (b*64+ci-64)*1024;
        tile[ci][pp] = s[p0+pp];
    }
    __syncthreads();
    for (int k=t;k<4096;k+=256){
        int pp = k>>6, c2 = k&63;
        ushort2v v;
        v.x = f2bf(tile[c2*2][pp]);
        v.y = f2bf(tile[c2*2+1][pp]);
        *reinterpret_cast<ushort2v*>(outp + ((b*1024+p0+pp)*128) + c2*2) = v;
    }
}

// ---------- implicit-GEMM 3x3 conv via MFMA ----------
// inp: [16][1024pix][128ci] bf16 ; wpk: [36 kchunk][256 co][32] bf16 ; out: [16][256][1024] f32
__global__ __launch_bounds__(256)
void conv_mfma_kernel(const unsigned short* __restrict__ inp,
                      const unsigned short* __restrict__ wpk,
                      const float* __restrict__ bias,
                      float* __restrict__ out)
{
    const int b   = blockIdx.z;
    const int co0 = blockIdx.y * 64;
    const int r0  = blockIdx.x * 4;
    const int t   = threadIdx.x;
    const int l   = t & 63;
    const int wv  = t >> 6;     // wave id == local output row 0..3
    const int l15 = l & 15;
    const int lhi = l >> 4;

    __shared__ __align__(16) unsigned short in_t[7168];  // 224 rows x 32 ci (64B rows), swizzled

    f32x4 acc[4][2];
#pragma unroll
    for (int i=0;i<4;i++)
#pragma unroll
        for (int f=0;f<2;f++)
            acc[i][f] = (f32x4){0.f,0.f,0.f,0.f};

    for (int cic = 0; cic < 4; ++cic) {
        __syncthreads();
        for (int it = t; it < 816; it += 256) {       // 204 pixlin x 4 octs of 8 ci
            int pixlin = it >> 2, oct = it & 3;
            int rr = pixlin / 34;
            int cc = pixlin - rr*34;
            int gr = r0 + rr - 1, gc = cc - 1;
            ushort8 v = {};
            if ((unsigned)gr < 32u && (unsigned)gc < 32u)
                v = *reinterpret_cast<const ushort8*>(
                        inp + ((b*1024 + gr*32 + gc)*128) + cic*32 + oct*8);
            unsigned byte = swz((unsigned)(pixlin*64 + oct*16));
            *reinterpret_cast<ushort8*>(reinterpret_cast<char*>(in_t) + byte) = v;
        }
        __syncthreads();
#pragma unroll
        for (int tap = 0; tap < 9; ++tap) {
            const int ky = tap/3, kx = tap - 3*(tap/3);
            const unsigned short* wrow = wpk + ((cic*9 + tap)*256 + co0)*32;
            bf16x8 af[4];
#pragma unroll
            for (int i=0;i<4;i++)
                af[i] = *reinterpret_cast<const bf16x8*>(wrow + (i*16 + l15)*32 + lhi*8);
            bf16x8 bfr[2];
#pragma unroll
            for (int f=0;f<2;f++){
                int pixlin = (wv + ky)*34 + (f*16 + l15 + kx);
                unsigned byte = swz((unsigned)(pixlin*64 + lhi*16));
                bfr[f] = *reinterpret_cast<const bf16x8*>(
                             reinterpret_cast<const char*>(in_t) + byte);
            }
#pragma unroll
            for (int i=0;i<4;i++)
#pragma unroll
                for (int f=0;f<2;f++)
                    acc[i][f] = __builtin_amdgcn_mfma_f32_16x16x32_bf16(af[i], bfr[f], acc[i][f], 0, 0, 0);
        }
    }
    const int orow = r0 + wv;
#pragma unroll
    for (int i=0;i<4;i++){
        int cobase = co0 + i*16 + lhi*4;
#pragma unroll
        for (int f=0;f<2;f++){
            int col = orow*32 + f*16 + l15;
#pragma unroll
            for (int r=0;r<4;r++)
                out[(b*256 + cobase + r)*1024 + col] = acc[i][f][r] + bias[cobase+r];
        }
    }
}

// ---------- GN (per-channel over 1024 pixels) + first gate block ----------
__global__ __launch_bounds__(256)
void gn_gate1_kernel(const float* __restrict__ cc, const float* __restrict__ gnw,
                     const float* __restrict__ gnb, const float* __restrict__ c_in,
                     float* __restrict__ c_tmp, float* __restrict__ sig_co)
{
    const int ch = blockIdx.x;   // 0..63
    const int b  = blockIdx.y;   // 0..15
    const int t  = threadIdx.x;
    __shared__ float red[4][8];

    float v[4][4];
    float scale[4], shift[4];
#pragma unroll
    for (int g=0; g<4; g++) {
        const float* src = cc + (b*256 + g*64 + ch)*1024;
        float ls = 0.f, lq = 0.f;
#pragma unroll
        for (int k=0;k<4;k++){
            float x = src[t + 256*k];
            v[g][k] = x; ls += x; lq += x*x;
        }
#pragma unroll
        for (int off=32; off>0; off>>=1){ ls += __shfl_xor(ls, off); lq += __shfl_xor(lq, off); }
        if ((t & 63) == 0){ red[t>>6][g] = ls; red[t>>6][4+g] = lq; }
    }
    __syncthreads();
#pragma unroll
    for (int g=0; g<4; g++) {
        float s = red[0][g]+red[1][g]+red[2][g]+red[3][g];
        float q = red[0][4+g]+red[1][4+g]+red[2][4+g]+red[3][4+g];
        float mu  = s * (1.0f/1024.0f);
        float var = q * (1.0f/1024.0f) - mu*mu;
        float rs  = rsqrtf(var + 1e-5f);
        float gw  = gnw[g*64+ch];
        scale[g] = rs*gw;
        shift[g] = gnb[g*64+ch] - mu*rs*gw;
    }
    const float* cp = c_in   + (b*64+ch)*1024;
    float* ct = c_tmp  + (b*64+ch)*1024;
    float* so = sig_co + (b*64+ch)*1024;
#pragma unroll
    for (int k=0;k<4;k++){
        int p = t + 256*k;
        float ni = v[0][k]*scale[0] + shift[0];
        float nf = v[1][k]*scale[1] + shift[1];
        float no = v[2][k]*scale[2] + shift[2];
        float ng = v[3][k]*scale[3] + shift[3];
        ct[p] = sigmoidf_(nf)*cp[p] + sigmoidf_(ni)*tanhf_(ng);
        so[p] = sigmoidf_(no);
    }
}

// ---------- GN + second (long) gate block ----------
__global__ __launch_bounds__(256)
void gn_gate2_kernel(const float* __restrict__ cc, const float* __restrict__ gnw,
                     const float* __restrict__ gnb, const float* __restrict__ lc_in,
                     const float* __restrict__ sig_co,
                     float* __restrict__ out_lc, float* __restrict__ out_c,
                     float* __restrict__ h_mid)
{
    const int ch = blockIdx.x;
    const int b  = blockIdx.y;
    const int t  = threadIdx.x;
    __shared__ float red[4][8];

    float v[4][4];
    float scale[4], shift[4];
#pragma unroll
    for (int g=0; g<4; g++) {
        const float* src = cc + (b*256 + g*64 + ch)*1024;
        float ls = 0.f, lq = 0.f;
#pragma unroll
        for (int k=0;k<4;k++){
            float x = src[t + 256*k];
            v[g][k] = x; ls += x; lq += x*x;
        }
#pragma unroll
        for (int off=32; off>0; off>>=1){ ls += __shfl_xor(ls, off); lq += __shfl_xor(lq, off); }
        if ((t & 63) == 0){ red[t>>6][g] = ls; red[t>>6][4+g] = lq; }
    }
    __syncthreads();
#pragma unroll
    for (int g=0; g<4; g++) {
        float s = red[0][g]+red[1][g]+red[2][g]+red[3][g];
        float q = red[0][4+g]+red[1][4+g]+red[2][4+g]+red[3][4+g];
        float mu  = s * (1.0f/1024.0f);
        float var = q * (1.0f/1024.0f) - mu*mu;
        float rs  = rsqrtf(var + 1e-5f);
        float gw  = gnw[g*64+ch];
        scale[g] = rs*gw;
        shift[g] = gnb[g*64+ch] - mu*rs*gw;
    }
    const float* lp = lc_in  + (b*64+ch)*1024;
    const float* so = sig_co + (b*64+ch)*1024;
    float* olc = out_lc + (b*64+ch)*1024;
    float* oc  = out_c  + (b*64+ch)*1024;
    float* ohm = h_mid  + (b*64+ch)*1024;
#pragma unroll
    for (int k=0;k<4;k++){
        int p = t + 256*k;
        float ni = v[0][k]*scale[0] + shift[0];
        float nf = v[1][k]*scale[1] + shift[1];
        float no = v[2][k]*scale[2] + shift[2];
        float ng = v[3][k]*scale[3] + shift[3];
        float lcn = sigmoidf_(nf)*lp[p] + sigmoidf_(ni)*tanhf_(ng);
        float cf  = sigmoidf_(no)*tanhf_(lcn);
        olc[p] = lcn;
        oc[p]  = cf;
        ohm[p] = so[p]*tanhf_(cf);
    }
}

// ---------- fused 1x1 projections: Q,Kh,Vh from h_mid; Km,Vm from m ----------
__global__ __launch_bounds__(256)
void proj_kernel(const float* __restrict__ h_mid, const float* __restrict__ m_in,
                 const float* __restrict__ wq, const float* __restrict__ bq,
                 const float* __restrict__ wk, const float* __restrict__ bk,
                 const float* __restrict__ wk2, const float* __restrict__ bk2,
                 const float* __restrict__ wv, const float* __restrict__ bv,
                 const float* __restrict__ wv2, const float* __restrict__ bv2,
                 float* __restrict__ Qo, float* __restrict__ Kho, float* __restrict__ Kmo,
                 float* __restrict__ Vho, float* __restrict__ Vmo)
{
    const int b  = blockIdx.y;
    const int p0 = blockIdx.x * 64;
    const int t  = threadIdx.x;
    __shared__ float hs[64*64];
    __shared__ float ms[64*64];
    for (int k=t;k<4096;k+=256){
        int cch = k>>6, pp = k&63;
        hs[k] = h_mid[(b*64+cch)*1024 + p0+pp];
        ms[k] = m_in [(b*64+cch)*1024 + p0+pp];
    }
    __syncthreads();
    const int p = t & 63;
    const int g = __builtin_amdgcn_readfirstlane(t >> 6);   // wave-uniform 0..3

    {
        float aq[8], ak[8], av[16];
#pragma unroll
        for (int j=0;j<8;j++){ aq[j]=bq[g*8+j]; ak[j]=bk[g*8+j]; }
#pragma unroll
        for (int j=0;j<16;j++) av[j]=bv[g*16+j];
        for (int cc=0;cc<64;cc++){
            float x = hs[cc*64+p];
#pragma unroll
            for (int j=0;j<8;j++)  aq[j] = fmaf(wq[(g*8+j)*64+cc],  x, aq[j]);
#pragma unroll
            for (int j=0;j<8;j++)  ak[j] = fmaf(wk[(g*8+j)*64+cc],  x, ak[j]);
#pragma unroll
            for (int j=0;j<16;j++) av[j] = fmaf(wv[(g*16+j)*64+cc], x, av[j]);
        }
#pragma unroll
        for (int j=0;j<8;j++){
            Qo [(b*32 + g*8+j)*1024 + p0+p] = aq[j];
            Kho[(b*32 + g*8+j)*1024 + p0+p] = ak[j];
        }
#pragma unroll
        for (int j=0;j<16;j++)
            Vho[(b*64 + g*16+j)*1024 + p0+p] = av[j];
    }
    {
        float ak[8], av[16];
#pragma unroll
        for (int j=0;j<8;j++)  ak[j]=bk2[g*8+j];
#pragma unroll
        for (int j=0;j<16;j++) av[j]=bv2[g*16+j];
        for (int cc=0;cc<64;cc++){
            float x = ms[cc*64+p];
#pragma unroll
            for (int j=0;j<8;j++)  ak[j] = fmaf(wk2[(g*8+j)*64+cc],  x, ak[j]);
#pragma unroll
            for (int j=0;j<16;j++) av[j] = fmaf(wv2[(g*16+j)*64+cc], x, av[j]);
        }
#pragma unroll
        for (int j=0;j<8;j++)
            Kmo[(b*32 + g*8+j)*1024 + p0+p] = ak[j];
#pragma unroll
        for (int j=0;j<16;j++)
            Vmo[(b*64 + g*16+j)*1024 + p0+p] = av[j];
    }
}

// ---------- dual flash attention: softmax(Q^T K) V for (Kh,Vh) and (Km,Vm) ----------
__global__ __launch_bounds__(512)
void attn_kernel(const float* __restrict__ Qg,
                 const float* __restrict__ K1, const float* __restrict__ V1,
                 const float* __restrict__ K2, const float* __restrict__ V2,
                 float* __restrict__ Z1, float* __restrict__ Z2)
{
    const int b   = blockIdx.y;
    const int p0  = blockIdx.x * 64;
    const int t   = threadIdx.x;
    const int p   = t & 63;
    const int sub = __builtin_amdgcn_readfirstlane(t >> 6);  // 0..7

    __shared__ __align__(16) float Kt[32*128];
    __shared__ __align__(16) float Vt[64*128];
    __shared__ __align__(16) float Pt[128*64];
    __shared__ float redm[8][64];
    __shared__ float reds[8][64];

    float qreg[32];
#pragma unroll
    for (int a=0;a<32;a++) qreg[a] = Qg[(b*32+a)*1024 + p0 + p];

    for (int pass=0; pass<2; pass++){
        const float* Kg = pass ? K2 : K1;
        const float* Vg = pass ? V2 : V1;
        float*       Zg = pass ? Z2 : Z1;
        float m_run = -1e30f, l_run = 0.0f;
        float acc[8];
#pragma unroll
        for (int j=0;j<8;j++) acc[j]=0.f;

        for (int q0=0;q0<1024;q0+=128){
            __syncthreads();
            for (int k=t;k<32*128;k+=512) Kt[k] = Kg[(b*32 + (k>>7))*1024 + q0 + (k&127)];
            for (int k=t;k<64*128;k+=512) Vt[k] = Vg[(b*64 + (k>>7))*1024 + q0 + (k&127)];
            __syncthreads();

            float s[16];
#pragma unroll
            for (int j=0;j<16;j++) s[j]=0.f;
            for (int a=0;a<32;a++){
                float qa = qreg[a];
                const float4* krow = reinterpret_cast<const float4*>(Kt + a*128 + sub*16);
#pragma unroll
                for (int j4=0;j4<4;j4++){
                    float4 kv = krow[j4];
                    s[j4*4+0] = fmaf(qa, kv.x, s[j4*4+0]);
                    s[j4*4+1] = fmaf(qa, kv.y, s[j4*4+1]);
                    s[j4*4+2] = fmaf(qa, kv.z, s[j4*4+2]);
                    s[j4*4+3] = fmaf(qa, kv.w, s[j4*4+3]);
                }
            }
            float lm = s[0];
#pragma unroll
            for (int j=1;j<16;j++) lm = fmaxf(lm, s[j]);
            redm[sub][p] = lm;
            __syncthreads();
            float chm = redm[0][p];
#pragma unroll
            for (int ss=1;ss<8;ss++) chm = fmaxf(chm, redm[ss][p]);
            float m_new = fmaxf(m_run, chm);
            float f = __expf(m_run - m_new);
            __syncthreads();
            float lsum = 0.f;
#pragma unroll
            for (int j=0;j<16;j++){
                float pv = __expf(s[j] - m_new);
                lsum += pv;
                Pt[(sub*16+j)*64 + p] = pv;
            }
            reds[sub][p] = lsum;
            __syncthreads();
            float chs = 0.f;
#pragma unroll
            for (int ss=0;ss<8;ss++) chs += reds[ss][p];
            l_run = l_run*f + chs;
            m_run = m_new;
#pragma unroll
            for (int j=0;j<8;j++) acc[j] *= f;
#pragma unroll 4
            for (int qq=0;qq<128;qq++){
                float pv = Pt[qq*64 + p];
#pragma unroll
                for (int j=0;j<8;j++)
                    acc[j] = fmaf(pv, Vt[(sub*8+j)*128 + qq], acc[j]);
            }
        }
        float rl = 1.0f / l_run;
#pragma unroll
        for (int j=0;j<8;j++)
            Zg[(b*64 + sub*8+j)*1024 + p0 + p] = acc[j]*rl;
    }
}

// ---------- final: Z = wz*[Zh;Zm]+bz, comb = wm*[Z;h_mid]+bm, memory gates ----------
__global__ __launch_bounds__(256)
void final_kernel(const float* __restrict__ Zh, const float* __restrict__ Zm,
                  const float* __restrict__ h_mid, const float* __restrict__ m_in,
                  const float* __restrict__ wz, const float* __restrict__ bz,
                  const float* __restrict__ wm, const float* __restrict__ bm,
                  float* __restrict__ out_h, float* __restrict__ out_m)
{
    const int b  = blockIdx.y;
    const int p0 = blockIdx.x * 64;
    const int t  = threadIdx.x;
    const int p  = t & 63;
    const int g  = __builtin_amdgcn_readfirstlane(t >> 6);

    __shared__ float Zin[128*64];
    __shared__ float hs[64*64];
    __shared__ float Zmid[128*64];

    for (int k=t;k<8192;k+=256){
        int cch = k>>6, pp = k&63;
        Zin[k] = (cch<64) ? Zh[(b*64+cch)*1024 + p0+pp]
                          : Zm[(b*64+cch-64)*1024 + p0+pp];
    }
    for (int k=t;k<4096;k+=256){
        int cch = k>>6, pp = k&63;
        hs[k] = h_mid[(b*64+cch)*1024 + p0+pp];
    }
    __syncthreads();

    {
        float za[32];
#pragma unroll
        for (int j=0;j<32;j++) za[j] = bz[g*32+j];
        for (int k=0;k<128;k++){
            float x = Zin[k*64+p];
#pragma unroll
            for (int j=0;j<32;j++) za[j] = fmaf(wz[(g*32+j)*128 + k], x, za[j]);
        }
#pragma unroll
        for (int j=0;j<32;j++) Zmid[(g*32+j)*64 + p] = za[j];
    }
    __syncthreads();
    {
        float ao[16], ag[16], ai[16];
#pragma unroll
        for (int j=0;j<16;j++){
            ao[j]=bm[g*16+j]; ag[j]=bm[64+g*16+j]; ai[j]=bm[128+g*16+j];
        }
        for (int k=0;k<128;k++){
            float x = Zmid[k*64+p];
#pragma unroll
            for (int j=0;j<16;j++){
                ao[j] = fmaf(wm[(g*16+j)*192 + k],      x, ao[j]);
                ag[j] = fmaf(wm[(64+g*16+j)*192 + k],   x, ag[j]);
                ai[j] = fmaf(wm[(128+g*16+j)*192 + k],  x, ai[j]);
            }
        }
        for (int k=0;k<64;k++){
            float x = hs[k*64+p];
#pragma unroll
            for (int j=0;j<16;j++){
                ao[j] = fmaf(wm[(g*16+j)*192 + 128 + k],     x, ao[j]);
                ag[j] = fmaf(wm[(64+g*16+j)*192 + 128 + k],  x, ag[j]);
                ai[j] = fmaf(wm[(128+g*16+j)*192 + 128 + k], x, ai[j]);
            }
        }
#pragma unroll
        for (int j=0;j<16;j++){
            int ch = g*16+j;
            float mi = sigmoidf_(ai[j]);
            float mg = tanhf_(ag[j]);
            float mv = m_in[(b*64+ch)*1024 + p0+p];
            float mn = (1.0f - mi)*mv + mi*mg;
            out_m[(b*64+ch)*1024 + p0+p] = mn;
            out_h[(b*64+ch)*1024 + p0+p] = sigmoidf_(ao[j])*mn;
        }
    }
}

extern "C" void kernel_launch(void* const* d_in, const int* in_sizes, int n_in,
                              void* d_out, int out_size, void* d_ws, size_t ws_size,
                              hipStream_t stream)
{
    const float* x      = (const float*)d_in[0];
    const float* h      = (const float*)d_in[1];
    const float* c      = (const float*)d_in[2];
    const float* m      = (const float*)d_in[3];
    const float* lc     = (const float*)d_in[4];
    const float* conv_w = (const float*)d_in[5];
    const float* conv_b = (const float*)d_in[6];
    const float* gn1_w  = (const float*)d_in[7];
    const float* gn1_b  = (const float*)d_in[8];
    const float* convL_w= (const float*)d_in[9];
    const float* convL_b= (const float*)d_in[10];
    const float* gn2_w  = (const float*)d_in[11];
    const float* gn2_b  = (const float*)d_in[12];
    const float* wq  = (const float*)d_in[13];
    const float* bq  = (const float*)d_in[14];
    const float* wk  = (const float*)d_in[15];
    const float* bk  = (const float*)d_in[16];
    const float* wk2 = (const float*)d_in[17];
    const float* bk2 = (const float*)d_in[18];
    const float* wv  = (const float*)d_in[19];
    const float* bv  = (const float*)d_in[20];
    const float* wv2 = (const float*)d_in[21];
    const float* bv2 = (const float*)d_in[22];
    const float* wz  = (const float*)d_in[23];
    const float* bz  = (const float*)d_in[24];
    const float* wmw = (const float*)d_in[25];
    const float* bm  = (const float*)d_in[26];

    float* out = (float*)d_out;
    float* F = (float*)d_ws;
    // workspace layout (f32 units), ~53.6 MB total
    float* cc_raw = F;                         // 4,194,304
    float* c_tmp  = F + 4194304;               // 1,048,576
    float* sig_co = F + 5242880;               // 1,048,576
    float* h_mid  = F + 6291456;               // 1,048,576
    float* Qw     = F + 7340032;               //   524,288
    float* Khw    = F + 7864320;
    float* Kmw    = F + 8388608;
    float* Vhw    = F + 8912896;               // 1,048,576
    float* Vmw    = F + 9961472;
    float* Zh     = F + 11010048;              // 1,048,576 (aliases buf1, dead by then)
    float* Zm     = F + 12058624;              // 1,048,576 (aliases buf2)
    unsigned short* buf1 = (unsigned short*)(F + 11010048);  // 16*1024*128 bf16
    unsigned short* buf2 = (unsigned short*)(F + 12058624);
    unsigned short* wpk1 = (unsigned short*)(F + 13107200);  // 36*256*32 bf16
    unsigned short* wpk2 = (unsigned short*)(F + 13254656);

    dim3 blk256(256);
    wprep_kernel<<<dim3(1152), blk256, 0, stream>>>(conv_w,  wpk1);
    wprep_kernel<<<dim3(1152), blk256, 0, stream>>>(convL_w, wpk2);
    packin_kernel<<<dim3(16,16), blk256, 0, stream>>>(x, h, buf1);

    dim3 cgrid(8, 4, 16);
    conv_mfma_kernel<<<cgrid, blk256, 0, stream>>>(buf1, wpk1, conv_b, cc_raw);
    gn_gate1_kernel<<<dim3(64,16), blk256, 0, stream>>>(cc_raw, gn1_w, gn1_b, c, c_tmp, sig_co);
    packin_kernel<<<dim3(16,16), blk256, 0, stream>>>(h, c_tmp, buf2);
    conv_mfma_kernel<<<cgrid, blk256, 0, stream>>>(buf2, wpk2, convL_b, cc_raw);
    gn_gate2_kernel<<<dim3(64,16), blk256, 0, stream>>>(cc_raw, gn2_w, gn2_b, lc, sig_co,
                                                        out + 3*1048576 /*lc_next*/,
                                                        out + 1*1048576 /*c_next*/,
                                                        h_mid);
    proj_kernel<<<dim3(16,16), blk256, 0, stream>>>(h_mid, m, wq,bq, wk,bk, wk2,bk2,
                                                    wv,bv, wv2,bv2, Qw, Khw, Kmw, Vhw, Vmw);
    attn_kernel<<<dim3(16,16), dim3(512), 0, stream>>>(Qw, Khw, Vhw, Kmw, Vmw, Zh, Zm);
    final_kernel<<<dim3(16,16), blk256, 0, stream>>>(Zh, Zm, h_mid, m, wz, bz, wmw, bm,
                                                     out /*h_next*/, out + 2*1048576 /*m_next*/);
    (void)in_sizes; (void)n_in; (void)out_size; (void)ws_size;
}

// Round 3
// 301.782 us; speedup vs baseline: 3.4984x; 1.7946x over previous
//
#include <hip/hip_runtime.h>

#define DEV __device__ __forceinline__

typedef __attribute__((ext_vector_type(8))) __bf16 bf16x8;
typedef __attribute__((ext_vector_type(4))) float f32x4;
typedef __attribute__((ext_vector_type(8))) unsigned short ushort8;
typedef __attribute__((ext_vector_type(2))) unsigned short ushort2v;

DEV float sigmoidf_(float x){ return 1.0f/(1.0f + __expf(-x)); }
DEV float tanhf_(float x){
    x = fminf(15.0f, fmaxf(-15.0f, x));
    float e = __expf(2.0f*x);
    return (e - 1.0f)/(e + 1.0f);
}
DEV unsigned short f2bf(float f){
    unsigned u = __builtin_bit_cast(unsigned, f);
    unsigned r = (u + 0x7FFFu + ((u>>16)&1u)) >> 16;
    return (unsigned short)r;
}
DEV unsigned swz(unsigned byte){ return byte ^ (((byte>>9)&1u)<<5); }

// ---------- weight pack: [256co][128ci][9tap] f32 -> [(ci/32)*9+tap][256co][32ci] bf16 ----------
__global__ __launch_bounds__(256)
void wprep_kernel(const float* __restrict__ w, unsigned short* __restrict__ wpk)
{
    int idx = blockIdx.x*256 + threadIdx.x;
    if (idx >= 256*128*9) return;
    int co  = idx / (128*9);
    int rem = idx - co*(128*9);
    int ci  = rem / 9;
    int tap = rem - ci*9;
    int kchunk = (ci>>5)*9 + tap;
    wpk[(kchunk*256 + co)*32 + (ci&31)] = f2bf(w[idx]);
}

// ---------- input pack: concat(in0,in1) [b][128ci][1024pix] f32 -> [b][1024pix][128ci] bf16 ----------
__global__ __launch_bounds__(256)
void packin_kernel(const float* __restrict__ in0, const float* __restrict__ in1,
                   unsigned short* __restrict__ outp)
{
    const int b  = blockIdx.y;
    const int p0 = blockIdx.x * 64;
    const int t  = threadIdx.x;
    __shared__ float tile[128][65];
    for (int k=t;k<8192;k+=256){
        int ci = k>>6, pp = k&63;
        const float* s = (ci<64) ? in0 + (b*64+ci)*1024 : in1 + (b*64+ci-64)*1024;
        tile[ci][pp] = s[p0+pp];
    }
    __syncthreads();
    for (int k=t;k<4096;k+=256){
        int pp = k>>6, c2 = k&63;
        ushort2v v;
        v.x = f2bf(tile[c2*2][pp]);
        v.y = f2bf(tile[c2*2+1][pp]);
        *reinterpret_cast<ushort2v*>(outp + ((b*1024+p0+pp)*128) + c2*2) = v;
    }
}

// ---------- implicit-GEMM 3x3 conv via MFMA ----------
__global__ __launch_bounds__(256)
void conv_mfma_kernel(const unsigned short* __restrict__ inp,
                      const unsigned short* __restrict__ wpk,
                      const float* __restrict__ bias,
                      float* __restrict__ out)
{
    const int b   = blockIdx.z;
    const int co0 = blockIdx.y * 64;
    const int r0  = blockIdx.x * 4;
    const int t   = threadIdx.x;
    const int l   = t & 63;
    const int wv  = t >> 6;
    const int l15 = l & 15;
    const int lhi = l >> 4;

    __shared__ __align__(16) unsigned short in_t[7168];

    f32x4 acc[4][2];
#pragma unroll
    for (int i=0;i<4;i++)
#pragma unroll
        for (int f=0;f<2;f++)
            acc[i][f] = (f32x4){0.f,0.f,0.f,0.f};

    for (int cic = 0; cic < 4; ++cic) {
        __syncthreads();
        for (int it = t; it < 816; it += 256) {
            int pixlin = it >> 2, oct = it & 3;
            int rr = pixlin / 34;
            int cc = pixlin - rr*34;
            int gr = r0 + rr - 1, gc = cc - 1;
            ushort8 v = {};
            if ((unsigned)gr < 32u && (unsigned)gc < 32u)
                v = *reinterpret_cast<const ushort8*>(
                        inp + ((b*1024 + gr*32 + gc)*128) + cic*32 + oct*8);
            unsigned byte = swz((unsigned)(pixlin*64 + oct*16));
            *reinterpret_cast<ushort8*>(reinterpret_cast<char*>(in_t) + byte) = v;
        }
        __syncthreads();
#pragma unroll
        for (int tap = 0; tap < 9; ++tap) {
            const int ky = tap/3, kx = tap - 3*(tap/3);
            const unsigned short* wrow = wpk + ((cic*9 + tap)*256 + co0)*32;
            bf16x8 af[4];
#pragma unroll
            for (int i=0;i<4;i++)
                af[i] = *reinterpret_cast<const bf16x8*>(wrow + (i*16 + l15)*32 + lhi*8);
            bf16x8 bfr[2];
#pragma unroll
            for (int f=0;f<2;f++){
                int pixlin = (wv + ky)*34 + (f*16 + l15 + kx);
                unsigned byte = swz((unsigned)(pixlin*64 + lhi*16));
                bfr[f] = *reinterpret_cast<const bf16x8*>(
                             reinterpret_cast<const char*>(in_t) + byte);
            }
#pragma unroll
            for (int i=0;i<4;i++)
#pragma unroll
                for (int f=0;f<2;f++)
                    acc[i][f] = __builtin_amdgcn_mfma_f32_16x16x32_bf16(af[i], bfr[f], acc[i][f], 0, 0, 0);
        }
    }
    const int orow = r0 + wv;
#pragma unroll
    for (int i=0;i<4;i++){
        int cobase = co0 + i*16 + lhi*4;
#pragma unroll
        for (int f=0;f<2;f++){
            int col = orow*32 + f*16 + l15;
#pragma unroll
            for (int r=0;r<4;r++)
                out[(b*256 + cobase + r)*1024 + col] = acc[i][f][r] + bias[cobase+r];
        }
    }
}

// ---------- GN + first gate block ----------
__global__ __launch_bounds__(256)
void gn_gate1_kernel(const float* __restrict__ cc, const float* __restrict__ gnw,
                     const float* __restrict__ gnb, const float* __restrict__ c_in,
                     float* __restrict__ c_tmp, float* __restrict__ sig_co)
{
    const int ch = blockIdx.x;
    const int b  = blockIdx.y;
    const int t  = threadIdx.x;
    __shared__ float red[4][8];

    float v[4][4];
    float scale[4], shift[4];
#pragma unroll
    for (int g=0; g<4; g++) {
        const float* src = cc + (b*256 + g*64 + ch)*1024;
        float ls = 0.f, lq = 0.f;
#pragma unroll
        for (int k=0;k<4;k++){
            float x = src[t + 256*k];
            v[g][k] = x; ls += x; lq += x*x;
        }
#pragma unroll
        for (int off=32; off>0; off>>=1){ ls += __shfl_xor(ls, off); lq += __shfl_xor(lq, off); }
        if ((t & 63) == 0){ red[t>>6][g] = ls; red[t>>6][4+g] = lq; }
    }
    __syncthreads();
#pragma unroll
    for (int g=0; g<4; g++) {
        float s = red[0][g]+red[1][g]+red[2][g]+red[3][g];
        float q = red[0][4+g]+red[1][4+g]+red[2][4+g]+red[3][4+g];
        float mu  = s * (1.0f/1024.0f);
        float var = q * (1.0f/1024.0f) - mu*mu;
        float rs  = rsqrtf(var + 1e-5f);
        float gw  = gnw[g*64+ch];
        scale[g] = rs*gw;
        shift[g] = gnb[g*64+ch] - mu*rs*gw;
    }
    const float* cp = c_in   + (b*64+ch)*1024;
    float* ct = c_tmp  + (b*64+ch)*1024;
    float* so = sig_co + (b*64+ch)*1024;
#pragma unroll
    for (int k=0;k<4;k++){
        int p = t + 256*k;
        float ni = v[0][k]*scale[0] + shift[0];
        float nf = v[1][k]*scale[1] + shift[1];
        float no = v[2][k]*scale[2] + shift[2];
        float ng = v[3][k]*scale[3] + shift[3];
        ct[p] = sigmoidf_(nf)*cp[p] + sigmoidf_(ni)*tanhf_(ng);
        so[p] = sigmoidf_(no);
    }
}

// ---------- GN + second (long) gate block ----------
__global__ __launch_bounds__(256)
void gn_gate2_kernel(const float* __restrict__ cc, const float* __restrict__ gnw,
                     const float* __restrict__ gnb, const float* __restrict__ lc_in,
                     const float* __restrict__ sig_co,
                     float* __restrict__ out_lc, float* __restrict__ out_c,
                     float* __restrict__ h_mid)
{
    const int ch = blockIdx.x;
    const int b  = blockIdx.y;
    const int t  = threadIdx.x;
    __shared__ float red[4][8];

    float v[4][4];
    float scale[4], shift[4];
#pragma unroll
    for (int g=0; g<4; g++) {
        const float* src = cc + (b*256 + g*64 + ch)*1024;
        float ls = 0.f, lq = 0.f;
#pragma unroll
        for (int k=0;k<4;k++){
            float x = src[t + 256*k];
            v[g][k] = x; ls += x; lq += x*x;
        }
#pragma unroll
        for (int off=32; off>0; off>>=1){ ls += __shfl_xor(ls, off); lq += __shfl_xor(lq, off); }
        if ((t & 63) == 0){ red[t>>6][g] = ls; red[t>>6][4+g] = lq; }
    }
    __syncthreads();
#pragma unroll
    for (int g=0; g<4; g++) {
        float s = red[0][g]+red[1][g]+red[2][g]+red[3][g];
        float q = red[0][4+g]+red[1][4+g]+red[2][4+g]+red[3][4+g];
        float mu  = s * (1.0f/1024.0f);
        float var = q * (1.0f/1024.0f) - mu*mu;
        float rs  = rsqrtf(var + 1e-5f);
        float gw  = gnw[g*64+ch];
        scale[g] = rs*gw;
        shift[g] = gnb[g*64+ch] - mu*rs*gw;
    }
    const float* lp = lc_in  + (b*64+ch)*1024;
    const float* so = sig_co + (b*64+ch)*1024;
    float* olc = out_lc + (b*64+ch)*1024;
    float* oc  = out_c  + (b*64+ch)*1024;
    float* ohm = h_mid  + (b*64+ch)*1024;
#pragma unroll
    for (int k=0;k<4;k++){
        int p = t + 256*k;
        float ni = v[0][k]*scale[0] + shift[0];
        float nf = v[1][k]*scale[1] + shift[1];
        float no = v[2][k]*scale[2] + shift[2];
        float ng = v[3][k]*scale[3] + shift[3];
        float lcn = sigmoidf_(nf)*lp[p] + sigmoidf_(ni)*tanhf_(ng);
        float cf  = sigmoidf_(no)*tanhf_(lcn);
        olc[p] = lcn;
        oc[p]  = cf;
        ohm[p] = so[p]*tanhf_(cf);
    }
}

// ---------- fused 1x1 projections -> bf16 MFMA layouts ----------
// Qb/Khb/Kmb: [b][1024pix][32a] bf16 ; Vhb/Vmb: [b][64c][1024pix] bf16
__global__ __launch_bounds__(256)
void proj_kernel(const float* __restrict__ h_mid, const float* __restrict__ m_in,
                 const float* __restrict__ wq, const float* __restrict__ bq,
                 const float* __restrict__ wk, const float* __restrict__ bk,
                 const float* __restrict__ wk2, const float* __restrict__ bk2,
                 const float* __restrict__ wv, const float* __restrict__ bv,
                 const float* __restrict__ wv2, const float* __restrict__ bv2,
                 unsigned short* __restrict__ Qb, unsigned short* __restrict__ Khb,
                 unsigned short* __restrict__ Kmb,
                 unsigned short* __restrict__ Vhb, unsigned short* __restrict__ Vmb)
{
    const int b  = blockIdx.y;
    const int p0 = blockIdx.x * 64;
    const int t  = threadIdx.x;
    __shared__ float hs[64*64];
    __shared__ float ms[64*64];
    for (int k=t;k<4096;k+=256){
        int cch = k>>6, pp = k&63;
        hs[k] = h_mid[(b*64+cch)*1024 + p0+pp];
        ms[k] = m_in [(b*64+cch)*1024 + p0+pp];
    }
    __syncthreads();
    const int p = t & 63;
    const int g = __builtin_amdgcn_readfirstlane(t >> 6);

    {
        float aq[8], ak[8], av[16];
#pragma unroll
        for (int j=0;j<8;j++){ aq[j]=bq[g*8+j]; ak[j]=bk[g*8+j]; }
#pragma unroll
        for (int j=0;j<16;j++) av[j]=bv[g*16+j];
        for (int cc=0;cc<64;cc++){
            float x = hs[cc*64+p];
#pragma unroll
            for (int j=0;j<8;j++)  aq[j] = fmaf(wq[(g*8+j)*64+cc],  x, aq[j]);
#pragma unroll
            for (int j=0;j<8;j++)  ak[j] = fmaf(wk[(g*8+j)*64+cc],  x, ak[j]);
#pragma unroll
            for (int j=0;j<16;j++) av[j] = fmaf(wv[(g*16+j)*64+cc], x, av[j]);
        }
        ushort8 vq, vk;
#pragma unroll
        for (int j=0;j<8;j++){ vq[j]=f2bf(aq[j]); vk[j]=f2bf(ak[j]); }
        *reinterpret_cast<ushort8*>(Qb  + (size_t)(b*1024+p0+p)*32 + g*8) = vq;
        *reinterpret_cast<ushort8*>(Khb + (size_t)(b*1024+p0+p)*32 + g*8) = vk;
#pragma unroll
        for (int j=0;j<16;j++)
            Vhb[(size_t)(b*64 + g*16+j)*1024 + p0+p] = f2bf(av[j]);
    }
    {
        float ak[8], av[16];
#pragma unroll
        for (int j=0;j<8;j++)  ak[j]=bk2[g*8+j];
#pragma unroll
        for (int j=0;j<16;j++) av[j]=bv2[g*16+j];
        for (int cc=0;cc<64;cc++){
            float x = ms[cc*64+p];
#pragma unroll
            for (int j=0;j<8;j++)  ak[j] = fmaf(wk2[(g*8+j)*64+cc],  x, ak[j]);
#pragma unroll
            for (int j=0;j<16;j++) av[j] = fmaf(wv2[(g*16+j)*64+cc], x, av[j]);
        }
        ushort8 vk;
#pragma unroll
        for (int j=0;j<8;j++) vk[j]=f2bf(ak[j]);
        *reinterpret_cast<ushort8*>(Kmb + (size_t)(b*1024+p0+p)*32 + g*8) = vk;
#pragma unroll
        for (int j=0;j<16;j++)
            Vmb[(size_t)(b*64 + g*16+j)*1024 + p0+p] = f2bf(av[j]);
    }
}

// ---------- MFMA flash attention: ZT[p][c] = softmax(Qt K) V^T per batch ----------
// Q/K: [b][1024][32] bf16, V: [b][64][1024] bf16, ZT: [b][1024][64] f32
__global__ __launch_bounds__(256)
void attn_mfma_kernel(const unsigned short* __restrict__ Qb,
                      const unsigned short* __restrict__ Kh,
                      const unsigned short* __restrict__ Km,
                      const unsigned short* __restrict__ Vh,
                      const unsigned short* __restrict__ Vm,
                      float* __restrict__ Z1T, float* __restrict__ Z2T)
{
    const int bid   = blockIdx.x;          // 512 blocks
    const int xcd   = bid & 7;
    const int slot  = bid >> 3;            // 0..63
    const int b     = xcd*2 + (slot>>5);   // 2 batches per XCD (L2 locality)
    const int pass  = (slot>>4) & 1;
    const int p0    = (slot & 15) * 64;
    const int t   = threadIdx.x;
    const int l   = t & 63;
    const int w   = t >> 6;
    const int l15 = l & 15, g = l >> 4;

    __shared__ __align__(16) unsigned short Kt[64*40];  // [64q][32a + 8 pad] (80B rows)
    __shared__ __align__(16) unsigned short Vt[64*64];  // [64c][64q], XOR-swizzled
    __shared__ __align__(16) unsigned short Pt[64*64];  // [64p][64q], XOR-swizzled, per-wave rows

    const unsigned short* Kg = pass ? Km : Kh;
    const unsigned short* Vg = pass ? Vm : Vh;
    float* ZT = pass ? Z2T : Z1T;

    // Q A-fragment (persistent): A[m=p][k=a], lane: p=w*16+l15, a=g*8..+7
    const bf16x8 qa = *reinterpret_cast<const bf16x8*>(
        Qb + (size_t)(b*1024 + p0 + w*16 + l15)*32 + g*8);

    float m_run[4], l_run[4];
    f32x4 acc[4];
#pragma unroll
    for (int r=0;r<4;r++){ m_run[r] = -1e30f; l_run[r] = 0.f; }
#pragma unroll
    for (int cf=0;cf<4;cf++) acc[cf] = (f32x4){0.f,0.f,0.f,0.f};

    for (int q0=0; q0<1024; q0+=64){
        __syncthreads();
        {   // stage K tile: 64 rows x 4 octs (16B each) — fully coalesced
            int row = t>>2, oct = t&3;
            ushort8 kv = *reinterpret_cast<const ushort8*>(
                Kg + (size_t)(b*1024 + q0 + row)*32 + oct*8);
            *reinterpret_cast<ushort8*>(Kt + row*40 + oct*8) = kv;
        }
        for (int it=t; it<512; it+=256){  // stage V tile [64c][64q], swizzled
            int row = it>>3, oct = it&7;
            ushort8 vv = *reinterpret_cast<const ushort8*>(
                Vg + (size_t)(b*64 + row)*1024 + q0 + oct*8);
            unsigned byte = (unsigned)(row*128) + (((unsigned)oct*16) ^ ((unsigned)(row&7)<<4));
            *reinterpret_cast<ushort8*>(reinterpret_cast<char*>(Vt) + byte) = vv;
        }
        __syncthreads();

        // S[16p][64q] per wave: 4 MFMAs (K=32 exactly)
        f32x4 s[4];
#pragma unroll
        for (int qf=0; qf<4; qf++){
            const bf16x8 kb = *reinterpret_cast<const bf16x8*>(
                reinterpret_cast<const char*>(Kt) + (qf*16 + l15)*80 + g*16);
            s[qf] = __builtin_amdgcn_mfma_f32_16x16x32_bf16(qa, kb, (f32x4){0.f,0.f,0.f,0.f}, 0,0,0);
        }
        // online softmax per p-row (row = g*4+r within wave, spread over 16 lanes)
        float pv[4][4];
#pragma unroll
        for (int r=0;r<4;r++){
            float pm = fmaxf(fmaxf(s[0][r], s[1][r]), fmaxf(s[2][r], s[3][r]));
            pm = fmaxf(pm, __shfl_xor(pm, 1));
            pm = fmaxf(pm, __shfl_xor(pm, 2));
            pm = fmaxf(pm, __shfl_xor(pm, 4));
            pm = fmaxf(pm, __shfl_xor(pm, 8));
            float mn = fmaxf(m_run[r], pm);
            float f  = __expf(m_run[r] - mn);
            m_run[r] = mn;
            float rs = 0.f;
#pragma unroll
            for (int qf=0;qf<4;qf++){
                float e = __expf(s[qf][r] - mn);
                pv[qf][r] = e;
                rs += e;
            }
            rs += __shfl_xor(rs, 1);
            rs += __shfl_xor(rs, 2);
            rs += __shfl_xor(rs, 4);
            rs += __shfl_xor(rs, 8);
            l_run[r] = l_run[r]*f + rs;
#pragma unroll
            for (int cf=0;cf<4;cf++) acc[cf][r] *= f;
        }
        // P -> bf16 into per-wave LDS rows (swizzled; same XOR on write & read)
#pragma unroll
        for (int qf=0;qf<4;qf++)
#pragma unroll
            for (int r=0;r<4;r++){
                unsigned wrow = (unsigned)(w*16 + g*4 + r);
                unsigned byte = wrow*128 + (((unsigned)(qf*16 + l15)*2) ^ ((wrow&7u)<<4));
                *reinterpret_cast<unsigned short*>(reinterpret_cast<char*>(Pt) + byte) = f2bf(pv[qf][r]);
            }
        // PV: acc[p][c] += P[16p][64q] * V[64q][64c]
#pragma unroll
        for (int ks=0;ks<2;ks++){
            unsigned arow = (unsigned)(w*16 + l15);
            unsigned abyte = arow*128 + (((unsigned)(ks*64 + g*16)) ^ ((arow&7u)<<4));
            const bf16x8 pa = *reinterpret_cast<const bf16x8*>(
                reinterpret_cast<const char*>(Pt) + abyte);
#pragma unroll
            for (int cf=0;cf<4;cf++){
                unsigned vrow = (unsigned)(cf*16 + l15);
                unsigned vbyte = vrow*128 + (((unsigned)(ks*64 + g*16)) ^ ((vrow&7u)<<4));
                const bf16x8 vb = *reinterpret_cast<const bf16x8*>(
                    reinterpret_cast<const char*>(Vt) + vbyte);
                acc[cf] = __builtin_amdgcn_mfma_f32_16x16x32_bf16(pa, vb, acc[cf], 0,0,0);
            }
        }
    }
    float rl[4];
#pragma unroll
    for (int r=0;r<4;r++) rl[r] = 1.0f / l_run[r];
#pragma unroll
    for (int cf=0;cf<4;cf++)
#pragma unroll
        for (int r=0;r<4;r++)
            ZT[(size_t)(b*1024 + p0 + w*16 + g*4 + r)*64 + cf*16 + l15] = acc[cf][r]*rl[r];
}

// ---------- final: Z = wz*[Zh;Zm]+bz, comb = wm*[Z;h_mid]+bm, memory gates ----------
// Z1T/Z2T: [b][1024p][64c] f32
__global__ __launch_bounds__(256)
void final_kernel(const float* __restrict__ Z1T, const float* __restrict__ Z2T,
                  const float* __restrict__ h_mid, const float* __restrict__ m_in,
                  const float* __restrict__ wz, const float* __restrict__ bz,
                  const float* __restrict__ wm, const float* __restrict__ bm,
                  float* __restrict__ out_h, float* __restrict__ out_m)
{
    const int b  = blockIdx.y;
    const int p0 = blockIdx.x * 64;
    const int t  = threadIdx.x;
    const int p  = t & 63;
    const int g  = __builtin_amdgcn_readfirstlane(t >> 6);

    __shared__ float Zt[64][130];     // [p][c0..127], +2 pad (2-way banks)
    __shared__ float hs[64][64];      // [c][p]
    __shared__ float Zmid[128][64];

    for (int k=t;k<4096;k+=256){
        int hi = k>>6, lo = k&63;
        Zt[hi][lo]    = Z1T[(size_t)(b*1024+p0+hi)*64 + lo];
        Zt[hi][64+lo] = Z2T[(size_t)(b*1024+p0+hi)*64 + lo];
        hs[hi][lo]    = h_mid[(size_t)(b*64+hi)*1024 + p0 + lo];
    }
    __syncthreads();

    {   // phase 1: Z rows g*32..g*32+31
        float za[32];
#pragma unroll
        for (int j=0;j<32;j++) za[j] = bz[g*32+j];
        for (int k=0;k<128;k++){
            float x = Zt[p][k];
#pragma unroll
            for (int j=0;j<32;j++) za[j] = fmaf(wz[(g*32+j)*128 + k], x, za[j]);
        }
#pragma unroll
        for (int j=0;j<32;j++) Zmid[g*32+j][p] = za[j];
    }
    __syncthreads();
    {   // phase 2: comb rows {g*16+j, 64+g*16+j, 128+g*16+j}
        float ao[16], ag[16], ai[16];
#pragma unroll
        for (int j=0;j<16;j++){
            ao[j]=bm[g*16+j]; ag[j]=bm[64+g*16+j]; ai[j]=bm[128+g*16+j];
        }
        for (int k=0;k<128;k++){
            float x = Zmid[k][p];
#pragma unroll
            for (int j=0;j<16;j++){
                ao[j] = fmaf(wm[(g*16+j)*192 + k],      x, ao[j]);
                ag[j] = fmaf(wm[(64+g*16+j)*192 + k],   x, ag[j]);
                ai[j] = fmaf(wm[(128+g*16+j)*192 + k],  x, ai[j]);
            }
        }
        for (int k=0;k<64;k++){
            float x = hs[k][p];
#pragma unroll
            for (int j=0;j<16;j++){
                ao[j] = fmaf(wm[(g*16+j)*192 + 128 + k],     x, ao[j]);
                ag[j] = fmaf(wm[(64+g*16+j)*192 + 128 + k],  x, ag[j]);
                ai[j] = fmaf(wm[(128+g*16+j)*192 + 128 + k], x, ai[j]);
            }
        }
#pragma unroll
        for (int j=0;j<16;j++){
            int ch = g*16+j;
            float mi = sigmoidf_(ai[j]);
            float mg = tanhf_(ag[j]);
            float mv = m_in[(size_t)(b*64+ch)*1024 + p0+p];
            float mn = (1.0f - mi)*mv + mi*mg;
            out_m[(size_t)(b*64+ch)*1024 + p0+p] = mn;
            out_h[(size_t)(b*64+ch)*1024 + p0+p] = sigmoidf_(ao[j])*mn;
        }
    }
}

extern "C" void kernel_launch(void* const* d_in, const int* in_sizes, int n_in,
                              void* d_out, int out_size, void* d_ws, size_t ws_size,
                              hipStream_t stream)
{
    const float* x      = (const float*)d_in[0];
    const float* h      = (const float*)d_in[1];
    const float* c      = (const float*)d_in[2];
    const float* m      = (const float*)d_in[3];
    const float* lc     = (const float*)d_in[4];
    const float* conv_w = (const float*)d_in[5];
    const float* conv_b = (const float*)d_in[6];
    const float* gn1_w  = (const float*)d_in[7];
    const float* gn1_b  = (const float*)d_in[8];
    const float* convL_w= (const float*)d_in[9];
    const float* convL_b= (const float*)d_in[10];
    const float* gn2_w  = (const float*)d_in[11];
    const float* gn2_b  = (const float*)d_in[12];
    const float* wq  = (const float*)d_in[13];
    const float* bq  = (const float*)d_in[14];
    const float* wk  = (const float*)d_in[15];
    const float* bk  = (const float*)d_in[16];
    const float* wk2 = (const float*)d_in[17];
    const float* bk2 = (const float*)d_in[18];
    const float* wv  = (const float*)d_in[19];
    const float* bv  = (const float*)d_in[20];
    const float* wv2 = (const float*)d_in[21];
    const float* bv2 = (const float*)d_in[22];
    const float* wz  = (const float*)d_in[23];
    const float* bz  = (const float*)d_in[24];
    const float* wmw = (const float*)d_in[25];
    const float* bm  = (const float*)d_in[26];

    float* out = (float*)d_out;
    float* F = (float*)d_ws;
    // workspace layout (f32 units), ~46.3 MB
    float* cc_raw = F;                           // 4,194,304
    float* c_tmp  = F + 4194304;                 // 1,048,576
    float* sig_co = F + 5242880;                 // 1,048,576
    float* h_mid  = F + 6291456;                 // 1,048,576
    float* Z1T    = F + 7340032;                 // 1,048,576 (aliases buf1, dead by attn)
    float* Z2T    = F + 8388608;                 // 1,048,576 (aliases buf2)
    unsigned short* buf1 = (unsigned short*)(F + 7340032);
    unsigned short* buf2 = (unsigned short*)(F + 8388608);
    unsigned short* Qb   = (unsigned short*)(F + 9437184);   // 524,288 us
    unsigned short* Khb  = (unsigned short*)(F + 9699328);
    unsigned short* Kmb  = (unsigned short*)(F + 9961472);
    unsigned short* Vhb  = (unsigned short*)(F + 10223616);  // 1,048,576 us
    unsigned short* Vmb  = (unsigned short*)(F + 10747904);
    unsigned short* wpk1 = (unsigned short*)(F + 11272192);
    unsigned short* wpk2 = (unsigned short*)(F + 11419648);

    dim3 blk256(256);
    wprep_kernel<<<dim3(1152), blk256, 0, stream>>>(conv_w,  wpk1);
    wprep_kernel<<<dim3(1152), blk256, 0, stream>>>(convL_w, wpk2);
    packin_kernel<<<dim3(16,16), blk256, 0, stream>>>(x, h, buf1);

    dim3 cgrid(8, 4, 16);
    conv_mfma_kernel<<<cgrid, blk256, 0, stream>>>(buf1, wpk1, conv_b, cc_raw);
    gn_gate1_kernel<<<dim3(64,16), blk256, 0, stream>>>(cc_raw, gn1_w, gn1_b, c, c_tmp, sig_co);
    packin_kernel<<<dim3(16,16), blk256, 0, stream>>>(h, c_tmp, buf2);
    conv_mfma_kernel<<<cgrid, blk256, 0, stream>>>(buf2, wpk2, convL_b, cc_raw);
    gn_gate2_kernel<<<dim3(64,16), blk256, 0, stream>>>(cc_raw, gn2_w, gn2_b, lc, sig_co,
                                                        out + 3*1048576 /*lc_next*/,
                                                        out + 1*1048576 /*c_next*/,
                                                        h_mid);
    proj_kernel<<<dim3(16,16), blk256, 0, stream>>>(h_mid, m, wq,bq, wk,bk, wk2,bk2,
                                                    wv,bv, wv2,bv2, Qb, Khb, Kmb, Vhb, Vmb);
    attn_mfma_kernel<<<dim3(512), blk256, 0, stream>>>(Qb, Khb, Kmb, Vhb, Vmb, Z1T, Z2T);
    final_kernel<<<dim3(16,16), blk256, 0, stream>>>(Z1T, Z2T, h_mid, m, wz, bz, wmw, bm,
                                                     out /*h_next*/, out + 2*1048576 /*m_next*/);
    (void)in_sizes; (void)n_in; (void)out_size; (void)ws_size;
}

// Round 4
// 189.584 us; speedup vs baseline: 5.5688x; 1.5918x over previous
//
#include <hip/hip_runtime.h>

#define DEV __device__ __forceinline__

typedef __attribute__((ext_vector_type(8))) __bf16 bf16x8;
typedef __attribute__((ext_vector_type(4))) float f32x4;
typedef __attribute__((ext_vector_type(8))) unsigned short ushort8;
typedef __attribute__((ext_vector_type(2))) unsigned short ushort2v;

DEV float sigmoidf_(float x){ return 1.0f/(1.0f + __expf(-x)); }
DEV float tanhf_(float x){
    x = fminf(15.0f, fmaxf(-15.0f, x));
    float e = __expf(2.0f*x);
    return (e - 1.0f)/(e + 1.0f);
}
DEV unsigned short f2bf(float f){
    unsigned u = __builtin_bit_cast(unsigned, f);
    unsigned r = (u + 0x7FFFu + ((u>>16)&1u)) >> 16;
    return (unsigned short)r;
}
DEV unsigned swz(unsigned byte){ return byte ^ (((byte>>9)&1u)<<5); }

// ---------- conv weight pack: [256co][128ci][9tap] f32 -> [(ci/32)*9+tap][256co][32ci] bf16 ----------
__global__ __launch_bounds__(256)
void wprep_kernel(const float* __restrict__ w, unsigned short* __restrict__ wpk)
{
    int idx = blockIdx.x*256 + threadIdx.x;
    if (idx >= 256*128*9) return;
    int co  = idx / (128*9);
    int rem = idx - co*(128*9);
    int ci  = rem / 9;
    int tap = rem - ci*9;
    int kchunk = (ci>>5)*9 + tap;
    wpk[(kchunk*256 + co)*32 + (ci&31)] = f2bf(w[idx]);
}

// ---------- wz/wm pack to bf16 row-major ----------
__global__ __launch_bounds__(256)
void wzm_pack_kernel(const float* __restrict__ wz, const float* __restrict__ wm,
                     unsigned short* __restrict__ wzb, unsigned short* __restrict__ wmb)
{
    int idx = blockIdx.x*256 + threadIdx.x;
    if (idx < 128*128) wzb[idx] = f2bf(wz[idx]);
    int j = idx - 128*128;
    if (j >= 0 && j < 192*192) wmb[j] = f2bf(wm[j]);
}

// ---------- input pack: concat(in0,in1) [b][128ci][1024pix] f32 -> [b][1024pix][128ci] bf16 ----------
__global__ __launch_bounds__(256)
void packin_kernel(const float* __restrict__ in0, const float* __restrict__ in1,
                   unsigned short* __restrict__ outp)
{
    const int b  = blockIdx.y;
    const int p0 = blockIdx.x * 64;
    const int t  = threadIdx.x;
    __shared__ float tile[128][65];
    for (int k=t;k<8192;k+=256){
        int ci = k>>6, pp = k&63;
        const float* s = (ci<64) ? in0 + (b*64+ci)*1024 : in1 + (b*64+ci-64)*1024;
        tile[ci][pp] = s[p0+pp];
    }
    __syncthreads();
    for (int k=t;k<4096;k+=256){
        int pp = k>>6, c2 = k&63;
        ushort2v v;
        v.x = f2bf(tile[c2*2][pp]);
        v.y = f2bf(tile[c2*2+1][pp]);
        *reinterpret_cast<ushort2v*>(outp + ((b*1024+p0+pp)*128) + c2*2) = v;
    }
}

// ---------- implicit-GEMM 3x3 conv via MFMA ----------
__global__ __launch_bounds__(256)
void conv_mfma_kernel(const unsigned short* __restrict__ inp,
                      const unsigned short* __restrict__ wpk,
                      const float* __restrict__ bias,
                      float* __restrict__ out)
{
    const int b   = blockIdx.z;
    const int co0 = blockIdx.y * 64;
    const int r0  = blockIdx.x * 4;
    const int t   = threadIdx.x;
    const int l   = t & 63;
    const int wv  = t >> 6;
    const int l15 = l & 15;
    const int lhi = l >> 4;

    __shared__ __align__(16) unsigned short in_t[7168];

    f32x4 acc[4][2];
#pragma unroll
    for (int i=0;i<4;i++)
#pragma unroll
        for (int f=0;f<2;f++)
            acc[i][f] = (f32x4){0.f,0.f,0.f,0.f};

    for (int cic = 0; cic < 4; ++cic) {
        __syncthreads();
        for (int it = t; it < 816; it += 256) {
            int pixlin = it >> 2, oct = it & 3;
            int rr = pixlin / 34;
            int cc = pixlin - rr*34;
            int gr = r0 + rr - 1, gc = cc - 1;
            ushort8 v = {};
            if ((unsigned)gr < 32u && (unsigned)gc < 32u)
                v = *reinterpret_cast<const ushort8*>(
                        inp + ((b*1024 + gr*32 + gc)*128) + cic*32 + oct*8);
            unsigned byte = swz((unsigned)(pixlin*64 + oct*16));
            *reinterpret_cast<ushort8*>(reinterpret_cast<char*>(in_t) + byte) = v;
        }
        __syncthreads();
#pragma unroll
        for (int tap = 0; tap < 9; ++tap) {
            const int ky = tap/3, kx = tap - 3*(tap/3);
            const unsigned short* wrow = wpk + ((cic*9 + tap)*256 + co0)*32;
            bf16x8 af[4];
#pragma unroll
            for (int i=0;i<4;i++)
                af[i] = *reinterpret_cast<const bf16x8*>(wrow + (i*16 + l15)*32 + lhi*8);
            bf16x8 bfr[2];
#pragma unroll
            for (int f=0;f<2;f++){
                int pixlin = (wv + ky)*34 + (f*16 + l15 + kx);
                unsigned byte = swz((unsigned)(pixlin*64 + lhi*16));
                bfr[f] = *reinterpret_cast<const bf16x8*>(
                             reinterpret_cast<const char*>(in_t) + byte);
            }
#pragma unroll
            for (int i=0;i<4;i++)
#pragma unroll
                for (int f=0;f<2;f++)
                    acc[i][f] = __builtin_amdgcn_mfma_f32_16x16x32_bf16(af[i], bfr[f], acc[i][f], 0, 0, 0);
        }
    }
    const int orow = r0 + wv;
#pragma unroll
    for (int i=0;i<4;i++){
        int cobase = co0 + i*16 + lhi*4;
#pragma unroll
        for (int f=0;f<2;f++){
            int col = orow*32 + f*16 + l15;
#pragma unroll
            for (int r=0;r<4;r++)
                out[(b*256 + cobase + r)*1024 + col] = acc[i][f][r] + bias[cobase+r];
        }
    }
}

// ---------- GN + first gate block ----------
__global__ __launch_bounds__(256)
void gn_gate1_kernel(const float* __restrict__ cc, const float* __restrict__ gnw,
                     const float* __restrict__ gnb, const float* __restrict__ c_in,
                     float* __restrict__ c_tmp, float* __restrict__ sig_co)
{
    const int ch = blockIdx.x;
    const int b  = blockIdx.y;
    const int t  = threadIdx.x;
    __shared__ float red[4][8];

    float v[4][4];
    float scale[4], shift[4];
#pragma unroll
    for (int g=0; g<4; g++) {
        const float* src = cc + (b*256 + g*64 + ch)*1024;
        float ls = 0.f, lq = 0.f;
#pragma unroll
        for (int k=0;k<4;k++){
            float x = src[t + 256*k];
            v[g][k] = x; ls += x; lq += x*x;
        }
#pragma unroll
        for (int off=32; off>0; off>>=1){ ls += __shfl_xor(ls, off); lq += __shfl_xor(lq, off); }
        if ((t & 63) == 0){ red[t>>6][g] = ls; red[t>>6][4+g] = lq; }
    }
    __syncthreads();
#pragma unroll
    for (int g=0; g<4; g++) {
        float s = red[0][g]+red[1][g]+red[2][g]+red[3][g];
        float q = red[0][4+g]+red[1][4+g]+red[2][4+g]+red[3][4+g];
        float mu  = s * (1.0f/1024.0f);
        float var = q * (1.0f/1024.0f) - mu*mu;
        float rs  = rsqrtf(var + 1e-5f);
        float gw  = gnw[g*64+ch];
        scale[g] = rs*gw;
        shift[g] = gnb[g*64+ch] - mu*rs*gw;
    }
    const float* cp = c_in   + (b*64+ch)*1024;
    float* ct = c_tmp  + (b*64+ch)*1024;
    float* so = sig_co + (b*64+ch)*1024;
#pragma unroll
    for (int k=0;k<4;k++){
        int p = t + 256*k;
        float ni = v[0][k]*scale[0] + shift[0];
        float nf = v[1][k]*scale[1] + shift[1];
        float no = v[2][k]*scale[2] + shift[2];
        float ng = v[3][k]*scale[3] + shift[3];
        ct[p] = sigmoidf_(nf)*cp[p] + sigmoidf_(ni)*tanhf_(ng);
        so[p] = sigmoidf_(no);
    }
}

// ---------- GN + second (long) gate block ----------
__global__ __launch_bounds__(256)
void gn_gate2_kernel(const float* __restrict__ cc, const float* __restrict__ gnw,
                     const float* __restrict__ gnb, const float* __restrict__ lc_in,
                     const float* __restrict__ sig_co,
                     float* __restrict__ out_lc, float* __restrict__ out_c,
                     float* __restrict__ h_mid)
{
    const int ch = blockIdx.x;
    const int b  = blockIdx.y;
    const int t  = threadIdx.x;
    __shared__ float red[4][8];

    float v[4][4];
    float scale[4], shift[4];
#pragma unroll
    for (int g=0; g<4; g++) {
        const float* src = cc + (b*256 + g*64 + ch)*1024;
        float ls = 0.f, lq = 0.f;
#pragma unroll
        for (int k=0;k<4;k++){
            float x = src[t + 256*k];
            v[g][k] = x; ls += x; lq += x*x;
        }
#pragma unroll
        for (int off=32; off>0; off>>=1){ ls += __shfl_xor(ls, off); lq += __shfl_xor(lq, off); }
        if ((t & 63) == 0){ red[t>>6][g] = ls; red[t>>6][4+g] = lq; }
    }
    __syncthreads();
#pragma unroll
    for (int g=0; g<4; g++) {
        float s = red[0][g]+red[1][g]+red[2][g]+red[3][g];
        float q = red[0][4+g]+red[1][4+g]+red[2][4+g]+red[3][4+g];
        float mu  = s * (1.0f/1024.0f);
        float var = q * (1.0f/1024.0f) - mu*mu;
        float rs  = rsqrtf(var + 1e-5f);
        float gw  = gnw[g*64+ch];
        scale[g] = rs*gw;
        shift[g] = gnb[g*64+ch] - mu*rs*gw;
    }
    const float* lp = lc_in  + (b*64+ch)*1024;
    const float* so = sig_co + (b*64+ch)*1024;
    float* olc = out_lc + (b*64+ch)*1024;
    float* oc  = out_c  + (b*64+ch)*1024;
    float* ohm = h_mid  + (b*64+ch)*1024;
#pragma unroll
    for (int k=0;k<4;k++){
        int p = t + 256*k;
        float ni = v[0][k]*scale[0] + shift[0];
        float nf = v[1][k]*scale[1] + shift[1];
        float no = v[2][k]*scale[2] + shift[2];
        float ng = v[3][k]*scale[3] + shift[3];
        float lcn = sigmoidf_(nf)*lp[p] + sigmoidf_(ni)*tanhf_(ng);
        float cf  = sigmoidf_(no)*tanhf_(lcn);
        olc[p] = lcn;
        oc[p]  = cf;
        ohm[p] = so[p]*tanhf_(cf);
    }
}

// ---------- fused 1x1 projections -> bf16 MFMA layouts (+ h_midT bf16) ----------
// Qb/Khb/Kmb: [b][1024pix][32a] ; Vhb/Vmb: [b][64c][1024pix] ; hT: [b][1024pix][64c]
__global__ __launch_bounds__(256)
void proj_kernel(const float* __restrict__ h_mid, const float* __restrict__ m_in,
                 const float* __restrict__ wq, const float* __restrict__ bq,
                 const float* __restrict__ wk, const float* __restrict__ bk,
                 const float* __restrict__ wk2, const float* __restrict__ bk2,
                 const float* __restrict__ wv, const float* __restrict__ bv,
                 const float* __restrict__ wv2, const float* __restrict__ bv2,
                 unsigned short* __restrict__ Qb, unsigned short* __restrict__ Khb,
                 unsigned short* __restrict__ Kmb,
                 unsigned short* __restrict__ Vhb, unsigned short* __restrict__ Vmb,
                 unsigned short* __restrict__ hT)
{
    const int b  = blockIdx.y;
    const int p0 = blockIdx.x * 64;
    const int t  = threadIdx.x;
    __shared__ float hs[64*64];
    __shared__ float ms[64*64];
    for (int k=t;k<4096;k+=256){
        int cch = k>>6, pp = k&63;
        hs[k] = h_mid[(b*64+cch)*1024 + p0+pp];
        ms[k] = m_in [(b*64+cch)*1024 + p0+pp];
    }
    __syncthreads();
    const int p = t & 63;
    const int g = __builtin_amdgcn_readfirstlane(t >> 6);

    // h_midT bf16 out (transpose from LDS; lanes read consecutive p -> 2-way banks)
#pragma unroll
    for (int e=0;e<2;e++){
        int oct = (t>>6) + e*4;
        ushort8 v;
#pragma unroll
        for (int j=0;j<8;j++) v[j] = f2bf(hs[(oct*8+j)*64 + p]);
        *reinterpret_cast<ushort8*>(hT + (size_t)(b*1024+p0+p)*64 + oct*8) = v;
    }

    {
        float aq[8], ak[8], av[16];
#pragma unroll
        for (int j=0;j<8;j++){ aq[j]=bq[g*8+j]; ak[j]=bk[g*8+j]; }
#pragma unroll
        for (int j=0;j<16;j++) av[j]=bv[g*16+j];
        for (int cc=0;cc<64;cc++){
            float x = hs[cc*64+p];
#pragma unroll
            for (int j=0;j<8;j++)  aq[j] = fmaf(wq[(g*8+j)*64+cc],  x, aq[j]);
#pragma unroll
            for (int j=0;j<8;j++)  ak[j] = fmaf(wk[(g*8+j)*64+cc],  x, ak[j]);
#pragma unroll
            for (int j=0;j<16;j++) av[j] = fmaf(wv[(g*16+j)*64+cc], x, av[j]);
        }
        ushort8 vq, vk;
#pragma unroll
        for (int j=0;j<8;j++){ vq[j]=f2bf(aq[j]); vk[j]=f2bf(ak[j]); }
        *reinterpret_cast<ushort8*>(Qb  + (size_t)(b*1024+p0+p)*32 + g*8) = vq;
        *reinterpret_cast<ushort8*>(Khb + (size_t)(b*1024+p0+p)*32 + g*8) = vk;
#pragma unroll
        for (int j=0;j<16;j++)
            Vhb[(size_t)(b*64 + g*16+j)*1024 + p0+p] = f2bf(av[j]);
    }
    {
        float ak[8], av[16];
#pragma unroll
        for (int j=0;j<8;j++)  ak[j]=bk2[g*8+j];
#pragma unroll
        for (int j=0;j<16;j++) av[j]=bv2[g*16+j];
        for (int cc=0;cc<64;cc++){
            float x = ms[cc*64+p];
#pragma unroll
            for (int j=0;j<8;j++)  ak[j] = fmaf(wk2[(g*8+j)*64+cc],  x, ak[j]);
#pragma unroll
            for (int j=0;j<16;j++) av[j] = fmaf(wv2[(g*16+j)*64+cc], x, av[j]);
        }
        ushort8 vk;
#pragma unroll
        for (int j=0;j<8;j++) vk[j]=f2bf(ak[j]);
        *reinterpret_cast<ushort8*>(Kmb + (size_t)(b*1024+p0+p)*32 + g*8) = vk;
#pragma unroll
        for (int j=0;j<16;j++)
            Vmb[(size_t)(b*64 + g*16+j)*1024 + p0+p] = f2bf(av[j]);
    }
}

// ---------- MFMA flash attention -> ZT bf16 [b][1024p][128c] (pass0: c0-63, pass1: c64-127) ----------
__global__ __launch_bounds__(256)
void attn_mfma_kernel(const unsigned short* __restrict__ Qb,
                      const unsigned short* __restrict__ Kh,
                      const unsigned short* __restrict__ Km,
                      const unsigned short* __restrict__ Vh,
                      const unsigned short* __restrict__ Vm,
                      unsigned short* __restrict__ ZT)
{
    const int bid   = blockIdx.x;
    const int xcd   = bid & 7;
    const int slot  = bid >> 3;
    const int b     = xcd*2 + (slot>>5);
    const int pass  = (slot>>4) & 1;
    const int p0    = (slot & 15) * 64;
    const int t   = threadIdx.x;
    const int l   = t & 63;
    const int w   = t >> 6;
    const int l15 = l & 15, g = l >> 4;

    __shared__ __align__(16) unsigned short Kt[64*40];
    __shared__ __align__(16) unsigned short Vt[64*64];
    __shared__ __align__(16) unsigned short Pt[64*64];

    const unsigned short* Kg = pass ? Km : Kh;
    const unsigned short* Vg = pass ? Vm : Vh;

    const bf16x8 qa = *reinterpret_cast<const bf16x8*>(
        Qb + (size_t)(b*1024 + p0 + w*16 + l15)*32 + g*8);

    float m_run[4], l_run[4];
    f32x4 acc[4];
#pragma unroll
    for (int r=0;r<4;r++){ m_run[r] = -1e30f; l_run[r] = 0.f; }
#pragma unroll
    for (int cf=0;cf<4;cf++) acc[cf] = (f32x4){0.f,0.f,0.f,0.f};

    for (int q0=0; q0<1024; q0+=64){
        __syncthreads();
        {
            int row = t>>2, oct = t&3;
            ushort8 kv = *reinterpret_cast<const ushort8*>(
                Kg + (size_t)(b*1024 + q0 + row)*32 + oct*8);
            *reinterpret_cast<ushort8*>(Kt + row*40 + oct*8) = kv;
        }
        for (int it=t; it<512; it+=256){
            int row = it>>3, oct = it&7;
            ushort8 vv = *reinterpret_cast<const ushort8*>(
                Vg + (size_t)(b*64 + row)*1024 + q0 + oct*8);
            unsigned byte = (unsigned)(row*128) + (((unsigned)oct*16) ^ ((unsigned)(row&7)<<4));
            *reinterpret_cast<ushort8*>(reinterpret_cast<char*>(Vt) + byte) = vv;
        }
        __syncthreads();

        f32x4 s[4];
#pragma unroll
        for (int qf=0; qf<4; qf++){
            const bf16x8 kb = *reinterpret_cast<const bf16x8*>(
                reinterpret_cast<const char*>(Kt) + (qf*16 + l15)*80 + g*16);
            s[qf] = __builtin_amdgcn_mfma_f32_16x16x32_bf16(qa, kb, (f32x4){0.f,0.f,0.f,0.f}, 0,0,0);
        }
        float pv[4][4];
#pragma unroll
        for (int r=0;r<4;r++){
            float pm = fmaxf(fmaxf(s[0][r], s[1][r]), fmaxf(s[2][r], s[3][r]));
            pm = fmaxf(pm, __shfl_xor(pm, 1));
            pm = fmaxf(pm, __shfl_xor(pm, 2));
            pm = fmaxf(pm, __shfl_xor(pm, 4));
            pm = fmaxf(pm, __shfl_xor(pm, 8));
            float mn = fmaxf(m_run[r], pm);
            float f  = __expf(m_run[r] - mn);
            m_run[r] = mn;
            float rs = 0.f;
#pragma unroll
            for (int qf=0;qf<4;qf++){
                float e = __expf(s[qf][r] - mn);
                pv[qf][r] = e;
                rs += e;
            }
            rs += __shfl_xor(rs, 1);
            rs += __shfl_xor(rs, 2);
            rs += __shfl_xor(rs, 4);
            rs += __shfl_xor(rs, 8);
            l_run[r] = l_run[r]*f + rs;
#pragma unroll
            for (int cf=0;cf<4;cf++) acc[cf][r] *= f;
        }
#pragma unroll
        for (int qf=0;qf<4;qf++)
#pragma unroll
            for (int r=0;r<4;r++){
                unsigned wrow = (unsigned)(w*16 + g*4 + r);
                unsigned byte = wrow*128 + (((unsigned)(qf*16 + l15)*2) ^ ((wrow&7u)<<4));
                *reinterpret_cast<unsigned short*>(reinterpret_cast<char*>(Pt) + byte) = f2bf(pv[qf][r]);
            }
#pragma unroll
        for (int ks=0;ks<2;ks++){
            unsigned arow = (unsigned)(w*16 + l15);
            unsigned abyte = arow*128 + (((unsigned)(ks*64 + g*16)) ^ ((arow&7u)<<4));
            const bf16x8 pa = *reinterpret_cast<const bf16x8*>(
                reinterpret_cast<const char*>(Pt) + abyte);
#pragma unroll
            for (int cf=0;cf<4;cf++){
                unsigned vrow = (unsigned)(cf*16 + l15);
                unsigned vbyte = vrow*128 + (((unsigned)(ks*64 + g*16)) ^ ((vrow&7u)<<4));
                const bf16x8 vb = *reinterpret_cast<const bf16x8*>(
                    reinterpret_cast<const char*>(Vt) + vbyte);
                acc[cf] = __builtin_amdgcn_mfma_f32_16x16x32_bf16(pa, vb, acc[cf], 0,0,0);
            }
        }
    }
    float rl[4];
#pragma unroll
    for (int r=0;r<4;r++) rl[r] = 1.0f / l_run[r];
#pragma unroll
    for (int cf=0;cf<4;cf++)
#pragma unroll
        for (int r=0;r<4;r++)
            ZT[(size_t)(b*1024 + p0 + w*16 + g*4 + r)*128 + pass*64 + cf*16 + l15]
                = f2bf(acc[cf][r]*rl[r]);
}

// ---------- final via MFMA: Z = wz*[Zh;Zm]+bz ; comb = wm*[Z;h_mid]+bm ; gates ----------
// ZT: [b][1024p][128c] bf16 ; hT: [b][1024p][64c] bf16 ; wzb: [128][128] ; wmb: [192][192]
__global__ __launch_bounds__(256)
void final_mfma_kernel(const unsigned short* __restrict__ ZT,
                       const unsigned short* __restrict__ hT,
                       const unsigned short* __restrict__ wzb,
                       const unsigned short* __restrict__ wmb,
                       const float* __restrict__ bz, const float* __restrict__ bm,
                       const float* __restrict__ m_in,
                       float* __restrict__ out_h, float* __restrict__ out_m)
{
    const int b  = blockIdx.y;
    const int p0 = blockIdx.x * 64;
    const int t  = threadIdx.x;
    const int l  = t & 63;
    const int w  = t >> 6;
    const int l15 = l & 15, g = l >> 4;

    __shared__ __align__(16) unsigned short Bs[64*192];   // [p][k], rows XOR-swizzled

    // stage Zin (cols 0..127) and h_mid (cols 128..191)
    for (int it=t; it<1024; it+=256){
        int row = it>>4, oct = it&15;
        ushort8 v = *reinterpret_cast<const ushort8*>(
            ZT + (size_t)(b*1024 + p0 + row)*128 + oct*8);
        unsigned byte = (unsigned)(row*384) + (((unsigned)oct*16) ^ ((unsigned)(row&7)<<4));
        *reinterpret_cast<ushort8*>(reinterpret_cast<char*>(Bs) + byte) = v;
    }
    for (int it=t; it<512; it+=256){
        int row = it>>3, oct = it&7;
        ushort8 v = *reinterpret_cast<const ushort8*>(
            hT + (size_t)(b*1024 + p0 + row)*64 + oct*8);
        unsigned byte = (unsigned)(row*384) + 256u + (((unsigned)oct*16) ^ ((unsigned)(row&7)<<4));
        *reinterpret_cast<ushort8*>(reinterpret_cast<char*>(Bs) + byte) = v;
    }
    __syncthreads();

    // GEMM1: Z[128co][64pix], wave w owns co rows w*32..w*32+31
    f32x4 acc1[2][4];
#pragma unroll
    for (int i=0;i<2;i++)
#pragma unroll
        for (int cf=0;cf<4;cf++) acc1[i][cf] = (f32x4){0.f,0.f,0.f,0.f};
#pragma unroll
    for (int ks=0; ks<4; ++ks){
        bf16x8 af[2];
#pragma unroll
        for (int i=0;i<2;i++)
            af[i] = *reinterpret_cast<const bf16x8*>(
                wzb + (size_t)(w*32 + i*16 + l15)*128 + ks*32 + g*8);
#pragma unroll
        for (int cf=0;cf<4;cf++){
            unsigned p = (unsigned)(cf*16 + l15);
            unsigned byte = p*384 + (((unsigned)(ks*64 + g*16)) ^ ((p&7u)<<4));
            const bf16x8 bfr = *reinterpret_cast<const bf16x8*>(
                reinterpret_cast<const char*>(Bs) + byte);
            acc1[0][cf] = __builtin_amdgcn_mfma_f32_16x16x32_bf16(af[0], bfr, acc1[0][cf], 0,0,0);
            acc1[1][cf] = __builtin_amdgcn_mfma_f32_16x16x32_bf16(af[1], bfr, acc1[1][cf], 0,0,0);
        }
    }
    __syncthreads();   // all Zin reads done
    // write Z (+bz) back into Bs cols 0..127 as bf16
#pragma unroll
    for (int i=0;i<2;i++){
        int co = w*32 + i*16 + g*4;
#pragma unroll
        for (int cf=0;cf<4;cf++){
            unsigned p = (unsigned)(cf*16 + l15);
#pragma unroll
            for (int r=0;r<4;r++){
                float val = acc1[i][cf][r] + bz[co+r];
                unsigned byte = p*384 + (((unsigned)((co+r)*2)) ^ ((p&7u)<<4));
                *reinterpret_cast<unsigned short*>(reinterpret_cast<char*>(Bs) + byte) = f2bf(val);
            }
        }
    }
    __syncthreads();

    // GEMM2: comb[192][64pix], wave w owns rows {w*16, 64+w*16, 128+w*16}
    f32x4 acc2[3][4];
#pragma unroll
    for (int j=0;j<3;j++)
#pragma unroll
        for (int cf=0;cf<4;cf++) acc2[j][cf] = (f32x4){0.f,0.f,0.f,0.f};
#pragma unroll
    for (int ks=0; ks<6; ++ks){
        bf16x8 am[3];
#pragma unroll
        for (int j=0;j<3;j++)
            am[j] = *reinterpret_cast<const bf16x8*>(
                wmb + (size_t)(j*64 + w*16 + l15)*192 + ks*32 + g*8);
#pragma unroll
        for (int cf=0;cf<4;cf++){
            unsigned p = (unsigned)(cf*16 + l15);
            unsigned byte = p*384 + (((unsigned)(ks*64 + g*16)) ^ ((p&7u)<<4));
            const bf16x8 bfr = *reinterpret_cast<const bf16x8*>(
                reinterpret_cast<const char*>(Bs) + byte);
#pragma unroll
            for (int j=0;j<3;j++)
                acc2[j][cf] = __builtin_amdgcn_mfma_f32_16x16x32_bf16(am[j], bfr, acc2[j][cf], 0,0,0);
        }
    }

    // epilogue: lane has (ch = w*16+g*4+r, pix = p0+cf*16+l15) for all three gates
    const int ch0 = w*16 + g*4;
#pragma unroll
    for (int cf=0;cf<4;cf++){
        int pix = p0 + cf*16 + l15;
#pragma unroll
        for (int r=0;r<4;r++){
            int ch = ch0 + r;
            float mo = acc2[0][cf][r] + bm[ch];
            float mg = acc2[1][cf][r] + bm[64+ch];
            float mi = sigmoidf_(acc2[2][cf][r] + bm[128+ch]);
            float mv = m_in[(size_t)(b*64+ch)*1024 + pix];
            float mn = (1.0f - mi)*mv + mi*tanhf_(mg);
            out_m[(size_t)(b*64+ch)*1024 + pix] = mn;
            out_h[(size_t)(b*64+ch)*1024 + pix] = sigmoidf_(mo)*mn;
        }
    }
}

extern "C" void kernel_launch(void* const* d_in, const int* in_sizes, int n_in,
                              void* d_out, int out_size, void* d_ws, size_t ws_size,
                              hipStream_t stream)
{
    const float* x      = (const float*)d_in[0];
    const float* h      = (const float*)d_in[1];
    const float* c      = (const float*)d_in[2];
    const float* m      = (const float*)d_in[3];
    const float* lc     = (const float*)d_in[4];
    const float* conv_w = (const float*)d_in[5];
    const float* conv_b = (const float*)d_in[6];
    const float* gn1_w  = (const float*)d_in[7];
    const float* gn1_b  = (const float*)d_in[8];
    const float* convL_w= (const float*)d_in[9];
    const float* convL_b= (const float*)d_in[10];
    const float* gn2_w  = (const float*)d_in[11];
    const float* gn2_b  = (const float*)d_in[12];
    const float* wq  = (const float*)d_in[13];
    const float* bq  = (const float*)d_in[14];
    const float* wk  = (const float*)d_in[15];
    const float* bk  = (const float*)d_in[16];
    const float* wk2 = (const float*)d_in[17];
    const float* bk2 = (const float*)d_in[18];
    const float* wv  = (const float*)d_in[19];
    const float* bv  = (const float*)d_in[20];
    const float* wv2 = (const float*)d_in[21];
    const float* bv2 = (const float*)d_in[22];
    const float* wz  = (const float*)d_in[23];
    const float* bz  = (const float*)d_in[24];
    const float* wmw = (const float*)d_in[25];
    const float* bm  = (const float*)d_in[26];

    float* out = (float*)d_out;
    float* F = (float*)d_ws;
    // workspace layout (f32 units)
    float* cc_raw = F;                           // 4,194,304
    float* c_tmp  = F + 4194304;                 // 1,048,576
    float* sig_co = F + 5242880;                 // 1,048,576
    float* h_mid  = F + 6291456;                 // 1,048,576
    unsigned short* buf1 = (unsigned short*)(F + 7340032);   // 2M us (conv1 in; later ZT)
    unsigned short* ZT   = buf1;                              // [16][1024][128] bf16
    unsigned short* buf2 = (unsigned short*)(F + 8388608);   // 2M us (conv2 in; later hT)
    unsigned short* hT   = buf2;                              // [16][1024][64] bf16 (1M us)
    unsigned short* Qb   = (unsigned short*)(F + 9437184);
    unsigned short* Khb  = (unsigned short*)(F + 9699328);
    unsigned short* Kmb  = (unsigned short*)(F + 9961472);
    unsigned short* Vhb  = (unsigned short*)(F + 10223616);
    unsigned short* Vmb  = (unsigned short*)(F + 10747904);
    unsigned short* wpk1 = (unsigned short*)(F + 11272192);
    unsigned short* wpk2 = (unsigned short*)(F + 11419648);
    unsigned short* wzb  = (unsigned short*)(F + 11567104);  // 16384 us
    unsigned short* wmb  = (unsigned short*)(F + 11575296);  // 36864 us

    dim3 blk256(256);
    wprep_kernel<<<dim3(1152), blk256, 0, stream>>>(conv_w,  wpk1);
    wprep_kernel<<<dim3(1152), blk256, 0, stream>>>(convL_w, wpk2);
    wzm_pack_kernel<<<dim3(208), blk256, 0, stream>>>(wz, wmw, wzb, wmb);
    packin_kernel<<<dim3(16,16), blk256, 0, stream>>>(x, h, buf1);

    dim3 cgrid(8, 4, 16);
    conv_mfma_kernel<<<cgrid, blk256, 0, stream>>>(buf1, wpk1, conv_b, cc_raw);
    gn_gate1_kernel<<<dim3(64,16), blk256, 0, stream>>>(cc_raw, gn1_w, gn1_b, c, c_tmp, sig_co);
    packin_kernel<<<dim3(16,16), blk256, 0, stream>>>(h, c_tmp, buf2);
    conv_mfma_kernel<<<cgrid, blk256, 0, stream>>>(buf2, wpk2, convL_b, cc_raw);
    gn_gate2_kernel<<<dim3(64,16), blk256, 0, stream>>>(cc_raw, gn2_w, gn2_b, lc, sig_co,
                                                        out + 3*1048576 /*lc_next*/,
                                                        out + 1*1048576 /*c_next*/,
                                                        h_mid);
    proj_kernel<<<dim3(16,16), blk256, 0, stream>>>(h_mid, m, wq,bq, wk,bk, wk2,bk2,
                                                    wv,bv, wv2,bv2, Qb, Khb, Kmb, Vhb, Vmb, hT);
    attn_mfma_kernel<<<dim3(512), blk256, 0, stream>>>(Qb, Khb, Kmb, Vhb, Vmb, ZT);
    final_mfma_kernel<<<dim3(16,16), blk256, 0, stream>>>(ZT, hT, wzb, wmb, bz, bm, m,
                                                          out /*h_next*/, out + 2*1048576 /*m_next*/);
    (void)in_sizes; (void)n_in; (void)out_size; (void)ws_size;
}

// Round 5
// 172.775 us; speedup vs baseline: 6.1105x; 1.0973x over previous
//
#include <hip/hip_runtime.h>

#define DEV __device__ __forceinline__

typedef __attribute__((ext_vector_type(8))) __bf16 bf16x8;
typedef __attribute__((ext_vector_type(4))) float f32x4;
typedef __attribute__((ext_vector_type(8))) unsigned short ushort8;
typedef __attribute__((ext_vector_type(2))) unsigned short ushort2v;
typedef __attribute__((ext_vector_type(2))) unsigned int uint2v;

DEV float sigmoidf_(float x){ return 1.0f/(1.0f + __expf(-x)); }
DEV float tanhf_(float x){
    x = fminf(15.0f, fmaxf(-15.0f, x));
    float e = __expf(2.0f*x);
    return (e - 1.0f)/(e + 1.0f);
}
DEV unsigned short f2bf(float f){
    unsigned u = __builtin_bit_cast(unsigned, f);
    unsigned r = (u + 0x7FFFu + ((u>>16)&1u)) >> 16;
    return (unsigned short)r;
}
DEV unsigned cvt_pk_bf16(float lo, float hi){
    unsigned r;
    asm("v_cvt_pk_bf16_f32 %0, %1, %2" : "=v"(r) : "v"(lo), "v"(hi));
    return r;
}
DEV unsigned swz(unsigned byte){ return byte ^ (((byte>>9)&1u)<<5); }

// ---------- conv weight pack: [256co][128ci][9tap] f32 -> [(ci/32)*9+tap][256co][32ci] bf16 ----------
__global__ __launch_bounds__(256)
void wprep_kernel(const float* __restrict__ w, unsigned short* __restrict__ wpk)
{
    int idx = blockIdx.x*256 + threadIdx.x;
    if (idx >= 256*128*9) return;
    int co  = idx / (128*9);
    int rem = idx - co*(128*9);
    int ci  = rem / 9;
    int tap = rem - ci*9;
    int kchunk = (ci>>5)*9 + tap;
    wpk[(kchunk*256 + co)*32 + (ci&31)] = f2bf(w[idx]);
}

// ---------- wz/wm pack to bf16 row-major ----------
__global__ __launch_bounds__(256)
void wzm_pack_kernel(const float* __restrict__ wz, const float* __restrict__ wm,
                     unsigned short* __restrict__ wzb, unsigned short* __restrict__ wmb)
{
    int idx = blockIdx.x*256 + threadIdx.x;
    if (idx < 128*128) wzb[idx] = f2bf(wz[idx]);
    int j = idx - 128*128;
    if (j >= 0 && j < 192*192) wmb[j] = f2bf(wm[j]);
}

// ---------- input pack: concat(in0,in1) [b][128ci][1024pix] f32 -> [b][1024pix][128ci] bf16 ----------
__global__ __launch_bounds__(256)
void packin_kernel(const float* __restrict__ in0, const float* __restrict__ in1,
                   unsigned short* __restrict__ outp)
{
    const int b  = blockIdx.y;
    const int p0 = blockIdx.x * 64;
    const int t  = threadIdx.x;
    __shared__ float tile[128][65];
    for (int k=t;k<8192;k+=256){
        int ci = k>>6, pp = k&63;
        const float* s = (ci<64) ? in0 + (b*64+ci)*1024 : in1 + (b*64+ci-64)*1024;
        tile[ci][pp] = s[p0+pp];
    }
    __syncthreads();
    for (int k=t;k<4096;k+=256){
        int pp = k>>6, c2 = k&63;
        ushort2v v;
        v.x = f2bf(tile[c2*2][pp]);
        v.y = f2bf(tile[c2*2+1][pp]);
        *reinterpret_cast<ushort2v*>(outp + ((b*1024+p0+pp)*128) + c2*2) = v;
    }
}

// ---------- implicit-GEMM 3x3 conv via MFMA ----------
__global__ __launch_bounds__(256)
void conv_mfma_kernel(const unsigned short* __restrict__ inp,
                      const unsigned short* __restrict__ wpk,
                      const float* __restrict__ bias,
                      float* __restrict__ out)
{
    const int b   = blockIdx.z;
    const int co0 = blockIdx.y * 64;
    const int r0  = blockIdx.x * 4;
    const int t   = threadIdx.x;
    const int l   = t & 63;
    const int wv  = t >> 6;
    const int l15 = l & 15;
    const int lhi = l >> 4;

    __shared__ __align__(16) unsigned short in_t[7168];

    f32x4 acc[4][2];
#pragma unroll
    for (int i=0;i<4;i++)
#pragma unroll
        for (int f=0;f<2;f++)
            acc[i][f] = (f32x4){0.f,0.f,0.f,0.f};

    for (int cic = 0; cic < 4; ++cic) {
        __syncthreads();
        for (int it = t; it < 816; it += 256) {
            int pixlin = it >> 2, oct = it & 3;
            int rr = pixlin / 34;
            int cc = pixlin - rr*34;
            int gr = r0 + rr - 1, gc = cc - 1;
            ushort8 v = {};
            if ((unsigned)gr < 32u && (unsigned)gc < 32u)
                v = *reinterpret_cast<const ushort8*>(
                        inp + ((b*1024 + gr*32 + gc)*128) + cic*32 + oct*8);
            unsigned byte = swz((unsigned)(pixlin*64 + oct*16));
            *reinterpret_cast<ushort8*>(reinterpret_cast<char*>(in_t) + byte) = v;
        }
        __syncthreads();
#pragma unroll
        for (int tap = 0; tap < 9; ++tap) {
            const int ky = tap/3, kx = tap - 3*(tap/3);
            const unsigned short* wrow = wpk + ((cic*9 + tap)*256 + co0)*32;
            bf16x8 af[4];
#pragma unroll
            for (int i=0;i<4;i++)
                af[i] = *reinterpret_cast<const bf16x8*>(wrow + (i*16 + l15)*32 + lhi*8);
            bf16x8 bfr[2];
#pragma unroll
            for (int f=0;f<2;f++){
                int pixlin = (wv + ky)*34 + (f*16 + l15 + kx);
                unsigned byte = swz((unsigned)(pixlin*64 + lhi*16));
                bfr[f] = *reinterpret_cast<const bf16x8*>(
                             reinterpret_cast<const char*>(in_t) + byte);
            }
#pragma unroll
            for (int i=0;i<4;i++)
#pragma unroll
                for (int f=0;f<2;f++)
                    acc[i][f] = __builtin_amdgcn_mfma_f32_16x16x32_bf16(af[i], bfr[f], acc[i][f], 0, 0, 0);
        }
    }
    const int orow = r0 + wv;
#pragma unroll
    for (int i=0;i<4;i++){
        int cobase = co0 + i*16 + lhi*4;
#pragma unroll
        for (int f=0;f<2;f++){
            int col = orow*32 + f*16 + l15;
#pragma unroll
            for (int r=0;r<4;r++)
                out[(b*256 + cobase + r)*1024 + col] = acc[i][f][r] + bias[cobase+r];
        }
    }
}

// ---------- GN + first gate block ----------
__global__ __launch_bounds__(256)
void gn_gate1_kernel(const float* __restrict__ cc, const float* __restrict__ gnw,
                     const float* __restrict__ gnb, const float* __restrict__ c_in,
                     float* __restrict__ c_tmp, float* __restrict__ sig_co)
{
    const int ch = blockIdx.x;
    const int b  = blockIdx.y;
    const int t  = threadIdx.x;
    __shared__ float red[4][8];

    float v[4][4];
    float scale[4], shift[4];
#pragma unroll
    for (int g=0; g<4; g++) {
        const float* src = cc + (b*256 + g*64 + ch)*1024;
        float ls = 0.f, lq = 0.f;
#pragma unroll
        for (int k=0;k<4;k++){
            float x = src[t + 256*k];
            v[g][k] = x; ls += x; lq += x*x;
        }
#pragma unroll
        for (int off=32; off>0; off>>=1){ ls += __shfl_xor(ls, off); lq += __shfl_xor(lq, off); }
        if ((t & 63) == 0){ red[t>>6][g] = ls; red[t>>6][4+g] = lq; }
    }
    __syncthreads();
#pragma unroll
    for (int g=0; g<4; g++) {
        float s = red[0][g]+red[1][g]+red[2][g]+red[3][g];
        float q = red[0][4+g]+red[1][4+g]+red[2][4+g]+red[3][4+g];
        float mu  = s * (1.0f/1024.0f);
        float var = q * (1.0f/1024.0f) - mu*mu;
        float rs  = rsqrtf(var + 1e-5f);
        float gw  = gnw[g*64+ch];
        scale[g] = rs*gw;
        shift[g] = gnb[g*64+ch] - mu*rs*gw;
    }
    const float* cp = c_in   + (b*64+ch)*1024;
    float* ct = c_tmp  + (b*64+ch)*1024;
    float* so = sig_co + (b*64+ch)*1024;
#pragma unroll
    for (int k=0;k<4;k++){
        int p = t + 256*k;
        float ni = v[0][k]*scale[0] + shift[0];
        float nf = v[1][k]*scale[1] + shift[1];
        float no = v[2][k]*scale[2] + shift[2];
        float ng = v[3][k]*scale[3] + shift[3];
        ct[p] = sigmoidf_(nf)*cp[p] + sigmoidf_(ni)*tanhf_(ng);
        so[p] = sigmoidf_(no);
    }
}

// ---------- GN + second (long) gate block ----------
__global__ __launch_bounds__(256)
void gn_gate2_kernel(const float* __restrict__ cc, const float* __restrict__ gnw,
                     const float* __restrict__ gnb, const float* __restrict__ lc_in,
                     const float* __restrict__ sig_co,
                     float* __restrict__ out_lc, float* __restrict__ out_c,
                     float* __restrict__ h_mid)
{
    const int ch = blockIdx.x;
    const int b  = blockIdx.y;
    const int t  = threadIdx.x;
    __shared__ float red[4][8];

    float v[4][4];
    float scale[4], shift[4];
#pragma unroll
    for (int g=0; g<4; g++) {
        const float* src = cc + (b*256 + g*64 + ch)*1024;
        float ls = 0.f, lq = 0.f;
#pragma unroll
        for (int k=0;k<4;k++){
            float x = src[t + 256*k];
            v[g][k] = x; ls += x; lq += x*x;
        }
#pragma unroll
        for (int off=32; off>0; off>>=1){ ls += __shfl_xor(ls, off); lq += __shfl_xor(lq, off); }
        if ((t & 63) == 0){ red[t>>6][g] = ls; red[t>>6][4+g] = lq; }
    }
    __syncthreads();
#pragma unroll
    for (int g=0; g<4; g++) {
        float s = red[0][g]+red[1][g]+red[2][g]+red[3][g];
        float q = red[0][4+g]+red[1][4+g]+red[2][4+g]+red[3][4+g];
        float mu  = s * (1.0f/1024.0f);
        float var = q * (1.0f/1024.0f) - mu*mu;
        float rs  = rsqrtf(var + 1e-5f);
        float gw  = gnw[g*64+ch];
        scale[g] = rs*gw;
        shift[g] = gnb[g*64+ch] - mu*rs*gw;
    }
    const float* lp = lc_in  + (b*64+ch)*1024;
    const float* so = sig_co + (b*64+ch)*1024;
    float* olc = out_lc + (b*64+ch)*1024;
    float* oc  = out_c  + (b*64+ch)*1024;
    float* ohm = h_mid  + (b*64+ch)*1024;
#pragma unroll
    for (int k=0;k<4;k++){
        int p = t + 256*k;
        float ni = v[0][k]*scale[0] + shift[0];
        float nf = v[1][k]*scale[1] + shift[1];
        float no = v[2][k]*scale[2] + shift[2];
        float ng = v[3][k]*scale[3] + shift[3];
        float lcn = sigmoidf_(nf)*lp[p] + sigmoidf_(ni)*tanhf_(ng);
        float cf  = sigmoidf_(no)*tanhf_(lcn);
        olc[p] = lcn;
        oc[p]  = cf;
        ohm[p] = so[p]*tanhf_(cf);
    }
}

// ---------- fused 1x1 projections -> bf16 MFMA layouts (+ h_midT bf16) ----------
__global__ __launch_bounds__(256)
void proj_kernel(const float* __restrict__ h_mid, const float* __restrict__ m_in,
                 const float* __restrict__ wq, const float* __restrict__ bq,
                 const float* __restrict__ wk, const float* __restrict__ bk,
                 const float* __restrict__ wk2, const float* __restrict__ bk2,
                 const float* __restrict__ wv, const float* __restrict__ bv,
                 const float* __restrict__ wv2, const float* __restrict__ bv2,
                 unsigned short* __restrict__ Qb, unsigned short* __restrict__ Khb,
                 unsigned short* __restrict__ Kmb,
                 unsigned short* __restrict__ Vhb, unsigned short* __restrict__ Vmb,
                 unsigned short* __restrict__ hT)
{
    const int b  = blockIdx.y;
    const int p0 = blockIdx.x * 64;
    const int t  = threadIdx.x;
    __shared__ float hs[64*64];
    __shared__ float ms[64*64];
    for (int k=t;k<4096;k+=256){
        int cch = k>>6, pp = k&63;
        hs[k] = h_mid[(b*64+cch)*1024 + p0+pp];
        ms[k] = m_in [(b*64+cch)*1024 + p0+pp];
    }
    __syncthreads();
    const int p = t & 63;
    const int g = __builtin_amdgcn_readfirstlane(t >> 6);

#pragma unroll
    for (int e=0;e<2;e++){
        int oct = (t>>6) + e*4;
        ushort8 v;
#pragma unroll
        for (int j=0;j<8;j++) v[j] = f2bf(hs[(oct*8+j)*64 + p]);
        *reinterpret_cast<ushort8*>(hT + (size_t)(b*1024+p0+p)*64 + oct*8) = v;
    }

    {
        float aq[8], ak[8], av[16];
#pragma unroll
        for (int j=0;j<8;j++){ aq[j]=bq[g*8+j]; ak[j]=bk[g*8+j]; }
#pragma unroll
        for (int j=0;j<16;j++) av[j]=bv[g*16+j];
        for (int cc=0;cc<64;cc++){
            float x = hs[cc*64+p];
#pragma unroll
            for (int j=0;j<8;j++)  aq[j] = fmaf(wq[(g*8+j)*64+cc],  x, aq[j]);
#pragma unroll
            for (int j=0;j<8;j++)  ak[j] = fmaf(wk[(g*8+j)*64+cc],  x, ak[j]);
#pragma unroll
            for (int j=0;j<16;j++) av[j] = fmaf(wv[(g*16+j)*64+cc], x, av[j]);
        }
        ushort8 vq, vk;
#pragma unroll
        for (int j=0;j<8;j++){ vq[j]=f2bf(aq[j]); vk[j]=f2bf(ak[j]); }
        *reinterpret_cast<ushort8*>(Qb  + (size_t)(b*1024+p0+p)*32 + g*8) = vq;
        *reinterpret_cast<ushort8*>(Khb + (size_t)(b*1024+p0+p)*32 + g*8) = vk;
#pragma unroll
        for (int j=0;j<16;j++)
            Vhb[(size_t)(b*64 + g*16+j)*1024 + p0+p] = f2bf(av[j]);
    }
    {
        float ak[8], av[16];
#pragma unroll
        for (int j=0;j<8;j++)  ak[j]=bk2[g*8+j];
#pragma unroll
        for (int j=0;j<16;j++) av[j]=bv2[g*16+j];
        for (int cc=0;cc<64;cc++){
            float x = ms[cc*64+p];
#pragma unroll
            for (int j=0;j<8;j++)  ak[j] = fmaf(wk2[(g*8+j)*64+cc],  x, ak[j]);
#pragma unroll
            for (int j=0;j<16;j++) av[j] = fmaf(wv2[(g*16+j)*64+cc], x, av[j]);
        }
        ushort8 vk;
#pragma unroll
        for (int j=0;j<8;j++) vk[j]=f2bf(ak[j]);
        *reinterpret_cast<ushort8*>(Kmb + (size_t)(b*1024+p0+p)*32 + g*8) = vk;
#pragma unroll
        for (int j=0;j<16;j++)
            Vmb[(size_t)(b*64 + g*16+j)*1024 + p0+p] = f2bf(av[j]);
    }
}

// ---------- MFMA flash attention (S^T swapped-operand, in-register softmax) ----------
// Q/K: [b][1024][32] bf16, V: [b][64][1024] bf16, ZT: [b][1024p][128c] bf16
__global__ __launch_bounds__(256)
void attn_mfma_kernel(const unsigned short* __restrict__ Qb,
                      const unsigned short* __restrict__ Kh,
                      const unsigned short* __restrict__ Km,
                      const unsigned short* __restrict__ Vh,
                      const unsigned short* __restrict__ Vm,
                      unsigned short* __restrict__ ZT)
{
    const int bid   = blockIdx.x;
    const int xcd   = bid & 7;
    const int slot  = bid >> 3;
    const int b     = xcd*2 + (slot>>5);
    const int pass  = (slot>>4) & 1;
    const int p0    = (slot & 15) * 64;
    const int t   = threadIdx.x;
    const int l   = t & 63;
    const int w   = t >> 6;
    const int l15 = l & 15, g = l >> 4;

    __shared__ __align__(16) unsigned short Kt[2][2560];   // [64q][32a+8pad] (80B rows)
    __shared__ __align__(16) unsigned short Vt[2][4096];   // [64c][64q] XOR-swizzled
    __shared__ __align__(16) unsigned short Pt[4096];      // [64p][64q] XOR-swizzled, per-wave rows

    const unsigned short* Kg = pass ? Km : Kh;
    const unsigned short* Vg = pass ? Vm : Vh;

    // Q fragment: serves as MFMA **B** operand (col p = l15, k-chunk a = g*8..+7)
    const bf16x8 qa = *reinterpret_cast<const bf16x8*>(
        Qb + (size_t)(b*1024 + p0 + w*16 + l15)*32 + g*8);

    // per-lane online softmax state for p = p0 + w*16 + l15 (uniform across g)
    float m_run = -1e30f, l_run = 0.0f;
    f32x4 acc[4];   // rows p' = g*4+r, cols c = cf*16+l15
#pragma unroll
    for (int cf=0;cf<4;cf++) acc[cf] = (f32x4){0.f,0.f,0.f,0.f};

    const int krow = t>>2, koct = t&3;
    const int vrow = t>>3, voct = t&7;
    const unsigned kwb  = (unsigned)(krow*80 + koct*16);
    const unsigned vwb0 = (unsigned)(vrow*128)      + (((unsigned)voct*16) ^ ((unsigned)(vrow&7)<<4));
    const unsigned vwb1 = (unsigned)((vrow+32)*128) + (((unsigned)voct*16) ^ ((unsigned)((vrow+32)&7)<<4));

    // prologue: tile 0
    ushort8 kreg = *reinterpret_cast<const ushort8*>(Kg + (size_t)(b*1024 + krow)*32 + koct*8);
    ushort8 vr0  = *reinterpret_cast<const ushort8*>(Vg + (size_t)(b*64 + vrow)*1024 + voct*8);
    ushort8 vr1  = *reinterpret_cast<const ushort8*>(Vg + (size_t)(b*64 + vrow+32)*1024 + voct*8);
    *reinterpret_cast<ushort8*>(reinterpret_cast<char*>(Kt[0]) + kwb)  = kreg;
    *reinterpret_cast<ushort8*>(reinterpret_cast<char*>(Vt[0]) + vwb0) = vr0;
    *reinterpret_cast<ushort8*>(reinterpret_cast<char*>(Vt[0]) + vwb1) = vr1;
    __syncthreads();

    for (int it=0; it<16; ++it){
        const int cur = it & 1;
        if (it < 15){
            const int q0n = (it+1)*64;
            kreg = *reinterpret_cast<const ushort8*>(Kg + (size_t)(b*1024 + q0n + krow)*32 + koct*8);
            vr0  = *reinterpret_cast<const ushort8*>(Vg + (size_t)(b*64 + vrow)*1024 + q0n + voct*8);
            vr1  = *reinterpret_cast<const ushort8*>(Vg + (size_t)(b*64 + vrow+32)*1024 + q0n + voct*8);
        }

        // S^T[q][p]: A = K (rows q), B = Q (cols p). Lane holds q = qt*16+g*4+r for p=l15.
        f32x4 s2[4];
#pragma unroll
        for (int qt=0; qt<4; qt++){
            const bf16x8 kb = *reinterpret_cast<const bf16x8*>(
                reinterpret_cast<const char*>(Kt[cur]) + (qt*16 + l15)*80 + g*16);
            s2[qt] = __builtin_amdgcn_mfma_f32_16x16x32_bf16(kb, qa, (f32x4){0.f,0.f,0.f,0.f}, 0,0,0);
        }

        // column max over 64 q: 15 in-lane + cross-g
        float pm = s2[0][0];
#pragma unroll
        for (int qt=0; qt<4; qt++)
#pragma unroll
            for (int r=0;r<4;r++) pm = fmaxf(pm, s2[qt][r]);
        pm = fmaxf(pm, __shfl_xor(pm, 16));
        pm = fmaxf(pm, __shfl_xor(pm, 32));

        // defer-max: rescale only when some column grew past m_run + 8
        if (!__all(pm <= m_run + 8.0f)){
            float mn = fmaxf(m_run, pm);
            float f  = __expf(m_run - mn);
            m_run = mn;
            l_run *= f;
#pragma unroll
            for (int r=0;r<4;r++){
                float fr = __shfl(f, (l & 48) | ((l>>4)*4 + r), 64);
#pragma unroll
                for (int cf=0;cf<4;cf++) acc[cf][r] *= fr;
            }
        }

        float e[4][4];
        float lsum = 0.f;
#pragma unroll
        for (int qt=0; qt<4; qt++)
#pragma unroll
            for (int r=0;r<4;r++){
                float ev = __expf(s2[qt][r] - m_run);
                e[qt][r] = ev;
                lsum += ev;
            }
        lsum += __shfl_xor(lsum, 16);
        lsum += __shfl_xor(lsum, 32);
        l_run += lsum;

        // P -> bf16, row-contiguous b64 writes (row = own p, cols q = qt*16+g*4..+3)
        const unsigned prow = (unsigned)(w*16 + l15);
        const unsigned psw  = (prow & 7u) << 4;
#pragma unroll
        for (int qt=0; qt<4; qt++){
            uint2v pk;
            pk.x = cvt_pk_bf16(e[qt][0], e[qt][1]);
            pk.y = cvt_pk_bf16(e[qt][2], e[qt][3]);
            unsigned byte = prow*128 + (((unsigned)(qt*32 + g*8)) ^ psw);
            *reinterpret_cast<uint2v*>(reinterpret_cast<char*>(Pt) + byte) = pk;
        }

        // PV: acc[p'][c] += P[p'][q] * V^T[q][c]
#pragma unroll
        for (int ks=0;ks<2;ks++){
            unsigned abyte = prow*128 + (((unsigned)(ks*64 + g*16)) ^ psw);
            const bf16x8 pa = *reinterpret_cast<const bf16x8*>(
                reinterpret_cast<const char*>(Pt) + abyte);
#pragma unroll
            for (int cf=0;cf<4;cf++){
                unsigned vrw = (unsigned)(cf*16 + l15);
                unsigned vbyte = vrw*128 + (((unsigned)(ks*64 + g*16)) ^ ((vrw&7u)<<4));
                const bf16x8 vb = *reinterpret_cast<const bf16x8*>(
                    reinterpret_cast<const char*>(Vt[cur]) + vbyte);
                acc[cf] = __builtin_amdgcn_mfma_f32_16x16x32_bf16(pa, vb, acc[cf], 0,0,0);
            }
        }

        if (it < 15){
            *reinterpret_cast<ushort8*>(reinterpret_cast<char*>(Kt[cur^1]) + kwb)  = kreg;
            *reinterpret_cast<ushort8*>(reinterpret_cast<char*>(Vt[cur^1]) + vwb0) = vr0;
            *reinterpret_cast<ushort8*>(reinterpret_cast<char*>(Vt[cur^1]) + vwb1) = vr1;
        }
        __syncthreads();
    }

    float rl = 1.0f / l_run;
    float rr[4];
#pragma unroll
    for (int r=0;r<4;r++) rr[r] = __shfl(rl, (l & 48) | ((l>>4)*4 + r), 64);
#pragma unroll
    for (int cf=0;cf<4;cf++)
#pragma unroll
        for (int r=0;r<4;r++)
            ZT[(size_t)(b*1024 + p0 + w*16 + g*4 + r)*128 + pass*64 + cf*16 + l15]
                = f2bf(acc[cf][r]*rr[r]);
}

// ---------- final via MFMA (32-pixel tiles): Z = wz*[Zh;Zm]+bz ; comb = wm*[Z;h]+bm ; gates ----------
__global__ __launch_bounds__(256)
void final_mfma_kernel(const unsigned short* __restrict__ ZT,
                       const unsigned short* __restrict__ hT,
                       const unsigned short* __restrict__ wzb,
                       const unsigned short* __restrict__ wmb,
                       const float* __restrict__ bz, const float* __restrict__ bm,
                       const float* __restrict__ m_in,
                       float* __restrict__ out_h, float* __restrict__ out_m)
{
    const int b  = blockIdx.y;
    const int p0 = blockIdx.x * 32;
    const int t  = threadIdx.x;
    const int l  = t & 63;
    const int w  = t >> 6;
    const int l15 = l & 15, g = l >> 4;

    __shared__ __align__(16) unsigned short Bs[32*192];   // [p][k], rows XOR-swizzled

    for (int it=t; it<512; it+=256){
        int row = it>>4, oct = it&15;
        ushort8 v = *reinterpret_cast<const ushort8*>(
            ZT + (size_t)(b*1024 + p0 + row)*128 + oct*8);
        unsigned byte = (unsigned)(row*384) + (((unsigned)oct*16) ^ ((unsigned)(row&7)<<4));
        *reinterpret_cast<ushort8*>(reinterpret_cast<char*>(Bs) + byte) = v;
    }
    {
        int row = t>>3, oct = t&7;
        ushort8 v = *reinterpret_cast<const ushort8*>(
            hT + (size_t)(b*1024 + p0 + row)*64 + oct*8);
        unsigned byte = (unsigned)(row*384) + 256u + (((unsigned)oct*16) ^ ((unsigned)(row&7)<<4));
        *reinterpret_cast<ushort8*>(reinterpret_cast<char*>(Bs) + byte) = v;
    }
    __syncthreads();

    // GEMM1: Z[128co][32pix], wave w owns co rows w*32..w*32+31
    f32x4 acc1[2][2];
#pragma unroll
    for (int i=0;i<2;i++)
#pragma unroll
        for (int cf=0;cf<2;cf++) acc1[i][cf] = (f32x4){0.f,0.f,0.f,0.f};
#pragma unroll
    for (int ks=0; ks<4; ++ks){
        bf16x8 af[2];
#pragma unroll
        for (int i=0;i<2;i++)
            af[i] = *reinterpret_cast<const bf16x8*>(
                wzb + (size_t)(w*32 + i*16 + l15)*128 + ks*32 + g*8);
#pragma unroll
        for (int cf=0;cf<2;cf++){
            unsigned p = (unsigned)(cf*16 + l15);
            unsigned byte = p*384 + (((unsigned)(ks*64 + g*16)) ^ ((p&7u)<<4));
            const bf16x8 bfr = *reinterpret_cast<const bf16x8*>(
                reinterpret_cast<const char*>(Bs) + byte);
            acc1[0][cf] = __builtin_amdgcn_mfma_f32_16x16x32_bf16(af[0], bfr, acc1[0][cf], 0,0,0);
            acc1[1][cf] = __builtin_amdgcn_mfma_f32_16x16x32_bf16(af[1], bfr, acc1[1][cf], 0,0,0);
        }
    }
    __syncthreads();
#pragma unroll
    for (int i=0;i<2;i++){
        int co = w*32 + i*16 + g*4;
#pragma unroll
        for (int cf=0;cf<2;cf++){
            unsigned p = (unsigned)(cf*16 + l15);
#pragma unroll
            for (int r=0;r<4;r++){
                float val = acc1[i][cf][r] + bz[co+r];
                unsigned byte = p*384 + (((unsigned)((co+r)*2)) ^ ((p&7u)<<4));
                *reinterpret_cast<unsigned short*>(reinterpret_cast<char*>(Bs) + byte) = f2bf(val);
            }
        }
    }
    __syncthreads();

    // GEMM2: comb[192][32pix], wave w owns rows {w*16, 64+w*16, 128+w*16}
    f32x4 acc2[3][2];
#pragma unroll
    for (int j=0;j<3;j++)
#pragma unroll
        for (int cf=0;cf<2;cf++) acc2[j][cf] = (f32x4){0.f,0.f,0.f,0.f};
#pragma unroll
    for (int ks=0; ks<6; ++ks){
        bf16x8 am[3];
#pragma unroll
        for (int j=0;j<3;j++)
            am[j] = *reinterpret_cast<const bf16x8*>(
                wmb + (size_t)(j*64 + w*16 + l15)*192 + ks*32 + g*8);
#pragma unroll
        for (int cf=0;cf<2;cf++){
            unsigned p = (unsigned)(cf*16 + l15);
            unsigned byte = p*384 + (((unsigned)(ks*64 + g*16)) ^ ((p&7u)<<4));
            const bf16x8 bfr = *reinterpret_cast<const bf16x8*>(
                reinterpret_cast<const char*>(Bs) + byte);
#pragma unroll
            for (int j=0;j<3;j++)
                acc2[j][cf] = __builtin_amdgcn_mfma_f32_16x16x32_bf16(am[j], bfr, acc2[j][cf], 0,0,0);
        }
    }

    const int ch0 = w*16 + g*4;
#pragma unroll
    for (int cf=0;cf<2;cf++){
        int pix = p0 + cf*16 + l15;
#pragma unroll
        for (int r=0;r<4;r++){
            int ch = ch0 + r;
            float mo = acc2[0][cf][r] + bm[ch];
            float mg = acc2[1][cf][r] + bm[64+ch];
            float mi = sigmoidf_(acc2[2][cf][r] + bm[128+ch]);
            float mv = m_in[(size_t)(b*64+ch)*1024 + pix];
            float mn = (1.0f - mi)*mv + mi*tanhf_(mg);
            out_m[(size_t)(b*64+ch)*1024 + pix] = mn;
            out_h[(size_t)(b*64+ch)*1024 + pix] = sigmoidf_(mo)*mn;
        }
    }
}

extern "C" void kernel_launch(void* const* d_in, const int* in_sizes, int n_in,
                              void* d_out, int out_size, void* d_ws, size_t ws_size,
                              hipStream_t stream)
{
    const float* x      = (const float*)d_in[0];
    const float* h      = (const float*)d_in[1];
    const float* c      = (const float*)d_in[2];
    const float* m      = (const float*)d_in[3];
    const float* lc     = (const float*)d_in[4];
    const float* conv_w = (const float*)d_in[5];
    const float* conv_b = (const float*)d_in[6];
    const float* gn1_w  = (const float*)d_in[7];
    const float* gn1_b  = (const float*)d_in[8];
    const float* convL_w= (const float*)d_in[9];
    const float* convL_b= (const float*)d_in[10];
    const float* gn2_w  = (const float*)d_in[11];
    const float* gn2_b  = (const float*)d_in[12];
    const float* wq  = (const float*)d_in[13];
    const float* bq  = (const float*)d_in[14];
    const float* wk  = (const float*)d_in[15];
    const float* bk  = (const float*)d_in[16];
    const float* wk2 = (const float*)d_in[17];
    const float* bk2 = (const float*)d_in[18];
    const float* wv  = (const float*)d_in[19];
    const float* bv  = (const float*)d_in[20];
    const float* wv2 = (const float*)d_in[21];
    const float* bv2 = (const float*)d_in[22];
    const float* wz  = (const float*)d_in[23];
    const float* bz  = (const float*)d_in[24];
    const float* wmw = (const float*)d_in[25];
    const float* bm  = (const float*)d_in[26];

    float* out = (float*)d_out;
    float* F = (float*)d_ws;
    float* cc_raw = F;                           // 4,194,304
    float* c_tmp  = F + 4194304;                 // 1,048,576
    float* sig_co = F + 5242880;                 // 1,048,576
    float* h_mid  = F + 6291456;                 // 1,048,576
    unsigned short* buf1 = (unsigned short*)(F + 7340032);   // conv1 in; later ZT
    unsigned short* ZT   = buf1;                              // [16][1024][128] bf16
    unsigned short* buf2 = (unsigned short*)(F + 8388608);   // conv2 in; later hT
    unsigned short* hT   = buf2;                              // [16][1024][64] bf16
    unsigned short* Qb   = (unsigned short*)(F + 9437184);
    unsigned short* Khb  = (unsigned short*)(F + 9699328);
    unsigned short* Kmb  = (unsigned short*)(F + 9961472);
    unsigned short* Vhb  = (unsigned short*)(F + 10223616);
    unsigned short* Vmb  = (unsigned short*)(F + 10747904);
    unsigned short* wpk1 = (unsigned short*)(F + 11272192);
    unsigned short* wpk2 = (unsigned short*)(F + 11419648);
    unsigned short* wzb  = (unsigned short*)(F + 11567104);
    unsigned short* wmb  = (unsigned short*)(F + 11575296);

    dim3 blk256(256);
    wprep_kernel<<<dim3(1152), blk256, 0, stream>>>(conv_w,  wpk1);
    wprep_kernel<<<dim3(1152), blk256, 0, stream>>>(convL_w, wpk2);
    wzm_pack_kernel<<<dim3(208), blk256, 0, stream>>>(wz, wmw, wzb, wmb);
    packin_kernel<<<dim3(16,16), blk256, 0, stream>>>(x, h, buf1);

    dim3 cgrid(8, 4, 16);
    conv_mfma_kernel<<<cgrid, blk256, 0, stream>>>(buf1, wpk1, conv_b, cc_raw);
    gn_gate1_kernel<<<dim3(64,16), blk256, 0, stream>>>(cc_raw, gn1_w, gn1_b, c, c_tmp, sig_co);
    packin_kernel<<<dim3(16,16), blk256, 0, stream>>>(h, c_tmp, buf2);
    conv_mfma_kernel<<<cgrid, blk256, 0, stream>>>(buf2, wpk2, convL_b, cc_raw);
    gn_gate2_kernel<<<dim3(64,16), blk256, 0, stream>>>(cc_raw, gn2_w, gn2_b, lc, sig_co,
                                                        out + 3*1048576 /*lc_next*/,
                                                        out + 1*1048576 /*c_next*/,
                                                        h_mid);
    proj_kernel<<<dim3(16,16), blk256, 0, stream>>>(h_mid, m, wq,bq, wk,bk, wk2,bk2,
                                                    wv,bv, wv2,bv2, Qb, Khb, Kmb, Vhb, Vmb, hT);
    attn_mfma_kernel<<<dim3(512), blk256, 0, stream>>>(Qb, Khb, Kmb, Vhb, Vmb, ZT);
    final_mfma_kernel<<<dim3(32,16), blk256, 0, stream>>>(ZT, hT, wzb, wmb, bz, bm, m,
                                                          out /*h_next*/, out + 2*1048576 /*m_next*/);
    (void)in_sizes; (void)n_in; (void)out_size; (void)ws_size;
}

// Round 6
// 146.123 us; speedup vs baseline: 7.2251x; 1.1824x over previous
//
#include <hip/hip_runtime.h>

#define DEV __device__ __forceinline__

typedef __attribute__((ext_vector_type(8))) __bf16 bf16x8;
typedef __attribute__((ext_vector_type(4))) float f32x4;
typedef __attribute__((ext_vector_type(8))) unsigned short ushort8;
typedef __attribute__((ext_vector_type(2))) unsigned short ushort2v;
typedef __attribute__((ext_vector_type(2))) unsigned int uint2v;

DEV float sigmoidf_(float x){ return 1.0f/(1.0f + __expf(-x)); }
DEV float tanhf_(float x){
    x = fminf(15.0f, fmaxf(-15.0f, x));
    float e = __expf(2.0f*x);
    return (e - 1.0f)/(e + 1.0f);
}
DEV unsigned short f2bf(float f){
    unsigned u = __builtin_bit_cast(unsigned, f);
    unsigned r = (u + 0x7FFFu + ((u>>16)&1u)) >> 16;
    return (unsigned short)r;
}
DEV float bf2f(unsigned short u){
    return __builtin_bit_cast(float, ((unsigned)u)<<16);
}
DEV unsigned cvt_pk_bf16(float lo, float hi){
    unsigned r;
    asm("v_cvt_pk_bf16_f32 %0, %1, %2" : "=v"(r) : "v"(lo), "v"(hi));
    return r;
}
DEV unsigned swz(unsigned byte){ return byte ^ (((byte>>9)&1u)<<5); }

// ---------- merged weight prep: conv weights -> wpk1/wpk2 ; wz/wm -> bf16 ----------
// conv pack: [256co][128ci][9tap] f32 -> [(ci/32)*9+tap][256co][32ci] bf16
__global__ __launch_bounds__(256)
void prep_kernel(const float* __restrict__ conv_w, const float* __restrict__ convL_w,
                 const float* __restrict__ wz, const float* __restrict__ wm,
                 unsigned short* __restrict__ wpk1, unsigned short* __restrict__ wpk2,
                 unsigned short* __restrict__ wzb, unsigned short* __restrict__ wmb)
{
    int idx = blockIdx.x*256 + threadIdx.x;
    if (idx < 256*128*9) {
        int co  = idx / (128*9);
        int rem = idx - co*(128*9);
        int ci  = rem / 9;
        int tap = rem - ci*9;
        int kchunk = (ci>>5)*9 + tap;
        int o = (kchunk*256 + co)*32 + (ci&31);
        wpk1[o] = f2bf(conv_w[idx]);
        wpk2[o] = f2bf(convL_w[idx]);
    }
    if (idx < 128*128) wzb[idx] = f2bf(wz[idx]);
    if (idx < 192*192) wmb[idx] = f2bf(wm[idx]);
}

// ---------- input pack: concat(in0,in1) [b][128ci][1024pix] f32 -> [b][1024pix][128ci] bf16 ----------
__global__ __launch_bounds__(256)
void packin_kernel(const float* __restrict__ in0, const float* __restrict__ in1,
                   unsigned short* __restrict__ outp)
{
    const int b  = blockIdx.y;
    const int p0 = blockIdx.x * 64;
    const int t  = threadIdx.x;
    __shared__ float tile[128][65];
    for (int k=t;k<8192;k+=256){
        int ci = k>>6, pp = k&63;
        const float* s = (ci<64) ? in0 + (b*64+ci)*1024 : in1 + (b*64+ci-64)*1024;
        tile[ci][pp] = s[p0+pp];
    }
    __syncthreads();
    for (int k=t;k<4096;k+=256){
        int pp = k>>6, c2 = k&63;
        ushort2v v;
        v.x = f2bf(tile[c2*2][pp]);
        v.y = f2bf(tile[c2*2+1][pp]);
        *reinterpret_cast<ushort2v*>(outp + ((b*1024+p0+pp)*128) + c2*2) = v;
    }
}

// ---------- implicit-GEMM 3x3 conv via MFMA (single-stage LDS, 1 barrier) ----------
// inp: [16][1024pix][128ci] bf16 ; wpk: [36][256co][32] bf16 ; out: [16][256][1024] bf16
__global__ __launch_bounds__(256)
void conv_mfma_kernel(const unsigned short* __restrict__ inp,
                      const unsigned short* __restrict__ wpk,
                      const float* __restrict__ bias,
                      unsigned short* __restrict__ out)
{
    const int b   = blockIdx.z;
    const int co0 = blockIdx.y * 64;
    const int r0  = blockIdx.x * 4;
    const int t   = threadIdx.x;
    const int l   = t & 63;
    const int wv  = t >> 6;
    const int l15 = l & 15;
    const int lhi = l >> 4;

    // 204 pixlin rows (6 input rows x 34 cols) x 128 ci, XOR-swizzled, 52224 B
    __shared__ __align__(16) unsigned short in_t[26112];

    // stage entire patch once: 3264 x 16B transfers
    for (int it = t; it < 3264; it += 256) {
        int pixlin = it >> 4, oct = it & 15;
        int rr = pixlin / 34;
        int cc = pixlin - rr*34;
        int gr = r0 + rr - 1, gc = cc - 1;
        ushort8 v = {};
        if ((unsigned)gr < 32u && (unsigned)gc < 32u)
            v = *reinterpret_cast<const ushort8*>(
                    inp + ((b*1024 + gr*32 + gc)*128) + oct*8);
        unsigned byte = (unsigned)(pixlin*256 + oct*16) ^ (((unsigned)pixlin & 7u) << 4);
        *reinterpret_cast<ushort8*>(reinterpret_cast<char*>(in_t) + byte) = v;
    }

    f32x4 acc[4][2];
#pragma unroll
    for (int i=0;i<4;i++)
#pragma unroll
        for (int f=0;f<2;f++)
            acc[i][f] = (f32x4){0.f,0.f,0.f,0.f};

    __syncthreads();

    for (int cic = 0; cic < 4; ++cic) {
#pragma unroll
        for (int tap = 0; tap < 9; ++tap) {
            const int ky = tap/3, kx = tap - 3*(tap/3);
            const unsigned short* wrow = wpk + ((cic*9 + tap)*256 + co0)*32;
            bf16x8 af[4];
#pragma unroll
            for (int i=0;i<4;i++)
                af[i] = *reinterpret_cast<const bf16x8*>(wrow + (i*16 + l15)*32 + lhi*8);
            bf16x8 bfr[2];
#pragma unroll
            for (int f=0;f<2;f++){
                int pixlin = (wv + ky)*34 + (f*16 + l15 + kx);
                unsigned byte = (unsigned)(pixlin*256 + cic*64 + lhi*16)
                                ^ (((unsigned)pixlin & 7u) << 4);
                bfr[f] = *reinterpret_cast<const bf16x8*>(
                             reinterpret_cast<const char*>(in_t) + byte);
            }
#pragma unroll
            for (int i=0;i<4;i++)
#pragma unroll
                for (int f=0;f<2;f++)
                    acc[i][f] = __builtin_amdgcn_mfma_f32_16x16x32_bf16(af[i], bfr[f], acc[i][f], 0, 0, 0);
        }
    }
    const int orow = r0 + wv;
#pragma unroll
    for (int i=0;i<4;i++){
        int cobase = co0 + i*16 + lhi*4;
#pragma unroll
        for (int f=0;f<2;f++){
            int col = orow*32 + f*16 + l15;
#pragma unroll
            for (int r=0;r<4;r++)
                out[(b*256 + cobase + r)*1024 + col] = f2bf(acc[i][f][r] + bias[cobase+r]);
        }
    }
}

// ---------- GN + first gate block (cc now bf16) ----------
__global__ __launch_bounds__(256)
void gn_gate1_kernel(const unsigned short* __restrict__ cc, const float* __restrict__ gnw,
                     const float* __restrict__ gnb, const float* __restrict__ c_in,
                     float* __restrict__ c_tmp, float* __restrict__ sig_co)
{
    const int ch = blockIdx.x;
    const int b  = blockIdx.y;
    const int t  = threadIdx.x;
    __shared__ float red[4][8];

    float v[4][4];
    float scale[4], shift[4];
#pragma unroll
    for (int g=0; g<4; g++) {
        const unsigned short* src = cc + (size_t)(b*256 + g*64 + ch)*1024;
        float ls = 0.f, lq = 0.f;
#pragma unroll
        for (int k=0;k<4;k++){
            float x = bf2f(src[t + 256*k]);
            v[g][k] = x; ls += x; lq += x*x;
        }
#pragma unroll
        for (int off=32; off>0; off>>=1){ ls += __shfl_xor(ls, off); lq += __shfl_xor(lq, off); }
        if ((t & 63) == 0){ red[t>>6][g] = ls; red[t>>6][4+g] = lq; }
    }
    __syncthreads();
#pragma unroll
    for (int g=0; g<4; g++) {
        float s = red[0][g]+red[1][g]+red[2][g]+red[3][g];
        float q = red[0][4+g]+red[1][4+g]+red[2][4+g]+red[3][4+g];
        float mu  = s * (1.0f/1024.0f);
        float var = q * (1.0f/1024.0f) - mu*mu;
        float rs  = rsqrtf(var + 1e-5f);
        float gw  = gnw[g*64+ch];
        scale[g] = rs*gw;
        shift[g] = gnb[g*64+ch] - mu*rs*gw;
    }
    const float* cp = c_in   + (b*64+ch)*1024;
    float* ct = c_tmp  + (b*64+ch)*1024;
    float* so = sig_co + (b*64+ch)*1024;
#pragma unroll
    for (int k=0;k<4;k++){
        int p = t + 256*k;
        float ni = v[0][k]*scale[0] + shift[0];
        float nf = v[1][k]*scale[1] + shift[1];
        float no = v[2][k]*scale[2] + shift[2];
        float ng = v[3][k]*scale[3] + shift[3];
        ct[p] = sigmoidf_(nf)*cp[p] + sigmoidf_(ni)*tanhf_(ng);
        so[p] = sigmoidf_(no);
    }
}

// ---------- GN + second (long) gate block (cc bf16) ----------
__global__ __launch_bounds__(256)
void gn_gate2_kernel(const unsigned short* __restrict__ cc, const float* __restrict__ gnw,
                     const float* __restrict__ gnb, const float* __restrict__ lc_in,
                     const float* __restrict__ sig_co,
                     float* __restrict__ out_lc, float* __restrict__ out_c,
                     float* __restrict__ h_mid)
{
    const int ch = blockIdx.x;
    const int b  = blockIdx.y;
    const int t  = threadIdx.x;
    __shared__ float red[4][8];

    float v[4][4];
    float scale[4], shift[4];
#pragma unroll
    for (int g=0; g<4; g++) {
        const unsigned short* src = cc + (size_t)(b*256 + g*64 + ch)*1024;
        float ls = 0.f, lq = 0.f;
#pragma unroll
        for (int k=0;k<4;k++){
            float x = bf2f(src[t + 256*k]);
            v[g][k] = x; ls += x; lq += x*x;
        }
#pragma unroll
        for (int off=32; off>0; off>>=1){ ls += __shfl_xor(ls, off); lq += __shfl_xor(lq, off); }
        if ((t & 63) == 0){ red[t>>6][g] = ls; red[t>>6][4+g] = lq; }
    }
    __syncthreads();
#pragma unroll
    for (int g=0; g<4; g++) {
        float s = red[0][g]+red[1][g]+red[2][g]+red[3][g];
        float q = red[0][4+g]+red[1][4+g]+red[2][4+g]+red[3][4+g];
        float mu  = s * (1.0f/1024.0f);
        float var = q * (1.0f/1024.0f) - mu*mu;
        float rs  = rsqrtf(var + 1e-5f);
        float gw  = gnw[g*64+ch];
        scale[g] = rs*gw;
        shift[g] = gnb[g*64+ch] - mu*rs*gw;
    }
    const float* lp = lc_in  + (b*64+ch)*1024;
    const float* so = sig_co + (b*64+ch)*1024;
    float* olc = out_lc + (b*64+ch)*1024;
    float* oc  = out_c  + (b*64+ch)*1024;
    float* ohm = h_mid  + (b*64+ch)*1024;
#pragma unroll
    for (int k=0;k<4;k++){
        int p = t + 256*k;
        float ni = v[0][k]*scale[0] + shift[0];
        float nf = v[1][k]*scale[1] + shift[1];
        float no = v[2][k]*scale[2] + shift[2];
        float ng = v[3][k]*scale[3] + shift[3];
        float lcn = sigmoidf_(nf)*lp[p] + sigmoidf_(ni)*tanhf_(ng);
        float cf  = sigmoidf_(no)*tanhf_(lcn);
        olc[p] = lcn;
        oc[p]  = cf;
        ohm[p] = so[p]*tanhf_(cf);
    }
}

// ---------- fused 1x1 projections -> bf16 MFMA layouts (+ h_midT bf16) ----------
__global__ __launch_bounds__(256)
void proj_kernel(const float* __restrict__ h_mid, const float* __restrict__ m_in,
                 const float* __restrict__ wq, const float* __restrict__ bq,
                 const float* __restrict__ wk, const float* __restrict__ bk,
                 const float* __restrict__ wk2, const float* __restrict__ bk2,
                 const float* __restrict__ wv, const float* __restrict__ bv,
                 const float* __restrict__ wv2, const float* __restrict__ bv2,
                 unsigned short* __restrict__ Qb, unsigned short* __restrict__ Khb,
                 unsigned short* __restrict__ Kmb,
                 unsigned short* __restrict__ Vhb, unsigned short* __restrict__ Vmb,
                 unsigned short* __restrict__ hT)
{
    const int b  = blockIdx.y;
    const int p0 = blockIdx.x * 64;
    const int t  = threadIdx.x;
    __shared__ float hs[64*64];
    __shared__ float ms[64*64];
    for (int k=t;k<4096;k+=256){
        int cch = k>>6, pp = k&63;
        hs[k] = h_mid[(b*64+cch)*1024 + p0+pp];
        ms[k] = m_in [(b*64+cch)*1024 + p0+pp];
    }
    __syncthreads();
    const int p = t & 63;
    const int g = __builtin_amdgcn_readfirstlane(t >> 6);

#pragma unroll
    for (int e=0;e<2;e++){
        int oct = (t>>6) + e*4;
        ushort8 v;
#pragma unroll
        for (int j=0;j<8;j++) v[j] = f2bf(hs[(oct*8+j)*64 + p]);
        *reinterpret_cast<ushort8*>(hT + (size_t)(b*1024+p0+p)*64 + oct*8) = v;
    }

    {
        float aq[8], ak[8], av[16];
#pragma unroll
        for (int j=0;j<8;j++){ aq[j]=bq[g*8+j]; ak[j]=bk[g*8+j]; }
#pragma unroll
        for (int j=0;j<16;j++) av[j]=bv[g*16+j];
        for (int cc=0;cc<64;cc++){
            float x = hs[cc*64+p];
#pragma unroll
            for (int j=0;j<8;j++)  aq[j] = fmaf(wq[(g*8+j)*64+cc],  x, aq[j]);
#pragma unroll
            for (int j=0;j<8;j++)  ak[j] = fmaf(wk[(g*8+j)*64+cc],  x, ak[j]);
#pragma unroll
            for (int j=0;j<16;j++) av[j] = fmaf(wv[(g*16+j)*64+cc], x, av[j]);
        }
        ushort8 vq, vk;
#pragma unroll
        for (int j=0;j<8;j++){ vq[j]=f2bf(aq[j]); vk[j]=f2bf(ak[j]); }
        *reinterpret_cast<ushort8*>(Qb  + (size_t)(b*1024+p0+p)*32 + g*8) = vq;
        *reinterpret_cast<ushort8*>(Khb + (size_t)(b*1024+p0+p)*32 + g*8) = vk;
#pragma unroll
        for (int j=0;j<16;j++)
            Vhb[(size_t)(b*64 + g*16+j)*1024 + p0+p] = f2bf(av[j]);
    }
    {
        float ak[8], av[16];
#pragma unroll
        for (int j=0;j<8;j++)  ak[j]=bk2[g*8+j];
#pragma unroll
        for (int j=0;j<16;j++) av[j]=bv2[g*16+j];
        for (int cc=0;cc<64;cc++){
            float x = ms[cc*64+p];
#pragma unroll
            for (int j=0;j<8;j++)  ak[j] = fmaf(wk2[(g*8+j)*64+cc],  x, ak[j]);
#pragma unroll
            for (int j=0;j<16;j++) av[j] = fmaf(wv2[(g*16+j)*64+cc], x, av[j]);
        }
        ushort8 vk;
#pragma unroll
        for (int j=0;j<8;j++) vk[j]=f2bf(ak[j]);
        *reinterpret_cast<ushort8*>(Kmb + (size_t)(b*1024+p0+p)*32 + g*8) = vk;
#pragma unroll
        for (int j=0;j<16;j++)
            Vmb[(size_t)(b*64 + g*16+j)*1024 + p0+p] = f2bf(av[j]);
    }
}

// ---------- MFMA flash attention (S^T swapped-operand, in-register softmax) ----------
__global__ __launch_bounds__(256)
void attn_mfma_kernel(const unsigned short* __restrict__ Qb,
                      const unsigned short* __restrict__ Kh,
                      const unsigned short* __restrict__ Km,
                      const unsigned short* __restrict__ Vh,
                      const unsigned short* __restrict__ Vm,
                      unsigned short* __restrict__ ZT)
{
    const int bid   = blockIdx.x;
    const int xcd   = bid & 7;
    const int slot  = bid >> 3;
    const int b     = xcd*2 + (slot>>5);
    const int pass  = (slot>>4) & 1;
    const int p0    = (slot & 15) * 64;
    const int t   = threadIdx.x;
    const int l   = t & 63;
    const int w   = t >> 6;
    const int l15 = l & 15, g = l >> 4;

    __shared__ __align__(16) unsigned short Kt[2][2560];
    __shared__ __align__(16) unsigned short Vt[2][4096];
    __shared__ __align__(16) unsigned short Pt[4096];

    const unsigned short* Kg = pass ? Km : Kh;
    const unsigned short* Vg = pass ? Vm : Vh;

    const bf16x8 qa = *reinterpret_cast<const bf16x8*>(
        Qb + (size_t)(b*1024 + p0 + w*16 + l15)*32 + g*8);

    float m_run = -1e30f, l_run = 0.0f;
    f32x4 acc[4];
#pragma unroll
    for (int cf=0;cf<4;cf++) acc[cf] = (f32x4){0.f,0.f,0.f,0.f};

    const int krow = t>>2, koct = t&3;
    const int vrow = t>>3, voct = t&7;
    const unsigned kwb  = (unsigned)(krow*80 + koct*16);
    const unsigned vwb0 = (unsigned)(vrow*128)      + (((unsigned)voct*16) ^ ((unsigned)(vrow&7)<<4));
    const unsigned vwb1 = (unsigned)((vrow+32)*128) + (((unsigned)voct*16) ^ ((unsigned)((vrow+32)&7)<<4));

    ushort8 kreg = *reinterpret_cast<const ushort8*>(Kg + (size_t)(b*1024 + krow)*32 + koct*8);
    ushort8 vr0  = *reinterpret_cast<const ushort8*>(Vg + (size_t)(b*64 + vrow)*1024 + voct*8);
    ushort8 vr1  = *reinterpret_cast<const ushort8*>(Vg + (size_t)(b*64 + vrow+32)*1024 + voct*8);
    *reinterpret_cast<ushort8*>(reinterpret_cast<char*>(Kt[0]) + kwb)  = kreg;
    *reinterpret_cast<ushort8*>(reinterpret_cast<char*>(Vt[0]) + vwb0) = vr0;
    *reinterpret_cast<ushort8*>(reinterpret_cast<char*>(Vt[0]) + vwb1) = vr1;
    __syncthreads();

    for (int it=0; it<16; ++it){
        const int cur = it & 1;
        if (it < 15){
            const int q0n = (it+1)*64;
            kreg = *reinterpret_cast<const ushort8*>(Kg + (size_t)(b*1024 + q0n + krow)*32 + koct*8);
            vr0  = *reinterpret_cast<const ushort8*>(Vg + (size_t)(b*64 + vrow)*1024 + q0n + voct*8);
            vr1  = *reinterpret_cast<const ushort8*>(Vg + (size_t)(b*64 + vrow+32)*1024 + q0n + voct*8);
        }

        f32x4 s2[4];
#pragma unroll
        for (int qt=0; qt<4; qt++){
            const bf16x8 kb = *reinterpret_cast<const bf16x8*>(
                reinterpret_cast<const char*>(Kt[cur]) + (qt*16 + l15)*80 + g*16);
            s2[qt] = __builtin_amdgcn_mfma_f32_16x16x32_bf16(kb, qa, (f32x4){0.f,0.f,0.f,0.f}, 0,0,0);
        }

        float pm = s2[0][0];
#pragma unroll
        for (int qt=0; qt<4; qt++)
#pragma unroll
            for (int r=0;r<4;r++) pm = fmaxf(pm, s2[qt][r]);
        pm = fmaxf(pm, __shfl_xor(pm, 16));
        pm = fmaxf(pm, __shfl_xor(pm, 32));

        if (!__all(pm <= m_run + 8.0f)){
            float mn = fmaxf(m_run, pm);
            float f  = __expf(m_run - mn);
            m_run = mn;
            l_run *= f;
#pragma unroll
            for (int r=0;r<4;r++){
                float fr = __shfl(f, (l & 48) | ((l>>4)*4 + r), 64);
#pragma unroll
                for (int cf=0;cf<4;cf++) acc[cf][r] *= fr;
            }
        }

        float e[4][4];
        float lsum = 0.f;
#pragma unroll
        for (int qt=0; qt<4; qt++)
#pragma unroll
            for (int r=0;r<4;r++){
                float ev = __expf(s2[qt][r] - m_run);
                e[qt][r] = ev;
                lsum += ev;
            }
        lsum += __shfl_xor(lsum, 16);
        lsum += __shfl_xor(lsum, 32);
        l_run += lsum;

        const unsigned prow = (unsigned)(w*16 + l15);
        const unsigned psw  = (prow & 7u) << 4;
#pragma unroll
        for (int qt=0; qt<4; qt++){
            uint2v pk;
            pk.x = cvt_pk_bf16(e[qt][0], e[qt][1]);
            pk.y = cvt_pk_bf16(e[qt][2], e[qt][3]);
            unsigned byte = prow*128 + (((unsigned)(qt*32 + g*8)) ^ psw);
            *reinterpret_cast<uint2v*>(reinterpret_cast<char*>(Pt) + byte) = pk;
        }

#pragma unroll
        for (int ks=0;ks<2;ks++){
            unsigned abyte = prow*128 + (((unsigned)(ks*64 + g*16)) ^ psw);
            const bf16x8 pa = *reinterpret_cast<const bf16x8*>(
                reinterpret_cast<const char*>(Pt) + abyte);
#pragma unroll
            for (int cf=0;cf<4;cf++){
                unsigned vrw = (unsigned)(cf*16 + l15);
                unsigned vbyte = vrw*128 + (((unsigned)(ks*64 + g*16)) ^ ((vrw&7u)<<4));
                const bf16x8 vb = *reinterpret_cast<const bf16x8*>(
                    reinterpret_cast<const char*>(Vt[cur]) + vbyte);
                acc[cf] = __builtin_amdgcn_mfma_f32_16x16x32_bf16(pa, vb, acc[cf], 0,0,0);
            }
        }

        if (it < 15){
            *reinterpret_cast<ushort8*>(reinterpret_cast<char*>(Kt[cur^1]) + kwb)  = kreg;
            *reinterpret_cast<ushort8*>(reinterpret_cast<char*>(Vt[cur^1]) + vwb0) = vr0;
            *reinterpret_cast<ushort8*>(reinterpret_cast<char*>(Vt[cur^1]) + vwb1) = vr1;
        }
        __syncthreads();
    }

    float rl = 1.0f / l_run;
    float rr[4];
#pragma unroll
    for (int r=0;r<4;r++) rr[r] = __shfl(rl, (l & 48) | ((l>>4)*4 + r), 64);
#pragma unroll
    for (int cf=0;cf<4;cf++)
#pragma unroll
        for (int r=0;r<4;r++)
            ZT[(size_t)(b*1024 + p0 + w*16 + g*4 + r)*128 + pass*64 + cf*16 + l15]
                = f2bf(acc[cf][r]*rr[r]);
}

// ---------- final via MFMA (32-pixel tiles) ----------
__global__ __launch_bounds__(256)
void final_mfma_kernel(const unsigned short* __restrict__ ZT,
                       const unsigned short* __restrict__ hT,
                       const unsigned short* __restrict__ wzb,
                       const unsigned short* __restrict__ wmb,
                       const float* __restrict__ bz, const float* __restrict__ bm,
                       const float* __restrict__ m_in,
                       float* __restrict__ out_h, float* __restrict__ out_m)
{
    const int b  = blockIdx.y;
    const int p0 = blockIdx.x * 32;
    const int t  = threadIdx.x;
    const int l  = t & 63;
    const int w  = t >> 6;
    const int l15 = l & 15, g = l >> 4;

    __shared__ __align__(16) unsigned short Bs[32*192];

    for (int it=t; it<512; it+=256){
        int row = it>>4, oct = it&15;
        ushort8 v = *reinterpret_cast<const ushort8*>(
            ZT + (size_t)(b*1024 + p0 + row)*128 + oct*8);
        unsigned byte = (unsigned)(row*384) + (((unsigned)oct*16) ^ ((unsigned)(row&7)<<4));
        *reinterpret_cast<ushort8*>(reinterpret_cast<char*>(Bs) + byte) = v;
    }
    {
        int row = t>>3, oct = t&7;
        ushort8 v = *reinterpret_cast<const ushort8*>(
            hT + (size_t)(b*1024 + p0 + row)*64 + oct*8);
        unsigned byte = (unsigned)(row*384) + 256u + (((unsigned)oct*16) ^ ((unsigned)(row&7)<<4));
        *reinterpret_cast<ushort8*>(reinterpret_cast<char*>(Bs) + byte) = v;
    }
    __syncthreads();

    f32x4 acc1[2][2];
#pragma unroll
    for (int i=0;i<2;i++)
#pragma unroll
        for (int cf=0;cf<2;cf++) acc1[i][cf] = (f32x4){0.f,0.f,0.f,0.f};
#pragma unroll
    for (int ks=0; ks<4; ++ks){
        bf16x8 af[2];
#pragma unroll
        for (int i=0;i<2;i++)
            af[i] = *reinterpret_cast<const bf16x8*>(
                wzb + (size_t)(w*32 + i*16 + l15)*128 + ks*32 + g*8);
#pragma unroll
        for (int cf=0;cf<2;cf++){
            unsigned p = (unsigned)(cf*16 + l15);
            unsigned byte = p*384 + (((unsigned)(ks*64 + g*16)) ^ ((p&7u)<<4));
            const bf16x8 bfr = *reinterpret_cast<const bf16x8*>(
                reinterpret_cast<const char*>(Bs) + byte);
            acc1[0][cf] = __builtin_amdgcn_mfma_f32_16x16x32_bf16(af[0], bfr, acc1[0][cf], 0,0,0);
            acc1[1][cf] = __builtin_amdgcn_mfma_f32_16x16x32_bf16(af[1], bfr, acc1[1][cf], 0,0,0);
        }
    }
    __syncthreads();
#pragma unroll
    for (int i=0;i<2;i++){
        int co = w*32 + i*16 + g*4;
#pragma unroll
        for (int cf=0;cf<2;cf++){
            unsigned p = (unsigned)(cf*16 + l15);
#pragma unroll
            for (int r=0;r<4;r++){
                float val = acc1[i][cf][r] + bz[co+r];
                unsigned byte = p*384 + (((unsigned)((co+r)*2)) ^ ((p&7u)<<4));
                *reinterpret_cast<unsigned short*>(reinterpret_cast<char*>(Bs) + byte) = f2bf(val);
            }
        }
    }
    __syncthreads();

    f32x4 acc2[3][2];
#pragma unroll
    for (int j=0;j<3;j++)
#pragma unroll
        for (int cf=0;cf<2;cf++) acc2[j][cf] = (f32x4){0.f,0.f,0.f,0.f};
#pragma unroll
    for (int ks=0; ks<6; ++ks){
        bf16x8 am[3];
#pragma unroll
        for (int j=0;j<3;j++)
            am[j] = *reinterpret_cast<const bf16x8*>(
                wmb + (size_t)(j*64 + w*16 + l15)*192 + ks*32 + g*8);
#pragma unroll
        for (int cf=0;cf<2;cf++){
            unsigned p = (unsigned)(cf*16 + l15);
            unsigned byte = p*384 + (((unsigned)(ks*64 + g*16)) ^ ((p&7u)<<4));
            const bf16x8 bfr = *reinterpret_cast<const bf16x8*>(
                reinterpret_cast<const char*>(Bs) + byte);
#pragma unroll
            for (int j=0;j<3;j++)
                acc2[j][cf] = __builtin_amdgcn_mfma_f32_16x16x32_bf16(am[j], bfr, acc2[j][cf], 0,0,0);
        }
    }

    const int ch0 = w*16 + g*4;
#pragma unroll
    for (int cf=0;cf<2;cf++){
        int pix = p0 + cf*16 + l15;
#pragma unroll
        for (int r=0;r<4;r++){
            int ch = ch0 + r;
            float mo = acc2[0][cf][r] + bm[ch];
            float mg = acc2[1][cf][r] + bm[64+ch];
            float mi = sigmoidf_(acc2[2][cf][r] + bm[128+ch]);
            float mv = m_in[(size_t)(b*64+ch)*1024 + pix];
            float mn = (1.0f - mi)*mv + mi*tanhf_(mg);
            out_m[(size_t)(b*64+ch)*1024 + pix] = mn;
            out_h[(size_t)(b*64+ch)*1024 + pix] = sigmoidf_(mo)*mn;
        }
    }
}

extern "C" void kernel_launch(void* const* d_in, const int* in_sizes, int n_in,
                              void* d_out, int out_size, void* d_ws, size_t ws_size,
                              hipStream_t stream)
{
    const float* x      = (const float*)d_in[0];
    const float* h      = (const float*)d_in[1];
    const float* c      = (const float*)d_in[2];
    const float* m      = (const float*)d_in[3];
    const float* lc     = (const float*)d_in[4];
    const float* conv_w = (const float*)d_in[5];
    const float* conv_b = (const float*)d_in[6];
    const float* gn1_w  = (const float*)d_in[7];
    const float* gn1_b  = (const float*)d_in[8];
    const float* convL_w= (const float*)d_in[9];
    const float* convL_b= (const float*)d_in[10];
    const float* gn2_w  = (const float*)d_in[11];
    const float* gn2_b  = (const float*)d_in[12];
    const float* wq  = (const float*)d_in[13];
    const float* bq  = (const float*)d_in[14];
    const float* wk  = (const float*)d_in[15];
    const float* bk  = (const float*)d_in[16];
    const float* wk2 = (const float*)d_in[17];
    const float* bk2 = (const float*)d_in[18];
    const float* wv  = (const float*)d_in[19];
    const float* bv  = (const float*)d_in[20];
    const float* wv2 = (const float*)d_in[21];
    const float* bv2 = (const float*)d_in[22];
    const float* wz  = (const float*)d_in[23];
    const float* bz  = (const float*)d_in[24];
    const float* wmw = (const float*)d_in[25];
    const float* bm  = (const float*)d_in[26];

    float* out = (float*)d_out;
    float* F = (float*)d_ws;
    unsigned short* cc_bf = (unsigned short*)F;               // [16][256][1024] bf16 (8MB)
    float* c_tmp  = F + 4194304;                 // 1,048,576
    float* sig_co = F + 5242880;                 // 1,048,576
    float* h_mid  = F + 6291456;                 // 1,048,576
    unsigned short* buf1 = (unsigned short*)(F + 7340032);   // conv1 in; later ZT
    unsigned short* ZT   = buf1;                              // [16][1024][128] bf16
    unsigned short* buf2 = (unsigned short*)(F + 8388608);   // conv2 in; later hT
    unsigned short* hT   = buf2;                              // [16][1024][64] bf16
    unsigned short* Qb   = (unsigned short*)(F + 9437184);
    unsigned short* Khb  = (unsigned short*)(F + 9699328);
    unsigned short* Kmb  = (unsigned short*)(F + 9961472);
    unsigned short* Vhb  = (unsigned short*)(F + 10223616);
    unsigned short* Vmb  = (unsigned short*)(F + 10747904);
    unsigned short* wpk1 = (unsigned short*)(F + 11272192);
    unsigned short* wpk2 = (unsigned short*)(F + 11419648);
    unsigned short* wzb  = (unsigned short*)(F + 11567104);
    unsigned short* wmb  = (unsigned short*)(F + 11575296);

    dim3 blk256(256);
    prep_kernel<<<dim3(1152), blk256, 0, stream>>>(conv_w, convL_w, wz, wmw,
                                                   wpk1, wpk2, wzb, wmb);
    packin_kernel<<<dim3(16,16), blk256, 0, stream>>>(x, h, buf1);

    dim3 cgrid(8, 4, 16);
    conv_mfma_kernel<<<cgrid, blk256, 0, stream>>>(buf1, wpk1, conv_b, cc_bf);
    gn_gate1_kernel<<<dim3(64,16), blk256, 0, stream>>>(cc_bf, gn1_w, gn1_b, c, c_tmp, sig_co);
    packin_kernel<<<dim3(16,16), blk256, 0, stream>>>(h, c_tmp, buf2);
    conv_mfma_kernel<<<cgrid, blk256, 0, stream>>>(buf2, wpk2, convL_b, cc_bf);
    gn_gate2_kernel<<<dim3(64,16), blk256, 0, stream>>>(cc_bf, gn2_w, gn2_b, lc, sig_co,
                                                        out + 3*1048576 /*lc_next*/,
                                                        out + 1*1048576 /*c_next*/,
                                                        h_mid);
    proj_kernel<<<dim3(16,16), blk256, 0, stream>>>(h_mid, m, wq,bq, wk,bk, wk2,bk2,
                                                    wv,bv, wv2,bv2, Qb, Khb, Kmb, Vhb, Vmb, hT);
    attn_mfma_kernel<<<dim3(512), blk256, 0, stream>>>(Qb, Khb, Kmb, Vhb, Vmb, ZT);
    final_mfma_kernel<<<dim3(32,16), blk256, 0, stream>>>(ZT, hT, wzb, wmb, bz, bm, m,
                                                          out /*h_next*/, out + 2*1048576 /*m_next*/);
    (void)in_sizes; (void)n_in; (void)out_size; (void)ws_size;
}

// Round 7
// 130.181 us; speedup vs baseline: 8.1098x; 1.1225x over previous
//
#include <hip/hip_runtime.h>

#define DEV __device__ __forceinline__

typedef __attribute__((ext_vector_type(8))) __bf16 bf16x8;
typedef __attribute__((ext_vector_type(4))) float f32x4;
typedef __attribute__((ext_vector_type(8))) unsigned short ushort8;
typedef __attribute__((ext_vector_type(2))) unsigned short ushort2v;
typedef __attribute__((ext_vector_type(2))) unsigned int uint2v;

DEV float sigmoidf_(float x){ return 1.0f/(1.0f + __expf(-x)); }
DEV float tanhf_(float x){
    x = fminf(15.0f, fmaxf(-15.0f, x));
    float e = __expf(2.0f*x);
    return (e - 1.0f)/(e + 1.0f);
}
DEV unsigned short f2bf(float f){
    unsigned u = __builtin_bit_cast(unsigned, f);
    unsigned r = (u + 0x7FFFu + ((u>>16)&1u)) >> 16;
    return (unsigned short)r;
}
DEV float bf2f(unsigned short u){
    return __builtin_bit_cast(float, ((unsigned)u)<<16);
}
DEV unsigned cvt_pk_bf16(float lo, float hi){
    unsigned r;
    asm("v_cvt_pk_bf16_f32 %0, %1, %2" : "=v"(r) : "v"(lo), "v"(hi));
    return r;
}

// ---------- merged prep: conv/proj/mix weights -> bf16 packs ; pack x,h -> buf1, h -> buf2-lo ----------
__global__ __launch_bounds__(256)
void prep_kernel(const float* __restrict__ conv_w, const float* __restrict__ convL_w,
                 const float* __restrict__ wz, const float* __restrict__ wm,
                 const float* __restrict__ wq, const float* __restrict__ wk,
                 const float* __restrict__ wv, const float* __restrict__ wk2,
                 const float* __restrict__ wv2,
                 const float* __restrict__ x, const float* __restrict__ h,
                 unsigned short* __restrict__ wpk1, unsigned short* __restrict__ wpk2,
                 unsigned short* __restrict__ wzb, unsigned short* __restrict__ wmb,
                 unsigned short* __restrict__ wph, unsigned short* __restrict__ wpm,
                 unsigned short* __restrict__ buf1, unsigned short* __restrict__ buf2)
{
    __shared__ float tile[128][65];
    if (blockIdx.x < 1152) {
        int idx = blockIdx.x*256 + threadIdx.x;
        {
            int co  = idx / (128*9);
            int rem = idx - co*(128*9);
            int ci  = rem / 9;
            int tap = rem - ci*9;
            int kchunk = (ci>>5)*9 + tap;
            int o = (kchunk*256 + co)*32 + (ci&31);
            wpk1[o] = f2bf(conv_w[idx]);
            wpk2[o] = f2bf(convL_w[idx]);
        }
        if (idx < 128*128) wzb[idx] = f2bf(wz[idx]);
        if (idx < 192*192) wmb[idx] = f2bf(wm[idx]);
        if (idx < 32*64){
            wph[idx]        = f2bf(wq[idx]);    // rows 0..31  : Q
            wph[2048 + idx] = f2bf(wk[idx]);    // rows 32..63 : K
            wpm[idx]        = f2bf(wk2[idx]);   // rows 0..31  : Km
        }
        if (idx < 64*64){
            wph[4096 + idx] = f2bf(wv[idx]);    // rows 64..127: V
            wpm[2048 + idx] = f2bf(wv2[idx]);   // rows 32..95 : Vm
        }
    } else {
        int bx = blockIdx.x - 1152;
        int b  = bx >> 4;
        int p0 = (bx & 15) * 64;
        int t  = threadIdx.x;
        for (int k=t;k<8192;k+=256){
            int ci = k>>6, pp = k&63;
            const float* s = (ci<64) ? x + (size_t)(b*64+ci)*1024
                                     : h + (size_t)(b*64+ci-64)*1024;
            tile[ci][pp] = s[p0+pp];
        }
        __syncthreads();
        for (int k=t;k<4096;k+=256){
            int pp = k>>6, c2 = k&63;
            ushort2v v;
            v.x = f2bf(tile[c2*2][pp]);
            v.y = f2bf(tile[c2*2+1][pp]);
            *reinterpret_cast<ushort2v*>(buf1 + (size_t)(b*1024+p0+pp)*128 + c2*2) = v;
            if (c2 >= 32)   // h channels -> buf2 lo half (conv2 ci 0..63)
                *reinterpret_cast<ushort2v*>(buf2 + (size_t)(b*1024+p0+pp)*128 + (c2-32)*2) = v;
        }
    }
}

// ---------- implicit-GEMM 3x3 conv via MFMA + per-block GN stat partials ----------
// inp: [16][1024pix][128ci] bf16 ; wpk: [36][256co][32] bf16 ; out: [16][256][1024] bf16
// stats: [16][256][8][2] f32 (sum, sumsq over this r0-block's 128 pixels)
__global__ __launch_bounds__(256)
void conv_mfma_kernel(const unsigned short* __restrict__ inp,
                      const unsigned short* __restrict__ wpk,
                      const float* __restrict__ bias,
                      unsigned short* __restrict__ out,
                      float* __restrict__ stats)
{
    const int b   = blockIdx.z;
    const int co0 = blockIdx.y * 64;
    const int r0  = blockIdx.x * 4;
    const int t   = threadIdx.x;
    const int l   = t & 63;
    const int wv  = t >> 6;
    const int l15 = l & 15;
    const int lhi = l >> 4;

    __shared__ __align__(16) unsigned short in_t[26112];  // 204 x 128ci, swizzled
    __shared__ float red_s[4][64];
    __shared__ float red_q[4][64];

    for (int it = t; it < 3264; it += 256) {
        int pixlin = it >> 4, oct = it & 15;
        int rr = pixlin / 34;
        int cc = pixlin - rr*34;
        int gr = r0 + rr - 1, gc = cc - 1;
        ushort8 v = {};
        if ((unsigned)gr < 32u && (unsigned)gc < 32u)
            v = *reinterpret_cast<const ushort8*>(
                    inp + ((size_t)(b*1024 + gr*32 + gc)*128) + oct*8);
        unsigned byte = (unsigned)(pixlin*256 + oct*16) ^ (((unsigned)pixlin & 7u) << 4);
        *reinterpret_cast<ushort8*>(reinterpret_cast<char*>(in_t) + byte) = v;
    }

    f32x4 acc[4][2];
#pragma unroll
    for (int i=0;i<4;i++)
#pragma unroll
        for (int f=0;f<2;f++)
            acc[i][f] = (f32x4){0.f,0.f,0.f,0.f};

    __syncthreads();

    for (int cic = 0; cic < 4; ++cic) {
#pragma unroll
        for (int tap = 0; tap < 9; ++tap) {
            const int ky = tap/3, kx = tap - 3*(tap/3);
            const unsigned short* wrow = wpk + ((cic*9 + tap)*256 + co0)*32;
            bf16x8 af[4];
#pragma unroll
            for (int i=0;i<4;i++)
                af[i] = *reinterpret_cast<const bf16x8*>(wrow + (i*16 + l15)*32 + lhi*8);
            bf16x8 bfr[2];
#pragma unroll
            for (int f=0;f<2;f++){
                int pixlin = (wv + ky)*34 + (f*16 + l15 + kx);
                unsigned byte = (unsigned)(pixlin*256 + cic*64 + lhi*16)
                                ^ (((unsigned)pixlin & 7u) << 4);
                bfr[f] = *reinterpret_cast<const bf16x8*>(
                             reinterpret_cast<const char*>(in_t) + byte);
            }
#pragma unroll
            for (int i=0;i<4;i++)
#pragma unroll
                for (int f=0;f<2;f++)
                    acc[i][f] = __builtin_amdgcn_mfma_f32_16x16x32_bf16(af[i], bfr[f], acc[i][f], 0, 0, 0);
        }
    }

    const int orow = r0 + wv;
    float s_ir[4][4], q_ir[4][4];
#pragma unroll
    for (int i=0;i<4;i++){
        int cobase = co0 + i*16 + lhi*4;
#pragma unroll
        for (int r=0;r<4;r++){
            float bs = bias[cobase+r];
            float e0 = acc[i][0][r] + bs;
            float e1 = acc[i][1][r] + bs;
            out[(size_t)(b*256 + cobase + r)*1024 + orow*32 + l15]      = f2bf(e0);
            out[(size_t)(b*256 + cobase + r)*1024 + orow*32 + 16 + l15] = f2bf(e1);
            s_ir[i][r] = e0 + e1;
            q_ir[i][r] = e0*e0 + e1*e1;
        }
    }
    // reduce over 16 pixel-lanes (l15) within each lhi group
#pragma unroll
    for (int i=0;i<4;i++)
#pragma unroll
        for (int r=0;r<4;r++){
            float s = s_ir[i][r], q = q_ir[i][r];
            s += __shfl_xor(s,1); q += __shfl_xor(q,1);
            s += __shfl_xor(s,2); q += __shfl_xor(q,2);
            s += __shfl_xor(s,4); q += __shfl_xor(q,4);
            s += __shfl_xor(s,8); q += __shfl_xor(q,8);
            s_ir[i][r] = s; q_ir[i][r] = q;
        }
    if (l15 == 0){
#pragma unroll
        for (int i=0;i<4;i++)
#pragma unroll
            for (int r=0;r<4;r++){
                red_s[wv][i*16 + lhi*4 + r] = s_ir[i][r];
                red_q[wv][i*16 + lhi*4 + r] = q_ir[i][r];
            }
    }
    __syncthreads();
    if (t < 64){
        float S = red_s[0][t]+red_s[1][t]+red_s[2][t]+red_s[3][t];
        float Q = red_q[0][t]+red_q[1][t]+red_q[2][t]+red_q[3][t];
        float* sp = stats + ((size_t)(b*256 + co0 + t)*8 + blockIdx.x)*2;
        sp[0] = S; sp[1] = Q;
    }
}

// ---------- GN gate1, pixel-tiled: gates -> buf2-hi (pixel-major bf16) + sig_pm ----------
__global__ __launch_bounds__(256)
void gn_gate1_kernel(const unsigned short* __restrict__ cc, const float* __restrict__ stats,
                     const float* __restrict__ gnw, const float* __restrict__ gnb,
                     const float* __restrict__ c_in,
                     unsigned short* __restrict__ buf2, unsigned short* __restrict__ sig_pm)
{
    const int b  = blockIdx.y;
    const int p0 = blockIdx.x * 64;
    const int t  = threadIdx.x;
    __shared__ float sc[256][2];
    __shared__ __align__(16) unsigned short cct[16384];   // [256ch][64p] swizzled

    {
        const float* sp = stats + (size_t)(b*256 + t)*16;
        float S=0.f, Q=0.f;
#pragma unroll
        for (int k=0;k<8;k++){ S += sp[2*k]; Q += sp[2*k+1]; }
        float mu  = S*(1.0f/1024.0f);
        float var = Q*(1.0f/1024.0f) - mu*mu;
        float rs  = rsqrtf(var + 1e-5f);
        float gw  = gnw[t];
        sc[t][0] = rs*gw;
        sc[t][1] = gnb[t] - mu*rs*gw;
    }
    for (int it=t; it<2048; it+=256){
        int row = it>>3, oct = it&7;
        ushort8 v = *reinterpret_cast<const ushort8*>(
            cc + (size_t)(b*256+row)*1024 + p0 + oct*8);
        unsigned byte = (unsigned)(row*128) + (((unsigned)oct*16) ^ ((unsigned)(row&7)<<4));
        *reinterpret_cast<ushort8*>(reinterpret_cast<char*>(cct) + byte) = v;
    }
    __syncthreads();

    const int p = t & 63, cg = t >> 6;
    float cn[16], so[16];
#pragma unroll
    for (int j=0;j<16;j++){
        int ch = cg*16 + j;
        float xg[4];
#pragma unroll
        for (int g=0; g<4; g++){
            int row = g*64 + ch;
            unsigned byte = (unsigned)(row*128) + (((unsigned)(p*2)) ^ ((unsigned)(row&7)<<4));
            float v = bf2f(*reinterpret_cast<const unsigned short*>(
                reinterpret_cast<const char*>(cct) + byte));
            xg[g] = v*sc[row][0] + sc[row][1];
        }
        float cv = c_in[(size_t)(b*64+ch)*1024 + p0 + p];
        cn[j] = sigmoidf_(xg[1])*cv + sigmoidf_(xg[0])*tanhf_(xg[3]);
        so[j] = sigmoidf_(xg[2]);
    }
    ushort8 v0, v1, s0, s1;
#pragma unroll
    for (int j=0;j<8;j++){
        v0[j]=f2bf(cn[j]); v1[j]=f2bf(cn[8+j]);
        s0[j]=f2bf(so[j]); s1[j]=f2bf(so[8+j]);
    }
    size_t prow = (size_t)(b*1024 + p0 + p);
    *reinterpret_cast<ushort8*>(buf2 + prow*128 + 64 + cg*16)     = v0;
    *reinterpret_cast<ushort8*>(buf2 + prow*128 + 64 + cg*16 + 8) = v1;
    *reinterpret_cast<ushort8*>(sig_pm + prow*64 + cg*16)     = s0;
    *reinterpret_cast<ushort8*>(sig_pm + prow*64 + cg*16 + 8) = s1;
}

// ---------- GN gate2 + projections fused (pixel-tiled, MFMA proj) ----------
__global__ __launch_bounds__(256)
void gn2_proj_kernel(const unsigned short* __restrict__ cc, const float* __restrict__ stats,
                     const float* __restrict__ gnw, const float* __restrict__ gnb,
                     const float* __restrict__ lc_in, const unsigned short* __restrict__ sig_pm,
                     const float* __restrict__ m_in,
                     const unsigned short* __restrict__ wph, const unsigned short* __restrict__ wpm,
                     const float* __restrict__ bq, const float* __restrict__ bk,
                     const float* __restrict__ bv, const float* __restrict__ bk2,
                     const float* __restrict__ bv2,
                     float* __restrict__ out_lc, float* __restrict__ out_c,
                     unsigned short* __restrict__ hT,
                     unsigned short* __restrict__ Qb, unsigned short* __restrict__ Khb,
                     unsigned short* __restrict__ Kmb,
                     unsigned short* __restrict__ Vhb, unsigned short* __restrict__ Vmb)
{
    const int b  = blockIdx.y;
    const int p0 = blockIdx.x * 64;
    const int t  = threadIdx.x;
    const int l  = t & 63;
    const int w  = t >> 6;
    const int l15 = l & 15, lhi = l >> 4;

    __shared__ float sc[256][2];
    // phase1: cct = cc tile [256][64] swizzled (32KB)
    // phase2 (reuse): bytes [0,8192) = hp[64p][64c] ; [8192,16384) = mp ; [16384,24576) = qk
    __shared__ __align__(16) unsigned short cct[16384];

    {
        const float* sp = stats + (size_t)(b*256 + t)*16;
        float S=0.f, Q=0.f;
#pragma unroll
        for (int k=0;k<8;k++){ S += sp[2*k]; Q += sp[2*k+1]; }
        float mu  = S*(1.0f/1024.0f);
        float var = Q*(1.0f/1024.0f) - mu*mu;
        float rs  = rsqrtf(var + 1e-5f);
        float gw  = gnw[t];
        sc[t][0] = rs*gw;
        sc[t][1] = gnb[t] - mu*rs*gw;
    }
    for (int it=t; it<2048; it+=256){
        int row = it>>3, oct = it&7;
        ushort8 v = *reinterpret_cast<const ushort8*>(
            cc + (size_t)(b*256+row)*1024 + p0 + oct*8);
        unsigned byte = (unsigned)(row*128) + (((unsigned)oct*16) ^ ((unsigned)(row&7)<<4));
        *reinterpret_cast<ushort8*>(reinterpret_cast<char*>(cct) + byte) = v;
    }
    __syncthreads();

    const int p = t & 63, cg = t >> 6;
    const size_t prow = (size_t)(b*1024 + p0 + p);
    float hm[16], mr[16];
    {
        ushort8 sv0 = *reinterpret_cast<const ushort8*>(sig_pm + prow*64 + cg*16);
        ushort8 sv1 = *reinterpret_cast<const ushort8*>(sig_pm + prow*64 + cg*16 + 8);
        float sof[16];
#pragma unroll
        for (int j=0;j<8;j++){ sof[j] = bf2f(sv0[j]); sof[8+j] = bf2f(sv1[j]); }
#pragma unroll
        for (int j=0;j<16;j++){
            int ch = cg*16 + j;
            float xg[4];
#pragma unroll
            for (int g=0; g<4; g++){
                int row = g*64 + ch;
                unsigned byte = (unsigned)(row*128) + (((unsigned)(p*2)) ^ ((unsigned)(row&7)<<4));
                float v = bf2f(*reinterpret_cast<const unsigned short*>(
                    reinterpret_cast<const char*>(cct) + byte));
                xg[g] = v*sc[row][0] + sc[row][1];
            }
            float lv  = lc_in[(size_t)(b*64+ch)*1024 + p0 + p];
            float lcn = sigmoidf_(xg[1])*lv + sigmoidf_(xg[0])*tanhf_(xg[3]);
            float cnx = sigmoidf_(xg[2])*tanhf_(lcn);
            out_lc[(size_t)(b*64+ch)*1024 + p0 + p] = lcn;
            out_c [(size_t)(b*64+ch)*1024 + p0 + p] = cnx;
            hm[j] = sof[j]*tanhf_(cnx);
            mr[j] = m_in[(size_t)(b*64+ch)*1024 + p0 + p];
        }
    }
    __syncthreads();   // all cct gate reads done; safe to overwrite with hp/mp

    {
        ushort8 h0,h1,m0,m1;
#pragma unroll
        for (int j=0;j<8;j++){
            h0[j]=f2bf(hm[j]); h1[j]=f2bf(hm[8+j]);
            m0[j]=f2bf(mr[j]); m1[j]=f2bf(mr[8+j]);
        }
        unsigned hb0 = (unsigned)(p*128) + (((unsigned)(cg*32))    ^ ((unsigned)(p&7)<<4));
        unsigned hb1 = (unsigned)(p*128) + (((unsigned)(cg*32+16)) ^ ((unsigned)(p&7)<<4));
        *reinterpret_cast<ushort8*>(reinterpret_cast<char*>(cct) + hb0) = h0;
        *reinterpret_cast<ushort8*>(reinterpret_cast<char*>(cct) + hb1) = h1;
        *reinterpret_cast<ushort8*>(reinterpret_cast<char*>(cct) + 8192 + hb0) = m0;
        *reinterpret_cast<ushort8*>(reinterpret_cast<char*>(cct) + 8192 + hb1) = m1;
        *reinterpret_cast<ushort8*>(hT + prow*64 + cg*16)     = h0;
        *reinterpret_cast<ushort8*>(hT + prow*64 + cg*16 + 8) = h1;
    }
    __syncthreads();

    // proj MFMAs: wave w owns pixel-frag w*16..w*16+15
    const int pix = w*16 + l15;
    const unsigned xsw = ((unsigned)(pix&7)) << 4;
    f32x4 dh[8], dm[6];
#pragma unroll
    for (int i=0;i<8;i++) dh[i] = (f32x4){0.f,0.f,0.f,0.f};
#pragma unroll
    for (int i=0;i<6;i++) dm[i] = (f32x4){0.f,0.f,0.f,0.f};
#pragma unroll
    for (int ks=0; ks<2; ++ks){
        unsigned xb = (unsigned)(pix*128) + (((unsigned)(ks*64 + lhi*16)) ^ xsw);
        bf16x8 xh = *reinterpret_cast<const bf16x8*>(reinterpret_cast<const char*>(cct) + xb);
        bf16x8 xm = *reinterpret_cast<const bf16x8*>(reinterpret_cast<const char*>(cct) + 8192 + xb);
#pragma unroll
        for (int ocf=0; ocf<8; ocf++){
            bf16x8 af = *reinterpret_cast<const bf16x8*>(
                wph + (size_t)(ocf*16 + l15)*64 + ks*32 + lhi*8);
            dh[ocf] = __builtin_amdgcn_mfma_f32_16x16x32_bf16(af, xh, dh[ocf], 0,0,0);
        }
#pragma unroll
        for (int ocf=0; ocf<6; ocf++){
            bf16x8 am = *reinterpret_cast<const bf16x8*>(
                wpm + (size_t)(ocf*16 + l15)*64 + ks*32 + lhi*8);
            dm[ocf] = __builtin_amdgcn_mfma_f32_16x16x32_bf16(am, xm, dm[ocf], 0,0,0);
        }
    }
    // V / Vm: direct coalesced channel-major stores
#pragma unroll
    for (int ocf=0; ocf<4; ocf++)
#pragma unroll
        for (int r=0;r<4;r++){
            int vc = ocf*16 + lhi*4 + r;
            Vhb[(size_t)(b*64+vc)*1024 + p0 + pix] = f2bf(dh[4+ocf][r] + bv[vc]);
            Vmb[(size_t)(b*64+vc)*1024 + p0 + pix] = f2bf(dm[2+ocf][r] + bv2[vc]);
        }
    // Q / K: scatter to qk LDS (pixel-major), then coalesced flush
#pragma unroll
    for (int ocf=0; ocf<2; ocf++)
#pragma unroll
        for (int r=0;r<4;r++){
            int qc = ocf*16 + lhi*4 + r;
            unsigned byq = (unsigned)(pix*128) + (((unsigned)(qc*2))      ^ xsw);
            unsigned byk = (unsigned)(pix*128) + (((unsigned)(64 + qc*2)) ^ xsw);
            *reinterpret_cast<unsigned short*>(reinterpret_cast<char*>(cct) + 16384 + byq)
                = f2bf(dh[ocf][r]   + bq[qc]);
            *reinterpret_cast<unsigned short*>(reinterpret_cast<char*>(cct) + 16384 + byk)
                = f2bf(dh[2+ocf][r] + bk[qc]);
        }
    __syncthreads();
    for (int it=t; it<512; it+=256){
        int pr = it>>3, oct = it&7;
        unsigned byte = (unsigned)(pr*128) + (((unsigned)(oct*16)) ^ ((unsigned)(pr&7)<<4));
        ushort8 v = *reinterpret_cast<const ushort8*>(
            reinterpret_cast<const char*>(cct) + 16384 + byte);
        if (oct < 4) *reinterpret_cast<ushort8*>(Qb  + (size_t)(b*1024+p0+pr)*32 + oct*8) = v;
        else         *reinterpret_cast<ushort8*>(Khb + (size_t)(b*1024+p0+pr)*32 + (oct-4)*8) = v;
    }
    __syncthreads();
#pragma unroll
    for (int ocf=0; ocf<2; ocf++)
#pragma unroll
        for (int r=0;r<4;r++){
            int qc = ocf*16 + lhi*4 + r;
            unsigned byq = (unsigned)(pix*128) + (((unsigned)(qc*2)) ^ xsw);
            *reinterpret_cast<unsigned short*>(reinterpret_cast<char*>(cct) + 16384 + byq)
                = f2bf(dm[ocf][r] + bk2[qc]);
        }
    __syncthreads();
    {
        int pr = t>>2, oct = t&3;
        unsigned byte = (unsigned)(pr*128) + (((unsigned)(oct*16)) ^ ((unsigned)(pr&7)<<4));
        ushort8 v = *reinterpret_cast<const ushort8*>(
            reinterpret_cast<const char*>(cct) + 16384 + byte);
        *reinterpret_cast<ushort8*>(Kmb + (size_t)(b*1024+p0+pr)*32 + oct*8) = v;
    }
}

// ---------- MFMA flash attention (S^T swapped-operand, in-register softmax) ----------
__global__ __launch_bounds__(256)
void attn_mfma_kernel(const unsigned short* __restrict__ Qb,
                      const unsigned short* __restrict__ Kh,
                      const unsigned short* __restrict__ Km,
                      const unsigned short* __restrict__ Vh,
                      const unsigned short* __restrict__ Vm,
                      unsigned short* __restrict__ ZT)
{
    const int bid   = blockIdx.x;
    const int xcd   = bid & 7;
    const int slot  = bid >> 3;
    const int b     = xcd*2 + (slot>>5);
    const int pass  = (slot>>4) & 1;
    const int p0    = (slot & 15) * 64;
    const int t   = threadIdx.x;
    const int l   = t & 63;
    const int w   = t >> 6;
    const int l15 = l & 15, g = l >> 4;

    __shared__ __align__(16) unsigned short Kt[2][2560];
    __shared__ __align__(16) unsigned short Vt[2][4096];
    __shared__ __align__(16) unsigned short Pt[4096];

    const unsigned short* Kg = pass ? Km : Kh;
    const unsigned short* Vg = pass ? Vm : Vh;

    const bf16x8 qa = *reinterpret_cast<const bf16x8*>(
        Qb + (size_t)(b*1024 + p0 + w*16 + l15)*32 + g*8);

    float m_run = -1e30f, l_run = 0.0f;
    f32x4 acc[4];
#pragma unroll
    for (int cf=0;cf<4;cf++) acc[cf] = (f32x4){0.f,0.f,0.f,0.f};

    const int krow = t>>2, koct = t&3;
    const int vrow = t>>3, voct = t&7;
    const unsigned kwb  = (unsigned)(krow*80 + koct*16);
    const unsigned vwb0 = (unsigned)(vrow*128)      + (((unsigned)voct*16) ^ ((unsigned)(vrow&7)<<4));
    const unsigned vwb1 = (unsigned)((vrow+32)*128) + (((unsigned)voct*16) ^ ((unsigned)((vrow+32)&7)<<4));

    ushort8 kreg = *reinterpret_cast<const ushort8*>(Kg + (size_t)(b*1024 + krow)*32 + koct*8);
    ushort8 vr0  = *reinterpret_cast<const ushort8*>(Vg + (size_t)(b*64 + vrow)*1024 + voct*8);
    ushort8 vr1  = *reinterpret_cast<const ushort8*>(Vg + (size_t)(b*64 + vrow+32)*1024 + voct*8);
    *reinterpret_cast<ushort8*>(reinterpret_cast<char*>(Kt[0]) + kwb)  = kreg;
    *reinterpret_cast<ushort8*>(reinterpret_cast<char*>(Vt[0]) + vwb0) = vr0;
    *reinterpret_cast<ushort8*>(reinterpret_cast<char*>(Vt[0]) + vwb1) = vr1;
    __syncthreads();

    for (int it=0; it<16; ++it){
        const int cur = it & 1;
        if (it < 15){
            const int q0n = (it+1)*64;
            kreg = *reinterpret_cast<const ushort8*>(Kg + (size_t)(b*1024 + q0n + krow)*32 + koct*8);
            vr0  = *reinterpret_cast<const ushort8*>(Vg + (size_t)(b*64 + vrow)*1024 + q0n + voct*8);
            vr1  = *reinterpret_cast<const ushort8*>(Vg + (size_t)(b*64 + vrow+32)*1024 + q0n + voct*8);
        }

        f32x4 s2[4];
#pragma unroll
        for (int qt=0; qt<4; qt++){
            const bf16x8 kb = *reinterpret_cast<const bf16x8*>(
                reinterpret_cast<const char*>(Kt[cur]) + (qt*16 + l15)*80 + g*16);
            s2[qt] = __builtin_amdgcn_mfma_f32_16x16x32_bf16(kb, qa, (f32x4){0.f,0.f,0.f,0.f}, 0,0,0);
        }

        float pm = s2[0][0];
#pragma unroll
        for (int qt=0; qt<4; qt++)
#pragma unroll
            for (int r=0;r<4;r++) pm = fmaxf(pm, s2[qt][r]);
        pm = fmaxf(pm, __shfl_xor(pm, 16));
        pm = fmaxf(pm, __shfl_xor(pm, 32));

        if (!__all(pm <= m_run + 8.0f)){
            float mn = fmaxf(m_run, pm);
            float f  = __expf(m_run - mn);
            m_run = mn;
            l_run *= f;
#pragma unroll
            for (int r=0;r<4;r++){
                float fr = __shfl(f, (l & 48) | ((l>>4)*4 + r), 64);
#pragma unroll
                for (int cf=0;cf<4;cf++) acc[cf][r] *= fr;
            }
        }

        float e[4][4];
        float lsum = 0.f;
#pragma unroll
        for (int qt=0; qt<4; qt++)
#pragma unroll
            for (int r=0;r<4;r++){
                float ev = __expf(s2[qt][r] - m_run);
                e[qt][r] = ev;
                lsum += ev;
            }
        lsum += __shfl_xor(lsum, 16);
        lsum += __shfl_xor(lsum, 32);
        l_run += lsum;

        const unsigned prow = (unsigned)(w*16 + l15);
        const unsigned psw  = (prow & 7u) << 4;
#pragma unroll
        for (int qt=0; qt<4; qt++){
            uint2v pk;
            pk.x = cvt_pk_bf16(e[qt][0], e[qt][1]);
            pk.y = cvt_pk_bf16(e[qt][2], e[qt][3]);
            unsigned byte = prow*128 + (((unsigned)(qt*32 + g*8)) ^ psw);
            *reinterpret_cast<uint2v*>(reinterpret_cast<char*>(Pt) + byte) = pk;
        }

#pragma unroll
        for (int ks=0;ks<2;ks++){
            unsigned abyte = prow*128 + (((unsigned)(ks*64 + g*16)) ^ psw);
            const bf16x8 pa = *reinterpret_cast<const bf16x8*>(
                reinterpret_cast<const char*>(Pt) + abyte);
#pragma unroll
            for (int cf=0;cf<4;cf++){
                unsigned vrw = (unsigned)(cf*16 + l15);
                unsigned vbyte = vrw*128 + (((unsigned)(ks*64 + g*16)) ^ ((vrw&7u)<<4));
                const bf16x8 vb = *reinterpret_cast<const bf16x8*>(
                    reinterpret_cast<const char*>(Vt[cur]) + vbyte);
                acc[cf] = __builtin_amdgcn_mfma_f32_16x16x32_bf16(pa, vb, acc[cf], 0,0,0);
            }
        }

        if (it < 15){
            *reinterpret_cast<ushort8*>(reinterpret_cast<char*>(Kt[cur^1]) + kwb)  = kreg;
            *reinterpret_cast<ushort8*>(reinterpret_cast<char*>(Vt[cur^1]) + vwb0) = vr0;
            *reinterpret_cast<ushort8*>(reinterpret_cast<char*>(Vt[cur^1]) + vwb1) = vr1;
        }
        __syncthreads();
    }

    float rl = 1.0f / l_run;
    float rr[4];
#pragma unroll
    for (int r=0;r<4;r++) rr[r] = __shfl(rl, (l & 48) | ((l>>4)*4 + r), 64);
#pragma unroll
    for (int cf=0;cf<4;cf++)
#pragma unroll
        for (int r=0;r<4;r++)
            ZT[(size_t)(b*1024 + p0 + w*16 + g*4 + r)*128 + pass*64 + cf*16 + l15]
                = f2bf(acc[cf][r]*rr[r]);
}

// ---------- final via MFMA (32-pixel tiles) ----------
__global__ __launch_bounds__(256)
void final_mfma_kernel(const unsigned short* __restrict__ ZT,
                       const unsigned short* __restrict__ hT,
                       const unsigned short* __restrict__ wzb,
                       const unsigned short* __restrict__ wmb,
                       const float* __restrict__ bz, const float* __restrict__ bm,
                       const float* __restrict__ m_in,
                       float* __restrict__ out_h, float* __restrict__ out_m)
{
    const int b  = blockIdx.y;
    const int p0 = blockIdx.x * 32;
    const int t  = threadIdx.x;
    const int l  = t & 63;
    const int w  = t >> 6;
    const int l15 = l & 15, g = l >> 4;

    __shared__ __align__(16) unsigned short Bs[32*192];

    for (int it=t; it<512; it+=256){
        int row = it>>4, oct = it&15;
        ushort8 v = *reinterpret_cast<const ushort8*>(
            ZT + (size_t)(b*1024 + p0 + row)*128 + oct*8);
        unsigned byte = (unsigned)(row*384) + (((unsigned)oct*16) ^ ((unsigned)(row&7)<<4));
        *reinterpret_cast<ushort8*>(reinterpret_cast<char*>(Bs) + byte) = v;
    }
    {
        int row = t>>3, oct = t&7;
        ushort8 v = *reinterpret_cast<const ushort8*>(
            hT + (size_t)(b*1024 + p0 + row)*64 + oct*8);
        unsigned byte = (unsigned)(row*384) + 256u + (((unsigned)oct*16) ^ ((unsigned)(row&7)<<4));
        *reinterpret_cast<ushort8*>(reinterpret_cast<char*>(Bs) + byte) = v;
    }
    __syncthreads();

    f32x4 acc1[2][2];
#pragma unroll
    for (int i=0;i<2;i++)
#pragma unroll
        for (int cf=0;cf<2;cf++) acc1[i][cf] = (f32x4){0.f,0.f,0.f,0.f};
#pragma unroll
    for (int ks=0; ks<4; ++ks){
        bf16x8 af[2];
#pragma unroll
        for (int i=0;i<2;i++)
            af[i] = *reinterpret_cast<const bf16x8*>(
                wzb + (size_t)(w*32 + i*16 + l15)*128 + ks*32 + g*8);
#pragma unroll
        for (int cf=0;cf<2;cf++){
            unsigned p = (unsigned)(cf*16 + l15);
            unsigned byte = p*384 + (((unsigned)(ks*64 + g*16)) ^ ((p&7u)<<4));
            const bf16x8 bfr = *reinterpret_cast<const bf16x8*>(
                reinterpret_cast<const char*>(Bs) + byte);
            acc1[0][cf] = __builtin_amdgcn_mfma_f32_16x16x32_bf16(af[0], bfr, acc1[0][cf], 0,0,0);
            acc1[1][cf] = __builtin_amdgcn_mfma_f32_16x16x32_bf16(af[1], bfr, acc1[1][cf], 0,0,0);
        }
    }
    __syncthreads();
#pragma unroll
    for (int i=0;i<2;i++){
        int co = w*32 + i*16 + g*4;
#pragma unroll
        for (int cf=0;cf<2;cf++){
            unsigned p = (unsigned)(cf*16 + l15);
#pragma unroll
            for (int r=0;r<4;r++){
                float val = acc1[i][cf][r] + bz[co+r];
                unsigned byte = p*384 + (((unsigned)((co+r)*2)) ^ ((p&7u)<<4));
                *reinterpret_cast<unsigned short*>(reinterpret_cast<char*>(Bs) + byte) = f2bf(val);
            }
        }
    }
    __syncthreads();

    f32x4 acc2[3][2];
#pragma unroll
    for (int j=0;j<3;j++)
#pragma unroll
        for (int cf=0;cf<2;cf++) acc2[j][cf] = (f32x4){0.f,0.f,0.f,0.f};
#pragma unroll
    for (int ks=0; ks<6; ++ks){
        bf16x8 am[3];
#pragma unroll
        for (int j=0;j<3;j++)
            am[j] = *reinterpret_cast<const bf16x8*>(
                wmb + (size_t)(j*64 + w*16 + l15)*192 + ks*32 + g*8);
#pragma unroll
        for (int cf=0;cf<2;cf++){
            unsigned p = (unsigned)(cf*16 + l15);
            unsigned byte = p*384 + (((unsigned)(ks*64 + g*16)) ^ ((p&7u)<<4));
            const bf16x8 bfr = *reinterpret_cast<const bf16x8*>(
                reinterpret_cast<const char*>(Bs) + byte);
#pragma unroll
            for (int j=0;j<3;j++)
                acc2[j][cf] = __builtin_amdgcn_mfma_f32_16x16x32_bf16(am[j], bfr, acc2[j][cf], 0,0,0);
        }
    }

    const int ch0 = w*16 + g*4;
#pragma unroll
    for (int cf=0;cf<2;cf++){
        int pix = p0 + cf*16 + l15;
#pragma unroll
        for (int r=0;r<4;r++){
            int ch = ch0 + r;
            float mo = acc2[0][cf][r] + bm[ch];
            float mg = acc2[1][cf][r] + bm[64+ch];
            float mi = sigmoidf_(acc2[2][cf][r] + bm[128+ch]);
            float mv = m_in[(size_t)(b*64+ch)*1024 + pix];
            float mn = (1.0f - mi)*mv + mi*tanhf_(mg);
            out_m[(size_t)(b*64+ch)*1024 + pix] = mn;
            out_h[(size_t)(b*64+ch)*1024 + pix] = sigmoidf_(mo)*mn;
        }
    }
}

extern "C" void kernel_launch(void* const* d_in, const int* in_sizes, int n_in,
                              void* d_out, int out_size, void* d_ws, size_t ws_size,
                              hipStream_t stream)
{
    const float* x      = (const float*)d_in[0];
    const float* h      = (const float*)d_in[1];
    const float* c      = (const float*)d_in[2];
    const float* m      = (const float*)d_in[3];
    const float* lc     = (const float*)d_in[4];
    const float* conv_w = (const float*)d_in[5];
    const float* conv_b = (const float*)d_in[6];
    const float* gn1_w  = (const float*)d_in[7];
    const float* gn1_b  = (const float*)d_in[8];
    const float* convL_w= (const float*)d_in[9];
    const float* convL_b= (const float*)d_in[10];
    const float* gn2_w  = (const float*)d_in[11];
    const float* gn2_b  = (const float*)d_in[12];
    const float* wq  = (const float*)d_in[13];
    const float* bq  = (const float*)d_in[14];
    const float* wk  = (const float*)d_in[15];
    const float* bk  = (const float*)d_in[16];
    const float* wk2 = (const float*)d_in[17];
    const float* bk2 = (const float*)d_in[18];
    const float* wv  = (const float*)d_in[19];
    const float* bv  = (const float*)d_in[20];
    const float* wv2 = (const float*)d_in[21];
    const float* bv2 = (const float*)d_in[22];
    const float* wz  = (const float*)d_in[23];
    const float* bz  = (const float*)d_in[24];
    const float* wmw = (const float*)d_in[25];
    const float* bm  = (const float*)d_in[26];

    float* out = (float*)d_out;
    float* F = (float*)d_ws;
    unsigned short* cc_bf  = (unsigned short*)F;              // [16][256][1024] bf16
    unsigned short* buf1   = (unsigned short*)(F + 4194304);  // conv1 in; later ZT [16][1024][128]
    unsigned short* ZT     = buf1;
    unsigned short* buf2   = (unsigned short*)(F + 5242880);  // conv2 in; later hT [16][1024][64]
    unsigned short* hT     = buf2;
    unsigned short* Qb     = (unsigned short*)(F + 6291456);
    unsigned short* Khb    = (unsigned short*)(F + 6553600);
    unsigned short* Kmb    = (unsigned short*)(F + 6815744);
    unsigned short* Vhb    = (unsigned short*)(F + 7077888);
    unsigned short* Vmb    = (unsigned short*)(F + 7602176);
    unsigned short* sig_pm = (unsigned short*)(F + 8126464);  // [16][1024][64] bf16
    unsigned short* wpk1   = (unsigned short*)(F + 8650752);
    unsigned short* wpk2   = (unsigned short*)(F + 8798208);
    unsigned short* wzb    = (unsigned short*)(F + 8945664);
    unsigned short* wmb    = (unsigned short*)(F + 8953856);
    unsigned short* wph    = (unsigned short*)(F + 8972288);  // [128][64] bf16
    unsigned short* wpm    = (unsigned short*)(F + 8976384);  // [96][64] bf16
    float*          stats  = F + 8979456;                     // [16][256][8][2] f32

    dim3 blk256(256);
    prep_kernel<<<dim3(1408), blk256, 0, stream>>>(conv_w, convL_w, wz, wmw,
                                                   wq, wk, wv, wk2, wv2, x, h,
                                                   wpk1, wpk2, wzb, wmb, wph, wpm,
                                                   buf1, buf2);
    dim3 cgrid(8, 4, 16);
    conv_mfma_kernel<<<cgrid, blk256, 0, stream>>>(buf1, wpk1, conv_b, cc_bf, stats);
    gn_gate1_kernel<<<dim3(16,16), blk256, 0, stream>>>(cc_bf, stats, gn1_w, gn1_b, c,
                                                        buf2, sig_pm);
    conv_mfma_kernel<<<cgrid, blk256, 0, stream>>>(buf2, wpk2, convL_b, cc_bf, stats);
    gn2_proj_kernel<<<dim3(16,16), blk256, 0, stream>>>(cc_bf, stats, gn2_w, gn2_b,
                                                        lc, sig_pm, m, wph, wpm,
                                                        bq, bk, bv, bk2, bv2,
                                                        out + 3*1048576 /*lc_next*/,
                                                        out + 1*1048576 /*c_next*/,
                                                        hT, Qb, Khb, Kmb, Vhb, Vmb);
    attn_mfma_kernel<<<dim3(512), blk256, 0, stream>>>(Qb, Khb, Kmb, Vhb, Vmb, ZT);
    final_mfma_kernel<<<dim3(32,16), blk256, 0, stream>>>(ZT, hT, wzb, wmb, bz, bm, m,
                                                          out /*h_next*/, out + 2*1048576 /*m_next*/);
    (void)in_sizes; (void)n_in; (void)out_size; (void)ws_size;
}

// Round 8
// 127.510 us; speedup vs baseline: 8.2797x; 1.0210x over previous
//
#include <hip/hip_runtime.h>

#define DEV __device__ __forceinline__

typedef __attribute__((ext_vector_type(8))) __bf16 bf16x8;
typedef __attribute__((ext_vector_type(4))) float f32x4;
typedef __attribute__((ext_vector_type(8))) unsigned short ushort8;
typedef __attribute__((ext_vector_type(2))) unsigned short ushort2v;
typedef __attribute__((ext_vector_type(2))) unsigned int uint2v;

DEV float sigmoidf_(float x){ return 1.0f/(1.0f + __expf(-x)); }
DEV float tanhf_(float x){
    x = fminf(15.0f, fmaxf(-15.0f, x));
    float e = __expf(2.0f*x);
    return (e - 1.0f)/(e + 1.0f);
}
DEV unsigned short f2bf(float f){
    unsigned u = __builtin_bit_cast(unsigned, f);
    unsigned r = (u + 0x7FFFu + ((u>>16)&1u)) >> 16;
    return (unsigned short)r;
}
DEV float bf2f(unsigned short u){
    return __builtin_bit_cast(float, ((unsigned)u)<<16);
}
DEV unsigned cvt_pk_bf16(float lo, float hi){
    unsigned r;
    asm("v_cvt_pk_bf16_f32 %0, %1, %2" : "=v"(r) : "v"(lo), "v"(hi));
    return r;
}

// ---------- merged prep: conv/proj/mix weights -> bf16 packs ; pack x,h -> buf1, h -> buf2-lo ----------
__global__ __launch_bounds__(256)
void prep_kernel(const float* __restrict__ conv_w, const float* __restrict__ convL_w,
                 const float* __restrict__ wz, const float* __restrict__ wm,
                 const float* __restrict__ wq, const float* __restrict__ wk,
                 const float* __restrict__ wv, const float* __restrict__ wk2,
                 const float* __restrict__ wv2,
                 const float* __restrict__ x, const float* __restrict__ h,
                 unsigned short* __restrict__ wpk1, unsigned short* __restrict__ wpk2,
                 unsigned short* __restrict__ wzb, unsigned short* __restrict__ wmb,
                 unsigned short* __restrict__ wph, unsigned short* __restrict__ wpm,
                 unsigned short* __restrict__ buf1, unsigned short* __restrict__ buf2)
{
    __shared__ float tile[128][65];
    if (blockIdx.x < 1152) {
        int idx = blockIdx.x*256 + threadIdx.x;
        {
            int co  = idx / (128*9);
            int rem = idx - co*(128*9);
            int ci  = rem / 9;
            int tap = rem - ci*9;
            int kchunk = (ci>>5)*9 + tap;
            int o = (kchunk*256 + co)*32 + (ci&31);
            wpk1[o] = f2bf(conv_w[idx]);
            wpk2[o] = f2bf(convL_w[idx]);
        }
        if (idx < 128*128) wzb[idx] = f2bf(wz[idx]);
        if (idx < 192*192) wmb[idx] = f2bf(wm[idx]);
        if (idx < 32*64){
            wph[idx]        = f2bf(wq[idx]);
            wph[2048 + idx] = f2bf(wk[idx]);
            wpm[idx]        = f2bf(wk2[idx]);
        }
        if (idx < 64*64){
            wph[4096 + idx] = f2bf(wv[idx]);
            wpm[2048 + idx] = f2bf(wv2[idx]);
        }
    } else {
        int bx = blockIdx.x - 1152;
        int b  = bx >> 4;
        int p0 = (bx & 15) * 64;
        int t  = threadIdx.x;
        for (int k=t;k<8192;k+=256){
            int ci = k>>6, pp = k&63;
            const float* s = (ci<64) ? x + (size_t)(b*64+ci)*1024
                                     : h + (size_t)(b*64+ci-64)*1024;
            tile[ci][pp] = s[p0+pp];
        }
        __syncthreads();
        for (int k=t;k<4096;k+=256){
            int pp = k>>6, c2 = k&63;
            ushort2v v;
            v.x = f2bf(tile[c2*2][pp]);
            v.y = f2bf(tile[c2*2+1][pp]);
            *reinterpret_cast<ushort2v*>(buf1 + (size_t)(b*1024+p0+pp)*128 + c2*2) = v;
            if (c2 >= 32)
                *reinterpret_cast<ushort2v*>(buf2 + (size_t)(b*1024+p0+pp)*128 + (c2-32)*2) = v;
        }
    }
}

// ---------- implicit-GEMM 3x3 conv via MFMA, software-pipelined + GN stat partials ----------
__global__ __launch_bounds__(256)
void conv_mfma_kernel(const unsigned short* __restrict__ inp,
                      const unsigned short* __restrict__ wpk,
                      const float* __restrict__ bias,
                      unsigned short* __restrict__ out,
                      float* __restrict__ stats)
{
    const int b   = blockIdx.z;
    const int co0 = blockIdx.y * 64;
    const int r0  = blockIdx.x * 4;
    const int t   = threadIdx.x;
    const int l   = t & 63;
    const int wv  = t >> 6;
    const int l15 = l & 15;
    const int lhi = l >> 4;

    __shared__ __align__(16) unsigned short in_t[26112];  // 204 x 128ci, swizzled
    __shared__ float red_s[4][64];
    __shared__ float red_q[4][64];

    for (int it = t; it < 3264; it += 256) {
        int pixlin = it >> 4, oct = it & 15;
        int rr = pixlin / 34;
        int cc = pixlin - rr*34;
        int gr = r0 + rr - 1, gc = cc - 1;
        ushort8 v = {};
        if ((unsigned)gr < 32u && (unsigned)gc < 32u)
            v = *reinterpret_cast<const ushort8*>(
                    inp + ((size_t)(b*1024 + gr*32 + gc)*128) + oct*8);
        unsigned byte = (unsigned)(pixlin*256 + oct*16) ^ (((unsigned)pixlin & 7u) << 4);
        *reinterpret_cast<ushort8*>(reinterpret_cast<char*>(in_t) + byte) = v;
    }

    f32x4 acc[4][2];
#pragma unroll
    for (int i=0;i<4;i++)
#pragma unroll
        for (int f=0;f<2;f++)
            acc[i][f] = (f32x4){0.f,0.f,0.f,0.f};

    __syncthreads();

    bf16x8 afc[4], bfc[2], afn[4], bfn[2];
#define LDA_(K, DST) do { const unsigned short* wrow_ = wpk + ((K)*256 + co0)*32; \
        for (int i_=0;i_<4;i_++) DST[i_] = *reinterpret_cast<const bf16x8*>(wrow_ + (i_*16 + l15)*32 + lhi*8); } while(0)
#define LDB_(K, DST) do { const int cic_ = (K)/9, tap_ = (K) - 9*((K)/9); \
        const int ky_ = tap_/3, kx_ = tap_ - 3*(tap_/3); \
        for (int f_=0;f_<2;f_++){ int pixlin_ = (wv + ky_)*34 + (f_*16 + l15 + kx_); \
            unsigned byte_ = (unsigned)(pixlin_*256 + cic_*64 + lhi*16) ^ (((unsigned)pixlin_ & 7u) << 4); \
            DST[f_] = *reinterpret_cast<const bf16x8*>(reinterpret_cast<const char*>(in_t) + byte_); } } while(0)

    LDA_(0, afc); LDB_(0, bfc);
#pragma unroll
    for (int k=0; k<36; ++k){
        if (k < 35){ LDA_(k+1, afn); LDB_(k+1, bfn); }
#pragma unroll
        for (int i=0;i<4;i++){
            acc[i][0] = __builtin_amdgcn_mfma_f32_16x16x32_bf16(afc[i], bfc[0], acc[i][0], 0,0,0);
            acc[i][1] = __builtin_amdgcn_mfma_f32_16x16x32_bf16(afc[i], bfc[1], acc[i][1], 0,0,0);
        }
        if (k < 35){
#pragma unroll
            for (int i=0;i<4;i++) afc[i] = afn[i];
            bfc[0] = bfn[0]; bfc[1] = bfn[1];
        }
    }
#undef LDA_
#undef LDB_

    const int orow = r0 + wv;
    float s_ir[4][4], q_ir[4][4];
#pragma unroll
    for (int i=0;i<4;i++){
        int cobase = co0 + i*16 + lhi*4;
#pragma unroll
        for (int r=0;r<4;r++){
            float bs = bias[cobase+r];
            float e0 = acc[i][0][r] + bs;
            float e1 = acc[i][1][r] + bs;
            out[(size_t)(b*256 + cobase + r)*1024 + orow*32 + l15]      = f2bf(e0);
            out[(size_t)(b*256 + cobase + r)*1024 + orow*32 + 16 + l15] = f2bf(e1);
            s_ir[i][r] = e0 + e1;
            q_ir[i][r] = e0*e0 + e1*e1;
        }
    }
#pragma unroll
    for (int i=0;i<4;i++)
#pragma unroll
        for (int r=0;r<4;r++){
            float s = s_ir[i][r], q = q_ir[i][r];
            s += __shfl_xor(s,1); q += __shfl_xor(q,1);
            s += __shfl_xor(s,2); q += __shfl_xor(q,2);
            s += __shfl_xor(s,4); q += __shfl_xor(q,4);
            s += __shfl_xor(s,8); q += __shfl_xor(q,8);
            s_ir[i][r] = s; q_ir[i][r] = q;
        }
    if (l15 == 0){
#pragma unroll
        for (int i=0;i<4;i++)
#pragma unroll
            for (int r=0;r<4;r++){
                red_s[wv][i*16 + lhi*4 + r] = s_ir[i][r];
                red_q[wv][i*16 + lhi*4 + r] = q_ir[i][r];
            }
    }
    __syncthreads();
    if (t < 64){
        float S = red_s[0][t]+red_s[1][t]+red_s[2][t]+red_s[3][t];
        float Q = red_q[0][t]+red_q[1][t]+red_q[2][t]+red_q[3][t];
        float* sp = stats + ((size_t)(b*256 + co0 + t)*8 + blockIdx.x)*2;
        sp[0] = S; sp[1] = Q;
    }
}

// ---------- GN gate1, pixel-tiled ----------
__global__ __launch_bounds__(256)
void gn_gate1_kernel(const unsigned short* __restrict__ cc, const float* __restrict__ stats,
                     const float* __restrict__ gnw, const float* __restrict__ gnb,
                     const float* __restrict__ c_in,
                     unsigned short* __restrict__ buf2, unsigned short* __restrict__ sig_pm)
{
    const int b  = blockIdx.y;
    const int p0 = blockIdx.x * 64;
    const int t  = threadIdx.x;
    __shared__ float sc[256][2];
    __shared__ __align__(16) unsigned short cct[16384];

    {
        const float* sp = stats + (size_t)(b*256 + t)*16;
        float S=0.f, Q=0.f;
#pragma unroll
        for (int k=0;k<8;k++){ S += sp[2*k]; Q += sp[2*k+1]; }
        float mu  = S*(1.0f/1024.0f);
        float var = Q*(1.0f/1024.0f) - mu*mu;
        float rs  = rsqrtf(var + 1e-5f);
        float gw  = gnw[t];
        sc[t][0] = rs*gw;
        sc[t][1] = gnb[t] - mu*rs*gw;
    }
    for (int it=t; it<2048; it+=256){
        int row = it>>3, oct = it&7;
        ushort8 v = *reinterpret_cast<const ushort8*>(
            cc + (size_t)(b*256+row)*1024 + p0 + oct*8);
        unsigned byte = (unsigned)(row*128) + (((unsigned)oct*16) ^ ((unsigned)(row&7)<<4));
        *reinterpret_cast<ushort8*>(reinterpret_cast<char*>(cct) + byte) = v;
    }
    __syncthreads();

    const int p = t & 63, cg = t >> 6;
    float cn[16], so[16];
#pragma unroll
    for (int j=0;j<16;j++){
        int ch = cg*16 + j;
        float xg[4];
#pragma unroll
        for (int g=0; g<4; g++){
            int row = g*64 + ch;
            unsigned byte = (unsigned)(row*128) + (((unsigned)(p*2)) ^ ((unsigned)(row&7)<<4));
            float v = bf2f(*reinterpret_cast<const unsigned short*>(
                reinterpret_cast<const char*>(cct) + byte));
            xg[g] = v*sc[row][0] + sc[row][1];
        }
        float cv = c_in[(size_t)(b*64+ch)*1024 + p0 + p];
        cn[j] = sigmoidf_(xg[1])*cv + sigmoidf_(xg[0])*tanhf_(xg[3]);
        so[j] = sigmoidf_(xg[2]);
    }
    ushort8 v0, v1, s0, s1;
#pragma unroll
    for (int j=0;j<8;j++){
        v0[j]=f2bf(cn[j]); v1[j]=f2bf(cn[8+j]);
        s0[j]=f2bf(so[j]); s1[j]=f2bf(so[8+j]);
    }
    size_t prow = (size_t)(b*1024 + p0 + p);
    *reinterpret_cast<ushort8*>(buf2 + prow*128 + 64 + cg*16)     = v0;
    *reinterpret_cast<ushort8*>(buf2 + prow*128 + 64 + cg*16 + 8) = v1;
    *reinterpret_cast<ushort8*>(sig_pm + prow*64 + cg*16)     = s0;
    *reinterpret_cast<ushort8*>(sig_pm + prow*64 + cg*16 + 8) = s1;
}

// ---------- GN gate2 + projections fused ----------
__global__ __launch_bounds__(256)
void gn2_proj_kernel(const unsigned short* __restrict__ cc, const float* __restrict__ stats,
                     const float* __restrict__ gnw, const float* __restrict__ gnb,
                     const float* __restrict__ lc_in, const unsigned short* __restrict__ sig_pm,
                     const float* __restrict__ m_in,
                     const unsigned short* __restrict__ wph, const unsigned short* __restrict__ wpm,
                     const float* __restrict__ bq, const float* __restrict__ bk,
                     const float* __restrict__ bv, const float* __restrict__ bk2,
                     const float* __restrict__ bv2,
                     float* __restrict__ out_lc, float* __restrict__ out_c,
                     unsigned short* __restrict__ hT,
                     unsigned short* __restrict__ Qb, unsigned short* __restrict__ Khb,
                     unsigned short* __restrict__ Kmb,
                     unsigned short* __restrict__ Vhb, unsigned short* __restrict__ Vmb)
{
    const int b  = blockIdx.y;
    const int p0 = blockIdx.x * 64;
    const int t  = threadIdx.x;
    const int l  = t & 63;
    const int w  = t >> 6;
    const int l15 = l & 15, lhi = l >> 4;

    __shared__ float sc[256][2];
    __shared__ __align__(16) unsigned short cct[16384];

    {
        const float* sp = stats + (size_t)(b*256 + t)*16;
        float S=0.f, Q=0.f;
#pragma unroll
        for (int k=0;k<8;k++){ S += sp[2*k]; Q += sp[2*k+1]; }
        float mu  = S*(1.0f/1024.0f);
        float var = Q*(1.0f/1024.0f) - mu*mu;
        float rs  = rsqrtf(var + 1e-5f);
        float gw  = gnw[t];
        sc[t][0] = rs*gw;
        sc[t][1] = gnb[t] - mu*rs*gw;
    }
    for (int it=t; it<2048; it+=256){
        int row = it>>3, oct = it&7;
        ushort8 v = *reinterpret_cast<const ushort8*>(
            cc + (size_t)(b*256+row)*1024 + p0 + oct*8);
        unsigned byte = (unsigned)(row*128) + (((unsigned)oct*16) ^ ((unsigned)(row&7)<<4));
        *reinterpret_cast<ushort8*>(reinterpret_cast<char*>(cct) + byte) = v;
    }
    __syncthreads();

    const int p = t & 63, cg = t >> 6;
    const size_t prow = (size_t)(b*1024 + p0 + p);
    float hm[16], mr[16];
    {
        ushort8 sv0 = *reinterpret_cast<const ushort8*>(sig_pm + prow*64 + cg*16);
        ushort8 sv1 = *reinterpret_cast<const ushort8*>(sig_pm + prow*64 + cg*16 + 8);
        float sof[16];
#pragma unroll
        for (int j=0;j<8;j++){ sof[j] = bf2f(sv0[j]); sof[8+j] = bf2f(sv1[j]); }
#pragma unroll
        for (int j=0;j<16;j++){
            int ch = cg*16 + j;
            float xg[4];
#pragma unroll
            for (int g=0; g<4; g++){
                int row = g*64 + ch;
                unsigned byte = (unsigned)(row*128) + (((unsigned)(p*2)) ^ ((unsigned)(row&7)<<4));
                float v = bf2f(*reinterpret_cast<const unsigned short*>(
                    reinterpret_cast<const char*>(cct) + byte));
                xg[g] = v*sc[row][0] + sc[row][1];
            }
            float lv  = lc_in[(size_t)(b*64+ch)*1024 + p0 + p];
            float lcn = sigmoidf_(xg[1])*lv + sigmoidf_(xg[0])*tanhf_(xg[3]);
            float cnx = sigmoidf_(xg[2])*tanhf_(lcn);
            out_lc[(size_t)(b*64+ch)*1024 + p0 + p] = lcn;
            out_c [(size_t)(b*64+ch)*1024 + p0 + p] = cnx;
            hm[j] = sof[j]*tanhf_(cnx);
            mr[j] = m_in[(size_t)(b*64+ch)*1024 + p0 + p];
        }
    }
    __syncthreads();

    {
        ushort8 h0,h1,m0,m1;
#pragma unroll
        for (int j=0;j<8;j++){
            h0[j]=f2bf(hm[j]); h1[j]=f2bf(hm[8+j]);
            m0[j]=f2bf(mr[j]); m1[j]=f2bf(mr[8+j]);
        }
        unsigned hb0 = (unsigned)(p*128) + (((unsigned)(cg*32))    ^ ((unsigned)(p&7)<<4));
        unsigned hb1 = (unsigned)(p*128) + (((unsigned)(cg*32+16)) ^ ((unsigned)(p&7)<<4));
        *reinterpret_cast<ushort8*>(reinterpret_cast<char*>(cct) + hb0) = h0;
        *reinterpret_cast<ushort8*>(reinterpret_cast<char*>(cct) + hb1) = h1;
        *reinterpret_cast<ushort8*>(reinterpret_cast<char*>(cct) + 8192 + hb0) = m0;
        *reinterpret_cast<ushort8*>(reinterpret_cast<char*>(cct) + 8192 + hb1) = m1;
        *reinterpret_cast<ushort8*>(hT + prow*64 + cg*16)     = h0;
        *reinterpret_cast<ushort8*>(hT + prow*64 + cg*16 + 8) = h1;
    }
    __syncthreads();

    const int pix = w*16 + l15;
    const unsigned xsw = ((unsigned)(pix&7)) << 4;
    f32x4 dh[8], dm[6];
#pragma unroll
    for (int i=0;i<8;i++) dh[i] = (f32x4){0.f,0.f,0.f,0.f};
#pragma unroll
    for (int i=0;i<6;i++) dm[i] = (f32x4){0.f,0.f,0.f,0.f};
#pragma unroll
    for (int ks=0; ks<2; ++ks){
        unsigned xb = (unsigned)(pix*128) + (((unsigned)(ks*64 + lhi*16)) ^ xsw);
        bf16x8 xh = *reinterpret_cast<const bf16x8*>(reinterpret_cast<const char*>(cct) + xb);
        bf16x8 xm = *reinterpret_cast<const bf16x8*>(reinterpret_cast<const char*>(cct) + 8192 + xb);
#pragma unroll
        for (int ocf=0; ocf<8; ocf++){
            bf16x8 af = *reinterpret_cast<const bf16x8*>(
                wph + (size_t)(ocf*16 + l15)*64 + ks*32 + lhi*8);
            dh[ocf] = __builtin_amdgcn_mfma_f32_16x16x32_bf16(af, xh, dh[ocf], 0,0,0);
        }
#pragma unroll
        for (int ocf=0; ocf<6; ocf++){
            bf16x8 am = *reinterpret_cast<const bf16x8*>(
                wpm + (size_t)(ocf*16 + l15)*64 + ks*32 + lhi*8);
            dm[ocf] = __builtin_amdgcn_mfma_f32_16x16x32_bf16(am, xm, dm[ocf], 0,0,0);
        }
    }
#pragma unroll
    for (int ocf=0; ocf<4; ocf++)
#pragma unroll
        for (int r=0;r<4;r++){
            int vc = ocf*16 + lhi*4 + r;
            Vhb[(size_t)(b*64+vc)*1024 + p0 + pix] = f2bf(dh[4+ocf][r] + bv[vc]);
            Vmb[(size_t)(b*64+vc)*1024 + p0 + pix] = f2bf(dm[2+ocf][r] + bv2[vc]);
        }
#pragma unroll
    for (int ocf=0; ocf<2; ocf++)
#pragma unroll
        for (int r=0;r<4;r++){
            int qc = ocf*16 + lhi*4 + r;
            unsigned byq = (unsigned)(pix*128) + (((unsigned)(qc*2))      ^ xsw);
            unsigned byk = (unsigned)(pix*128) + (((unsigned)(64 + qc*2)) ^ xsw);
            *reinterpret_cast<unsigned short*>(reinterpret_cast<char*>(cct) + 16384 + byq)
                = f2bf(dh[ocf][r]   + bq[qc]);
            *reinterpret_cast<unsigned short*>(reinterpret_cast<char*>(cct) + 16384 + byk)
                = f2bf(dh[2+ocf][r] + bk[qc]);
        }
    __syncthreads();
    for (int it=t; it<512; it+=256){
        int pr = it>>3, oct = it&7;
        unsigned byte = (unsigned)(pr*128) + (((unsigned)(oct*16)) ^ ((unsigned)(pr&7)<<4));
        ushort8 v = *reinterpret_cast<const ushort8*>(
            reinterpret_cast<const char*>(cct) + 16384 + byte);
        if (oct < 4) *reinterpret_cast<ushort8*>(Qb  + (size_t)(b*1024+p0+pr)*32 + oct*8) = v;
        else         *reinterpret_cast<ushort8*>(Khb + (size_t)(b*1024+p0+pr)*32 + (oct-4)*8) = v;
    }
    __syncthreads();
#pragma unroll
    for (int ocf=0; ocf<2; ocf++)
#pragma unroll
        for (int r=0;r<4;r++){
            int qc = ocf*16 + lhi*4 + r;
            unsigned byq = (unsigned)(pix*128) + (((unsigned)(qc*2)) ^ xsw);
            *reinterpret_cast<unsigned short*>(reinterpret_cast<char*>(cct) + 16384 + byq)
                = f2bf(dm[ocf][r] + bk2[qc]);
        }
    __syncthreads();
    {
        int pr = t>>2, oct = t&3;
        unsigned byte = (unsigned)(pr*128) + (((unsigned)(oct*16)) ^ ((unsigned)(pr&7)<<4));
        ushort8 v = *reinterpret_cast<const ushort8*>(
            reinterpret_cast<const char*>(cct) + 16384 + byte);
        *reinterpret_cast<ushort8*>(Kmb + (size_t)(b*1024+p0+pr)*32 + oct*8) = v;
    }
}

// ---------- fused attention + final mix: both passes per block, Z stays in LDS ----------
// Grid: 512 = 8 xcd x (2 b x 32 ptiles of 32 pixels). Waves 0-1: h-pass, waves 2-3: m-pass.
__global__ __launch_bounds__(256)
void attn_final_kernel(const unsigned short* __restrict__ Qb,
                       const unsigned short* __restrict__ Kh,
                       const unsigned short* __restrict__ Km,
                       const unsigned short* __restrict__ Vh,
                       const unsigned short* __restrict__ Vm,
                       const unsigned short* __restrict__ hT,
                       const unsigned short* __restrict__ wzb,
                       const unsigned short* __restrict__ wmb,
                       const float* __restrict__ bz, const float* __restrict__ bm,
                       const float* __restrict__ m_in,
                       float* __restrict__ out_h, float* __restrict__ out_m)
{
    const int bid  = blockIdx.x;
    const int xcd  = bid & 7;
    const int slot = bid >> 3;
    const int b    = xcd*2 + (slot>>5);
    const int p0   = (slot & 31) * 32;
    const int t   = threadIdx.x;
    const int l   = t & 63;
    const int w   = t >> 6;
    const int l15 = l & 15, g = l >> 4;
    const int pass = w >> 1;     // wave's attention pass (0=h, 1=m)
    const int ph   = w & 1;      // wave's 16-pixel half of the 32-pixel tile

    __shared__ __align__(16) unsigned short Kt[2][2][2560];  // [pass][buf][64q x 40]
    __shared__ __align__(16) unsigned short Vt[2][2][4096];  // [pass][buf][64c x 64q] swz
    __shared__ __align__(16) unsigned short Pt[2][2048];     // [pass][32p x 64q] swz
    __shared__ __align__(16) unsigned short Bs[32*192];      // final staging [32p][192k] swz

    const bf16x8 qa = *reinterpret_cast<const bf16x8*>(
        Qb + (size_t)(b*1024 + p0 + ph*16 + l15)*32 + g*8);

    float m_run = -1e30f, l_run = 0.0f;
    f32x4 acc[4];
#pragma unroll
    for (int cf=0;cf<4;cf++) acc[cf] = (f32x4){0.f,0.f,0.f,0.f};

    // staging assignments (all threads stage both passes)
    const int krow = t>>2, koct = t&3;
    const int vrow = t>>3, voct = t&7;
    const unsigned kwb  = (unsigned)(krow*80 + koct*16);
    const unsigned vwb0 = (unsigned)(vrow*128)      + (((unsigned)voct*16) ^ ((unsigned)(vrow&7)<<4));
    const unsigned vwb1 = (unsigned)((vrow+32)*128) + (((unsigned)voct*16) ^ ((unsigned)((vrow+32)&7)<<4));

    ushort8 kr0, kr1, vv0, vv1, vv2, vv3;
#define LDSTAGE(Q0N) do { \
        kr0 = *reinterpret_cast<const ushort8*>(Kh + (size_t)(b*1024 + (Q0N) + krow)*32 + koct*8); \
        kr1 = *reinterpret_cast<const ushort8*>(Km + (size_t)(b*1024 + (Q0N) + krow)*32 + koct*8); \
        vv0 = *reinterpret_cast<const ushort8*>(Vh + (size_t)(b*64 + vrow)*1024 + (Q0N) + voct*8); \
        vv1 = *reinterpret_cast<const ushort8*>(Vh + (size_t)(b*64 + vrow+32)*1024 + (Q0N) + voct*8); \
        vv2 = *reinterpret_cast<const ushort8*>(Vm + (size_t)(b*64 + vrow)*1024 + (Q0N) + voct*8); \
        vv3 = *reinterpret_cast<const ushort8*>(Vm + (size_t)(b*64 + vrow+32)*1024 + (Q0N) + voct*8); \
    } while(0)
#define WRSTAGE(BUF) do { \
        *reinterpret_cast<ushort8*>(reinterpret_cast<char*>(Kt[0][BUF]) + kwb)  = kr0; \
        *reinterpret_cast<ushort8*>(reinterpret_cast<char*>(Kt[1][BUF]) + kwb)  = kr1; \
        *reinterpret_cast<ushort8*>(reinterpret_cast<char*>(Vt[0][BUF]) + vwb0) = vv0; \
        *reinterpret_cast<ushort8*>(reinterpret_cast<char*>(Vt[0][BUF]) + vwb1) = vv1; \
        *reinterpret_cast<ushort8*>(reinterpret_cast<char*>(Vt[1][BUF]) + vwb0) = vv2; \
        *reinterpret_cast<ushort8*>(reinterpret_cast<char*>(Vt[1][BUF]) + vwb1) = vv3; \
    } while(0)

    LDSTAGE(0);
    WRSTAGE(0);
    __syncthreads();

    const unsigned prow = (unsigned)(ph*16 + l15);   // row within pass P region
    const unsigned psw  = (prow & 7u) << 4;
    char* Pbase = reinterpret_cast<char*>(Pt[pass]);

    for (int it=0; it<16; ++it){
        const int cur = it & 1;
        if (it < 15) LDSTAGE((it+1)*64);

        f32x4 s2[4];
#pragma unroll
        for (int qt=0; qt<4; qt++){
            const bf16x8 kb = *reinterpret_cast<const bf16x8*>(
                reinterpret_cast<const char*>(Kt[pass][cur]) + (qt*16 + l15)*80 + g*16);
            s2[qt] = __builtin_amdgcn_mfma_f32_16x16x32_bf16(kb, qa, (f32x4){0.f,0.f,0.f,0.f}, 0,0,0);
        }

        float pm = s2[0][0];
#pragma unroll
        for (int qt=0; qt<4; qt++)
#pragma unroll
            for (int r=0;r<4;r++) pm = fmaxf(pm, s2[qt][r]);
        pm = fmaxf(pm, __shfl_xor(pm, 16));
        pm = fmaxf(pm, __shfl_xor(pm, 32));

        if (!__all(pm <= m_run + 8.0f)){
            float mn = fmaxf(m_run, pm);
            float f  = __expf(m_run - mn);
            m_run = mn;
            l_run *= f;
#pragma unroll
            for (int r=0;r<4;r++){
                float fr = __shfl(f, (l & 48) | ((l>>4)*4 + r), 64);
#pragma unroll
                for (int cf=0;cf<4;cf++) acc[cf][r] *= fr;
            }
        }

        float e[4][4];
        float lsum = 0.f;
#pragma unroll
        for (int qt=0; qt<4; qt++)
#pragma unroll
            for (int r=0;r<4;r++){
                float ev = __expf(s2[qt][r] - m_run);
                e[qt][r] = ev;
                lsum += ev;
            }
        lsum += __shfl_xor(lsum, 16);
        lsum += __shfl_xor(lsum, 32);
        l_run += lsum;

#pragma unroll
        for (int qt=0; qt<4; qt++){
            uint2v pk;
            pk.x = cvt_pk_bf16(e[qt][0], e[qt][1]);
            pk.y = cvt_pk_bf16(e[qt][2], e[qt][3]);
            unsigned byte = prow*128 + (((unsigned)(qt*32 + g*8)) ^ psw);
            *reinterpret_cast<uint2v*>(Pbase + byte) = pk;
        }

#pragma unroll
        for (int ks=0;ks<2;ks++){
            unsigned abyte = prow*128 + (((unsigned)(ks*64 + g*16)) ^ psw);
            const bf16x8 pa = *reinterpret_cast<const bf16x8*>(Pbase + abyte);
#pragma unroll
            for (int cf=0;cf<4;cf++){
                unsigned vrw = (unsigned)(cf*16 + l15);
                unsigned vbyte = vrw*128 + (((unsigned)(ks*64 + g*16)) ^ ((vrw&7u)<<4));
                const bf16x8 vb = *reinterpret_cast<const bf16x8*>(
                    reinterpret_cast<const char*>(Vt[pass][cur]) + vbyte);
                acc[cf] = __builtin_amdgcn_mfma_f32_16x16x32_bf16(pa, vb, acc[cf], 0,0,0);
            }
        }

        if (it < 15) WRSTAGE(cur^1);
        __syncthreads();
    }
#undef LDSTAGE
#undef WRSTAGE

    // normalize + scatter Z into Bs cols [pass*64, pass*64+64)
    {
        float rl = 1.0f / l_run;
        float rr[4];
#pragma unroll
        for (int r=0;r<4;r++) rr[r] = __shfl(rl, (l & 48) | ((l>>4)*4 + r), 64);
#pragma unroll
        for (int cf=0;cf<4;cf++)
#pragma unroll
            for (int r=0;r<4;r++){
                unsigned pix = (unsigned)(ph*16 + g*4 + r);
                unsigned cch = (unsigned)(pass*64 + cf*16 + l15);
                unsigned byte = pix*384 + ((cch*2) ^ ((pix&7u)<<4));
                *reinterpret_cast<unsigned short*>(reinterpret_cast<char*>(Bs) + byte)
                    = f2bf(acc[cf][r]*rr[r]);
            }
    }
    // stage h_mid tile into Bs cols 128..191
    {
        int row = t>>3, oct = t&7;
        ushort8 v = *reinterpret_cast<const ushort8*>(
            hT + (size_t)(b*1024 + p0 + row)*64 + oct*8);
        unsigned byte = (unsigned)(row*384) + 256u + (((unsigned)oct*16) ^ ((unsigned)(row&7)<<4));
        *reinterpret_cast<ushort8*>(reinterpret_cast<char*>(Bs) + byte) = v;
    }
    __syncthreads();

    // GEMM1: Z1[128co][32pix], wave w owns co rows w*32..w*32+31
    f32x4 acc1[2][2];
#pragma unroll
    for (int i=0;i<2;i++)
#pragma unroll
        for (int cf=0;cf<2;cf++) acc1[i][cf] = (f32x4){0.f,0.f,0.f,0.f};
#pragma unroll
    for (int ks=0; ks<4; ++ks){
        bf16x8 af[2];
#pragma unroll
        for (int i=0;i<2;i++)
            af[i] = *reinterpret_cast<const bf16x8*>(
                wzb + (size_t)(w*32 + i*16 + l15)*128 + ks*32 + g*8);
#pragma unroll
        for (int cf=0;cf<2;cf++){
            unsigned p = (unsigned)(cf*16 + l15);
            unsigned byte = p*384 + (((unsigned)(ks*64 + g*16)) ^ ((p&7u)<<4));
            const bf16x8 bfr = *reinterpret_cast<const bf16x8*>(
                reinterpret_cast<const char*>(Bs) + byte);
            acc1[0][cf] = __builtin_amdgcn_mfma_f32_16x16x32_bf16(af[0], bfr, acc1[0][cf], 0,0,0);
            acc1[1][cf] = __builtin_amdgcn_mfma_f32_16x16x32_bf16(af[1], bfr, acc1[1][cf], 0,0,0);
        }
    }
    __syncthreads();
#pragma unroll
    for (int i=0;i<2;i++){
        int co = w*32 + i*16 + g*4;
#pragma unroll
        for (int cf=0;cf<2;cf++){
            unsigned p = (unsigned)(cf*16 + l15);
#pragma unroll
            for (int r=0;r<4;r++){
                float val = acc1[i][cf][r] + bz[co+r];
                unsigned byte = p*384 + (((unsigned)((co+r)*2)) ^ ((p&7u)<<4));
                *reinterpret_cast<unsigned short*>(reinterpret_cast<char*>(Bs) + byte) = f2bf(val);
            }
        }
    }
    __syncthreads();

    // GEMM2: comb[192][32pix], wave w owns rows {w*16, 64+w*16, 128+w*16}
    f32x4 acc2[3][2];
#pragma unroll
    for (int j=0;j<3;j++)
#pragma unroll
        for (int cf=0;cf<2;cf++) acc2[j][cf] = (f32x4){0.f,0.f,0.f,0.f};
#pragma unroll
    for (int ks=0; ks<6; ++ks){
        bf16x8 am[3];
#pragma unroll
        for (int j=0;j<3;j++)
            am[j] = *reinterpret_cast<const bf16x8*>(
                wmb + (size_t)(j*64 + w*16 + l15)*192 + ks*32 + g*8);
#pragma unroll
        for (int cf=0;cf<2;cf++){
            unsigned p = (unsigned)(cf*16 + l15);
            unsigned byte = p*384 + (((unsigned)(ks*64 + g*16)) ^ ((p&7u)<<4));
            const bf16x8 bfr = *reinterpret_cast<const bf16x8*>(
                reinterpret_cast<const char*>(Bs) + byte);
#pragma unroll
            for (int j=0;j<3;j++)
                acc2[j][cf] = __builtin_amdgcn_mfma_f32_16x16x32_bf16(am[j], bfr, acc2[j][cf], 0,0,0);
        }
    }

    const int ch0 = w*16 + g*4;
#pragma unroll
    for (int cf=0;cf<2;cf++){
        int pix = p0 + cf*16 + l15;
#pragma unroll
        for (int r=0;r<4;r++){
            int ch = ch0 + r;
            float mo = acc2[0][cf][r] + bm[ch];
            float mg = acc2[1][cf][r] + bm[64+ch];
            float mi = sigmoidf_(acc2[2][cf][r] + bm[128+ch]);
            float mv = m_in[(size_t)(b*64+ch)*1024 + pix];
            float mn = (1.0f - mi)*mv + mi*tanhf_(mg);
            out_m[(size_t)(b*64+ch)*1024 + pix] = mn;
            out_h[(size_t)(b*64+ch)*1024 + pix] = sigmoidf_(mo)*mn;
        }
    }
}

extern "C" void kernel_launch(void* const* d_in, const int* in_sizes, int n_in,
                              void* d_out, int out_size, void* d_ws, size_t ws_size,
                              hipStream_t stream)
{
    const float* x      = (const float*)d_in[0];
    const float* h      = (const float*)d_in[1];
    const float* c      = (const float*)d_in[2];
    const float* m      = (const float*)d_in[3];
    const float* lc     = (const float*)d_in[4];
    const float* conv_w = (const float*)d_in[5];
    const float* conv_b = (const float*)d_in[6];
    const float* gn1_w  = (const float*)d_in[7];
    const float* gn1_b  = (const float*)d_in[8];
    const float* convL_w= (const float*)d_in[9];
    const float* convL_b= (const float*)d_in[10];
    const float* gn2_w  = (const float*)d_in[11];
    const float* gn2_b  = (const float*)d_in[12];
    const float* wq  = (const float*)d_in[13];
    const float* bq  = (const float*)d_in[14];
    const float* wk  = (const float*)d_in[15];
    const float* bk  = (const float*)d_in[16];
    const float* wk2 = (const float*)d_in[17];
    const float* bk2 = (const float*)d_in[18];
    const float* wv  = (const float*)d_in[19];
    const float* bv  = (const float*)d_in[20];
    const float* wv2 = (const float*)d_in[21];
    const float* bv2 = (const float*)d_in[22];
    const float* wz  = (const float*)d_in[23];
    const float* bz  = (const float*)d_in[24];
    const float* wmw = (const float*)d_in[25];
    const float* bm  = (const float*)d_in[26];

    float* out = (float*)d_out;
    float* F = (float*)d_ws;
    unsigned short* cc_bf  = (unsigned short*)F;              // [16][256][1024] bf16
    unsigned short* buf1   = (unsigned short*)(F + 4194304);  // conv1 input [16][1024][128]
    unsigned short* buf2   = (unsigned short*)(F + 5242880);  // conv2 input
    unsigned short* hT     = (unsigned short*)(F + 6291456);  // [16][1024][64] bf16
    unsigned short* Qb     = (unsigned short*)(F + 6815744);
    unsigned short* Khb    = (unsigned short*)(F + 7077888);
    unsigned short* Kmb    = (unsigned short*)(F + 7340032);
    unsigned short* Vhb    = (unsigned short*)(F + 7602176);
    unsigned short* Vmb    = (unsigned short*)(F + 8126464);
    unsigned short* sig_pm = (unsigned short*)(F + 8650752);  // [16][1024][64] bf16
    unsigned short* wpk1   = (unsigned short*)(F + 9175040);
    unsigned short* wpk2   = (unsigned short*)(F + 9322496);
    unsigned short* wzb    = (unsigned short*)(F + 9469952);
    unsigned short* wmb    = (unsigned short*)(F + 9478144);
    unsigned short* wph    = (unsigned short*)(F + 9496576);  // [128][64] bf16
    unsigned short* wpm    = (unsigned short*)(F + 9500672);  // [96][64] bf16
    float*          stats  = F + 9503744;                     // [16][256][8][2] f32

    dim3 blk256(256);
    prep_kernel<<<dim3(1408), blk256, 0, stream>>>(conv_w, convL_w, wz, wmw,
                                                   wq, wk, wv, wk2, wv2, x, h,
                                                   wpk1, wpk2, wzb, wmb, wph, wpm,
                                                   buf1, buf2);
    dim3 cgrid(8, 4, 16);
    conv_mfma_kernel<<<cgrid, blk256, 0, stream>>>(buf1, wpk1, conv_b, cc_bf, stats);
    gn_gate1_kernel<<<dim3(16,16), blk256, 0, stream>>>(cc_bf, stats, gn1_w, gn1_b, c,
                                                        buf2, sig_pm);
    conv_mfma_kernel<<<cgrid, blk256, 0, stream>>>(buf2, wpk2, convL_b, cc_bf, stats);
    gn2_proj_kernel<<<dim3(16,16), blk256, 0, stream>>>(cc_bf, stats, gn2_w, gn2_b,
                                                        lc, sig_pm, m, wph, wpm,
                                                        bq, bk, bv, bk2, bv2,
                                                        out + 3*1048576 /*lc_next*/,
                                                        out + 1*1048576 /*c_next*/,
                                                        hT, Qb, Khb, Kmb, Vhb, Vmb);
    attn_final_kernel<<<dim3(512), blk256, 0, stream>>>(Qb, Khb, Kmb, Vhb, Vmb, hT,
                                                        wzb, wmb, bz, bm, m,
                                                        out /*h_next*/, out + 2*1048576 /*m_next*/);
    (void)in_sizes; (void)n_in; (void)out_size; (void)ws_size;
}